// Round 1
// baseline (5676.558 us; speedup 1.0000x reference)
//
#include <hip/hip_runtime.h>

// ============================================================================
// HOTRG (2D Ising) — fp32 baseline.
// Phase 1: build all U_i = expm(antisym(A_i))[:, :dcut] (batched scaling-squaring)
// Phase 2: 12 RG steps, each:
//   K1:    X2[(b,m,a),(j,n)] = sum_i T[i,b,m,n] * U[i,j,a]
//   GEMM2: Y[(b,m,a),(p,e)]  = X2 @ T[(j,n),(p,e)]      (the 28^7 hot GEMM)
//   K3:    Z[a,b,c,e]        = sum_{m,p} Y[b,m,a,p,e] * U[m,p,c]
//   lam = max|Z|; fe -= TEMP*log(lam)/2^(i+1); T' = permute(Z,(1,2,3,0))/lam
// ============================================================================

#define TEMPC 2.269f

struct SmallStep { int n, d0, dcut, s; long aoff; long uoff; };
struct SmallStep4 { SmallStep st[4]; };

// ---------------- small expm (n<=16), one block per step ----------------
__global__ __launch_bounds__(256) void expm_small_kernel(const float* __restrict__ Aflat,
                                                         float* __restrict__ W, SmallStep4 ps)
{
  SmallStep p = ps.st[blockIdx.x];
  const int n = p.n, nn = n * n;
  __shared__ float As[256], A2[256], Qa[256], Qb[256];
  const int tid = threadIdx.x;
  const int r = (tid < nn) ? (tid / n) : 0;
  const int c = (tid < nn) ? (tid % n) : 0;
  const float sc = 1.0f / (float)(1 << p.s);
  if (tid < nn) {
    float v = 0.0f;
    if (c > r)      v =  Aflat[p.aoff + (long)r*(n-1) - (long)r*(r-1)/2 + (c - r - 1)] * sc;
    else if (c < r) v = -Aflat[p.aoff + (long)c*(n-1) - (long)c*(c-1)/2 + (r - c - 1)] * sc;
    As[tid] = v;
  }
  __syncthreads();
  if (tid < nn) {
    float s2 = 0.0f;
    for (int k = 0; k < n; ++k) s2 += As[r*n+k] * As[k*n+c];
    A2[tid] = s2;
  }
  __syncthreads();
  if (tid < nn)
    Qa[tid] = (1.0f/40320.0f)*A2[tid] + (1.0f/5040.0f)*As[tid] + ((r==c) ? (1.0f/720.0f) : 0.0f);
  __syncthreads();
  float* q = Qa; float* qn = Qb;
  const float cis[3] = {1.0f/24.0f, 0.5f, 1.0f};
  const float cas[3] = {1.0f/120.0f, 1.0f/6.0f, 1.0f};
  #pragma unroll
  for (int it = 0; it < 3; ++it) {
    if (tid < nn) {
      float s2 = 0.0f;
      for (int k = 0; k < n; ++k) s2 += A2[r*n+k] * q[k*n+c];
      qn[tid] = s2 + cas[it]*As[tid] + ((r==c) ? cis[it] : 0.0f);
    }
    __syncthreads();
    float* t = q; q = qn; qn = t;
  }
  for (int it = 0; it < p.s; ++it) {
    float s2 = 0.0f;
    if (tid < nn) { for (int k = 0; k < n; ++k) s2 += q[r*n+k] * q[k*n+c]; }
    if (tid < nn) qn[tid] = s2;
    __syncthreads();
    float* t = q; q = qn; qn = t;
  }
  if (tid < n * p.dcut) {
    int rr = tid / p.dcut, aa = tid % p.dcut;
    W[p.uoff + tid] = q[rr*n + aa];
  }
}

// ---------------- batched big expm helpers ----------------
__global__ __launch_bounds__(256) void build_A_kernel(const float* __restrict__ Aflat, float* __restrict__ A,
                                                      int n, long aoff, long tri, float sc)
{
  const int b = blockIdx.y;
  const long nn = (long)n * n;
  const long id = (long)blockIdx.x * 256 + threadIdx.x;
  if (id >= nn) return;
  const int r = (int)(id / n), c = (int)(id % n);
  float v = 0.0f;
  if (c > r)      v =  Aflat[aoff + b*tri + (long)r*(n-1) - (long)r*(r-1)/2 + (c - r - 1)] * sc;
  else if (c < r) v = -Aflat[aoff + b*tri + (long)c*(n-1) - (long)c*(c-1)/2 + (r - c - 1)] * sc;
  A[b*nn + id] = v;
}

__global__ __launch_bounds__(256) void axpy_q_kernel(const float* __restrict__ A2, const float* __restrict__ A,
                                                     float* __restrict__ Q, int n)
{
  const int b = blockIdx.y;
  const long nn = (long)n * n;
  const long id = (long)blockIdx.x * 256 + threadIdx.x;
  if (id >= nn) return;
  const int r = (int)(id / n), c = (int)(id % n);
  Q[b*nn + id] = (1.0f/40320.0f)*A2[b*nn + id] + (1.0f/5040.0f)*A[b*nn + id]
               + ((r==c) ? (1.0f/720.0f) : 0.0f);
}

__global__ __launch_bounds__(256) void extract_u_kernel(const float* __restrict__ E, float* __restrict__ W,
                                                        int n, int dcut, long ubase, long ustride, long estride)
{
  const int b = blockIdx.y;
  const long tot = (long)n * dcut;
  const long id = (long)blockIdx.x * 256 + threadIdx.x;
  if (id >= tot) return;
  const int rr = (int)(id / dcut), aa = (int)(id % dcut);
  W[ubase + b*ustride + id] = E[b*estride + (long)rr*n + aa];
}

// ---------------- generic tiled fp32 GEMM (row-major), optional epilogue ----
// C = A@B (+ cA*Aadd + cI*I when useEp). Batched via blockIdx.z strides.
template<int BM, int BN, int BK, int TM, int TN>
__global__ __launch_bounds__(256) void gemm_f32(
    const float* __restrict__ A, const float* __restrict__ B, float* __restrict__ C,
    const float* __restrict__ Aadd, float cA, float cI, int useEp,
    int M, int N, int K, long sA, long sB, long sC, long sAd)
{
  constexpr int PAD = 4;
  __shared__ float As[BK][BM + PAD];
  __shared__ float Bs[BK][BN + PAD];
  const int tid = threadIdx.x;
  const int bz = blockIdx.z;
  const float* Ap = A + (long)bz * sA;
  const float* Bp = B + (long)bz * sB;
  float* Cp = C + (long)bz * sC;
  const float* Adp = useEp ? (Aadd + (long)bz * sAd) : nullptr;
  const int m0 = blockIdx.y * BM, n0 = blockIdx.x * BN;
  constexpr int TX = BN / TN;
  const int tx = tid % TX, ty = tid / TX;
  float acc[TM][TN];
  #pragma unroll
  for (int i = 0; i < TM; ++i)
    #pragma unroll
    for (int j = 0; j < TN; ++j) acc[i][j] = 0.0f;

  const int a_m = tid / (BK / 4);
  const int a_k = (tid % (BK / 4)) * 4;
  const int b_k = tid / (BN / 4);
  const int b_n = (tid % (BN / 4)) * 4;

  for (int k0 = 0; k0 < K; k0 += BK) {
    float4 av = make_float4(0.f, 0.f, 0.f, 0.f);
    if (m0 + a_m < M && k0 + a_k < K)
      av = *(const float4*)(Ap + (long)(m0 + a_m) * K + k0 + a_k);
    As[a_k + 0][a_m] = av.x; As[a_k + 1][a_m] = av.y;
    As[a_k + 2][a_m] = av.z; As[a_k + 3][a_m] = av.w;
    float4 bv = make_float4(0.f, 0.f, 0.f, 0.f);
    if (k0 + b_k < K && n0 + b_n < N)
      bv = *(const float4*)(Bp + (long)(k0 + b_k) * N + n0 + b_n);
    *(float4*)&Bs[b_k][b_n] = bv;
    __syncthreads();
    #pragma unroll
    for (int kk = 0; kk < BK; ++kk) {
      float af[TM], bf[TN];
      #pragma unroll
      for (int i = 0; i < TM; i += 4) *(float4*)&af[i] = *(const float4*)&As[kk][ty*TM + i];
      #pragma unroll
      for (int j = 0; j < TN; j += 4) *(float4*)&bf[j] = *(const float4*)&Bs[kk][tx*TN + j];
      #pragma unroll
      for (int i = 0; i < TM; ++i)
        #pragma unroll
        for (int j = 0; j < TN; ++j)
          acc[i][j] = fmaf(af[i], bf[j], acc[i][j]);
    }
    __syncthreads();
  }
  #pragma unroll
  for (int i = 0; i < TM; ++i) {
    int row = m0 + ty*TM + i;
    if (row >= M) continue;
    #pragma unroll
    for (int j = 0; j < TN; ++j) {
      int col = n0 + tx*TN + j;
      if (col >= N) continue;
      float v = acc[i][j];
      if (useEp) v += cA * Adp[(long)row * N + col] + ((row == col) ? cI : 0.0f);
      Cp[(long)row * N + col] = v;
    }
  }
}

// ---------------- contraction kernels ----------------
// X2[(b*t2+m)*dcut + a][j*t3 + n] = sum_i T[i,b,m,n]*U[i,j,a]; one block per (b,m)
__global__ __launch_bounds__(256) void k1_kernel(const float* __restrict__ T, const float* __restrict__ U,
                                                 float* __restrict__ X2, int t1, int t2, int t3, int d0, int dcut)
{
  extern __shared__ float lds[];
  float* Ts = lds;             // [i][n]  d0*t3
  float* Us = lds + d0 * t3;   // [i][a]  d0*dcut
  const int tid = threadIdx.x;
  const int bm = blockIdx.x;
  const long tstride = (long)t1 * t2 * t3;
  const long tbase = (long)bm * t3;
  for (int idx = tid; idx < d0 * t3; idx += 256) {
    int i = idx / t3, nn = idx % t3;
    Ts[idx] = T[(long)i * tstride + tbase + nn];
  }
  const int nout = dcut * t3;
  const int KK = d0 * t3;
  const long xbase = (long)bm * dcut * KK;
  __syncthreads();
  for (int j = 0; j < d0; ++j) {
    for (int idx = tid; idx < d0 * dcut; idx += 256)
      Us[idx] = U[((long)(idx / dcut) * d0 + j) * dcut + (idx % dcut)];
    __syncthreads();
    for (int idx = tid; idx < nout; idx += 256) {
      int a = idx / t3, nn = idx % t3;
      float s = 0.0f;
      for (int i = 0; i < d0; ++i) s += Ts[i*t3 + nn] * Us[i*dcut + a];
      X2[xbase + (long)a * KK + j*t3 + nn] = s;
    }
    __syncthreads();
  }
}

// Z[a,b,c,e] = sum_{m,p} Y[(b*t2+m)*dcut+a][p*t3+e] * U[m,p,c]; one block per (b,a)
__global__ __launch_bounds__(256) void k3_kernel(const float* __restrict__ Y, const float* __restrict__ U,
                                                 float* __restrict__ Z, int t1, int t2, int t3, int d0, int dcut)
{
  extern __shared__ float lds[];
  float* Ys = lds;             // [p][e]  d0*t3
  float* Us = lds + d0 * t3;   // [p][c]  d0*dcut
  const int tid = threadIdx.x;
  const int ba = blockIdx.x;
  const int b = ba / dcut, a = ba % dcut;
  const int nout = dcut * t3;
  const long NY = (long)t2 * t3;
  float acc[4] = {0.f, 0.f, 0.f, 0.f};
  for (int m = 0; m < t2; ++m) {
    const long yrow = ((long)(b*t2 + m) * dcut + a) * NY;
    for (int idx = tid; idx < d0 * t3; idx += 256) Ys[idx] = Y[yrow + idx];
    for (int idx = tid; idx < d0 * dcut; idx += 256) Us[idx] = U[(long)m * d0 * dcut + idx];
    __syncthreads();
    #pragma unroll
    for (int o = 0; o < 4; ++o) {
      int idx = tid + o * 256;
      if (idx < nout) {
        int cc = idx / t3, e = idx % t3;
        float s = 0.0f;
        for (int p = 0; p < d0; ++p) s += Ys[p*t3 + e] * Us[p*dcut + cc];
        acc[o] += s;
      }
    }
    __syncthreads();
  }
  #pragma unroll
  for (int o = 0; o < 4; ++o) {
    int idx = tid + o * 256;
    if (idx < nout) {
      int cc = idx / t3, e = idx % t3;
      Z[(((long)a * t1 + b) * dcut + cc) * t3 + e] = acc[o];
    }
  }
}

// ---------------- reductions / permute / init ----------------
__global__ __launch_bounds__(256) void redmax1_kernel(const float* __restrict__ Z, long cnt, float* __restrict__ part)
{
  __shared__ float sm[256];
  float v = 0.0f;
  for (long i = (long)blockIdx.x * 256 + threadIdx.x; i < cnt; i += (long)gridDim.x * 256)
    v = fmaxf(v, fabsf(Z[i]));
  sm[threadIdx.x] = v; __syncthreads();
  for (int s = 128; s > 0; s >>= 1) {
    if ((int)threadIdx.x < s) sm[threadIdx.x] = fmaxf(sm[threadIdx.x], sm[threadIdx.x + s]);
    __syncthreads();
  }
  if (threadIdx.x == 0) part[blockIdx.x] = sm[0];
}

__global__ __launch_bounds__(256) void redmax2_kernel(const float* __restrict__ part, float* __restrict__ invlam,
                                                      float* __restrict__ fe, float w, float* __restrict__ dout)
{
  __shared__ float sm[256];
  sm[threadIdx.x] = part[threadIdx.x]; __syncthreads();
  for (int s = 128; s > 0; s >>= 1) {
    if ((int)threadIdx.x < s) sm[threadIdx.x] = fmaxf(sm[threadIdx.x], sm[threadIdx.x + s]);
    __syncthreads();
  }
  if (threadIdx.x == 0) {
    float lam = sm[0];
    invlam[0] = 1.0f / lam;
    float f = fe[0] - w * logf(lam);
    fe[0] = f;
    dout[0] = f;
  }
}

// T'[b,c,e,a] = Z[a,b,c,e] * invlam; one block per (b,c)
__global__ __launch_bounds__(256) void permute_scale_kernel(const float* __restrict__ Z, float* __restrict__ Tn,
                                                            const float* __restrict__ invlam, int t1, int t3, int dcut)
{
  extern __shared__ float lds[];   // [a][e]
  const int tid = threadIdx.x;
  const int bc = blockIdx.x;
  const int b = bc / dcut, c = bc % dcut;
  const float s = invlam[0];
  const int tot = dcut * t3;
  for (int idx = tid; idx < tot; idx += 256) {
    int a = idx / t3, e = idx % t3;
    lds[idx] = Z[(((long)a * t1 + b) * dcut + c) * t3 + e] * s;
  }
  __syncthreads();
  const long ob = (long)bc * t3 * dcut;
  for (int idx = tid; idx < tot; idx += 256) {
    int e = idx / dcut, a = idx % dcut;
    Tn[ob + idx] = lds[a * t3 + e];
  }
}

__global__ void init_kernel(const float* __restrict__ T0, float* __restrict__ Tdst, float* __restrict__ fe)
{
  int t = threadIdx.x;
  if (t < 16) Tdst[t] = T0[t];
  if (t == 0) fe[0] = 0.0f;
}

// ============================================================================
extern "C" void kernel_launch(void* const* d_in, const int* in_sizes, int n_in,
                              void* d_out, int out_size, void* d_ws, size_t ws_size,
                              hipStream_t stream)
{
  const float* Aflat = (const float*)d_in[0];
  const float* T0    = (const float*)d_in[1];
  float* out = (float*)d_out;
  float* W = (float*)d_ws;

  // ---- static plan ----
  const int SH_n[12]  = {4,4,16,16,256,256,784,784,784,784,784,784};
  const int SH_d0[12] = {2,2,4,4,16,16,28,28,28,28,28,28};
  const int SH_dc[12] = {4,4,16,16,28,28,28,28,28,28,28,28};
  long aoff[12]; { long o = 0; for (int i = 0; i < 12; ++i) { aoff[i] = o; o += (long)SH_n[i]*(SH_n[i]-1)/2; } }
  long uoff[12]; { long o = 512; for (int i = 0; i < 12; ++i) { uoff[i] = o; o += (long)SH_d0[i]*SH_d0[i]*SH_dc[i]; } }
  int T1d[12], T2d[12], T3d[12], T0d[12];
  { int a=2,b=2,c=2,d=2;
    for (int i = 0; i < 12; ++i) { T0d[i]=a; T1d[i]=b; T2d[i]=c; T3d[i]=d;
      int dc = SH_dc[i]; int na=b, nb=dc, nc=d, nd=dc; a=na; b=nb; c=nc; d=nd; } }

  // ---- workspace layout (float offsets) ----
  const long FE = 0, INVLAM = 1, PART = 64;
  const long TA  = 147200;
  const long TB  = TA + 614656;          // 761856
  const long ZBo = TB + 614656;          // 1376512
  const long BIG = ZBo + 614656;         // 1991168
  const long X2o = BIG;
  const long Yo  = BIG + 17210368;
  // phase-1 expm scratch (overlaps X2/Y region; phases are sequential)
  const long NN784 = 614656, B6 = 6 * NN784;       // 3,687,936
  const long A_as = BIG, A_a2 = BIG + B6, A_q1 = BIG + 2*B6, A_q2 = BIG + 3*B6;
  const long NN256 = 65536, B2 = 2 * NN256;
  const long Bb = BIG + 4*B6;
  const long B_as = Bb, B_a2 = Bb + B2, B_q1 = Bb + 2*B2, B_q2 = Bb + 3*B2;
  (void)ws_size; (void)in_sizes; (void)n_in; (void)out_size;

  const float c5 = 1.0f/120.0f, c4 = 1.0f/24.0f, c3 = 1.0f/6.0f, c2 = 0.5f;

  // ================= Phase 1: build all U matrices =================
  // steps 0-3 (n=4,4,16,16): single fused kernel, s = {0,0,1,1}
  {
    SmallStep4 sp;
    const int ss[4] = {0,0,1,1};
    for (int i = 0; i < 4; ++i) {
      sp.st[i].n = SH_n[i]; sp.st[i].d0 = SH_d0[i]; sp.st[i].dcut = SH_dc[i];
      sp.st[i].s = ss[i]; sp.st[i].aoff = aoff[i]; sp.st[i].uoff = uoff[i];
    }
    expm_small_kernel<<<4, 256, 0, stream>>>(Aflat, W, sp);
  }

  // group B: steps 4,5 (n=256, batch=2, s=3)
  {
    const int n = 256, bt = 2; const long st = NN256; const long tri = 32640;
    build_A_kernel<<<dim3(256, bt), 256, 0, stream>>>(Aflat, W + B_as, n, aoff[4], tri, 1.0f/8.0f);
    dim3 g(4, 4, bt);
    gemm_f32<64,64,16,4,4><<<g,256,0,stream>>>(W+B_as, W+B_as, W+B_a2, nullptr,0,0,0, n,n,n, st,st,st,st);
    axpy_q_kernel<<<dim3(256, bt), 256, 0, stream>>>(W + B_a2, W + B_as, W + B_q1, n);
    gemm_f32<64,64,16,4,4><<<g,256,0,stream>>>(W+B_a2, W+B_q1, W+B_q2, W+B_as, c5, c4, 1, n,n,n, st,st,st,st);
    gemm_f32<64,64,16,4,4><<<g,256,0,stream>>>(W+B_a2, W+B_q2, W+B_q1, W+B_as, c3, c2, 1, n,n,n, st,st,st,st);
    gemm_f32<64,64,16,4,4><<<g,256,0,stream>>>(W+B_a2, W+B_q1, W+B_q2, W+B_as, 1.f, 1.f, 1, n,n,n, st,st,st,st);
    gemm_f32<64,64,16,4,4><<<g,256,0,stream>>>(W+B_q2, W+B_q2, W+B_q1, nullptr,0,0,0, n,n,n, st,st,st,st);
    gemm_f32<64,64,16,4,4><<<g,256,0,stream>>>(W+B_q1, W+B_q1, W+B_q2, nullptr,0,0,0, n,n,n, st,st,st,st);
    gemm_f32<64,64,16,4,4><<<g,256,0,stream>>>(W+B_q2, W+B_q2, W+B_q1, nullptr,0,0,0, n,n,n, st,st,st,st);
    extract_u_kernel<<<dim3(28, bt), 256, 0, stream>>>(W + B_q1, W, n, 28, uoff[4], 7168, st);
  }

  // group A: steps 6-11 (n=784, batch=6, s=4)
  {
    const int n = 784, bt = 6; const long st = NN784; const long tri = 306936;
    build_A_kernel<<<dim3(2401, bt), 256, 0, stream>>>(Aflat, W + A_as, n, aoff[6], tri, 1.0f/16.0f);
    dim3 g(13, 13, bt);
    gemm_f32<64,64,16,4,4><<<g,256,0,stream>>>(W+A_as, W+A_as, W+A_a2, nullptr,0,0,0, n,n,n, st,st,st,st);
    axpy_q_kernel<<<dim3(2401, bt), 256, 0, stream>>>(W + A_a2, W + A_as, W + A_q1, n);
    gemm_f32<64,64,16,4,4><<<g,256,0,stream>>>(W+A_a2, W+A_q1, W+A_q2, W+A_as, c5, c4, 1, n,n,n, st,st,st,st);
    gemm_f32<64,64,16,4,4><<<g,256,0,stream>>>(W+A_a2, W+A_q2, W+A_q1, W+A_as, c3, c2, 1, n,n,n, st,st,st,st);
    gemm_f32<64,64,16,4,4><<<g,256,0,stream>>>(W+A_a2, W+A_q1, W+A_q2, W+A_as, 1.f, 1.f, 1, n,n,n, st,st,st,st);
    gemm_f32<64,64,16,4,4><<<g,256,0,stream>>>(W+A_q2, W+A_q2, W+A_q1, nullptr,0,0,0, n,n,n, st,st,st,st);
    gemm_f32<64,64,16,4,4><<<g,256,0,stream>>>(W+A_q1, W+A_q1, W+A_q2, nullptr,0,0,0, n,n,n, st,st,st,st);
    gemm_f32<64,64,16,4,4><<<g,256,0,stream>>>(W+A_q2, W+A_q2, W+A_q1, nullptr,0,0,0, n,n,n, st,st,st,st);
    gemm_f32<64,64,16,4,4><<<g,256,0,stream>>>(W+A_q1, W+A_q1, W+A_q2, nullptr,0,0,0, n,n,n, st,st,st,st);
    extract_u_kernel<<<dim3(86, bt), 256, 0, stream>>>(W + A_q2, W, n, 28, uoff[6], 21952, st);
  }

  // ================= Phase 2: 12 RG steps =================
  float* Tcur = W + TA;
  float* Tnext = W + TB;
  init_kernel<<<1, 256, 0, stream>>>(T0, Tcur, W + FE);

  for (int i = 0; i < 12; ++i) {
    const int t1 = T1d[i], t2 = T2d[i], t3 = T3d[i], d0 = T0d[i], dc = SH_dc[i];
    const float* U = W + uoff[i];

    // K1: X2
    const int lds1 = (d0*t3 + d0*dc) * (int)sizeof(float);
    k1_kernel<<<t1*t2, 256, lds1, stream>>>(Tcur, U, W + X2o, t1, t2, t3, d0, dc);

    // GEMM2: Y = X2 @ T
    const int M = t1*t2*dc, K = d0*t3, N = t2*t3;
    dim3 g2((N + 127) / 128, (M + 127) / 128, 1);
    gemm_f32<128,128,8,8,8><<<g2, 256, 0, stream>>>(W + X2o, Tcur, W + Yo, nullptr, 0, 0, 0,
                                                    M, N, K, 0, 0, 0, 0);

    // K3: Z
    const int lds3 = (d0*t3 + d0*dc) * (int)sizeof(float);
    k3_kernel<<<t1*dc, 256, lds3, stream>>>(W + Yo, U, W + ZBo, t1, t2, t3, d0, dc);

    // lam = max|Z|; fe update (also writes running fe to d_out; last write wins)
    const long cnt = (long)dc * t1 * dc * t3;
    redmax1_kernel<<<256, 256, 0, stream>>>(W + ZBo, cnt, W + PART);
    const float w = TEMPC / (float)(1 << (i + 1));
    redmax2_kernel<<<1, 256, 0, stream>>>(W + PART, W + INVLAM, W + FE, w, out);

    // T' = permute(Z)/lam
    permute_scale_kernel<<<t1*dc, 256, dc*t3*(int)sizeof(float), stream>>>(W + ZBo, Tnext, W + INVLAM, t1, t3, dc);

    float* tmp = Tcur; Tcur = Tnext; Tnext = tmp;
  }
}

// Round 2
// 2982.862 us; speedup vs baseline: 1.9031x; 1.9031x over previous
//
#include <hip/hip_runtime.h>

// ============================================================================
// HOTRG (2D Ising) — R2: bf16 MFMA for all heavy GEMMs.
//  - expm (n=784, batch 6): Taylor-8 + 4 squarings, all products via
//    mfma_f32_16x16x32_bf16 with fp32 accumulate. Transpose-free Horner:
//    A2 symmetric => its own K-major operand; A^T = -A. Squarings use a
//    bf16 transpose kernel.
//  - big contraction GEMM (steps 4-11): X2(bf16) @ T^T(bf16) -> Y(bf16).
//  - steps 0-3 and n=256 expm stay in exact fp32 (weights too large / cheap).
// ============================================================================

#define TEMPC 2.269f

typedef unsigned int uint32;
typedef short short8b __attribute__((ext_vector_type(8)));
typedef float f32x4 __attribute__((ext_vector_type(4)));

__device__ __forceinline__ ushort f2bf(float x) {
  uint32 u = __float_as_uint(x);
  u = (u + 0x7FFFu + ((u >> 16) & 1u)) >> 16;
  return (ushort)u;
}
__device__ __forceinline__ float toF(float x) { return x; }
__device__ __forceinline__ float toF(ushort h) { return __uint_as_float(((uint32)h) << 16); }

__device__ __forceinline__ void gll16(const ushort* g, ushort* l) {
  __builtin_amdgcn_global_load_lds((const __attribute__((address_space(1))) void*)g,
                                   (__attribute__((address_space(3))) void*)l, 16, 0, 0);
}

// ---------------- MFMA GEMM: C = A @ B, A row-major [.][Kp], B given K-major
// (Bt[n][k]). 4 waves, 2x2 wave grid, BK=64, XOR-swizzled LDS, global_load_lds.
// mode: 1=add cA*Aadd + cI*I, 2=write Cf (f32), 4=write Cb (bf16).
template<int BM, int BN>
__global__ __launch_bounds__(256) void gemm_mfma(
    const ushort* __restrict__ A, const ushort* __restrict__ Bt,
    float* __restrict__ Cf, ushort* __restrict__ Cb,
    const float* __restrict__ Aadd, float cA, float cI, int mode,
    int Np, int Kp, long sA, long sB, long sC)
{
  constexpr int FRM = BM / 32, FRN = BN / 32;
  constexpr int LA = BM / 8, LB = BN / 8, LPW = (LA + LB) / 4;
  __shared__ __align__(16) ushort As[BM * 64];
  __shared__ __align__(16) ushort Bs[BN * 64];
  const int tid = threadIdx.x;
  const int wid = tid >> 6, lane = tid & 63;
  const int bz = blockIdx.z;
  const int m0 = blockIdx.y * BM, n0 = blockIdx.x * BN;
  const int wm0 = (wid >> 1) * (BM / 2), wn0 = (wid & 1) * (BN / 2);
  const int rl = lane & 15, cb = lane >> 4;
  const ushort* Ap = A + (long)bz * sA + (long)m0 * Kp;
  const ushort* Bp = Bt + (long)bz * sB + (long)n0 * Kp;

  f32x4 acc[FRM][FRN];
  #pragma unroll
  for (int i = 0; i < FRM; ++i)
    #pragma unroll
    for (int j = 0; j < FRN; ++j) { acc[i][j][0]=0.f; acc[i][j][1]=0.f; acc[i][j][2]=0.f; acc[i][j][3]=0.f; }

  for (int k0 = 0; k0 < Kp; k0 += 64) {
    #pragma unroll
    for (int t = 0; t < LPW; ++t) {
      int gl = wid * LPW + t;
      int isA = gl < LA;
      int tt = isA ? gl : gl - LA;
      int li = tt * 64 + lane;
      int r = li >> 3, ch = li & 7;
      int sch = ch ^ (r & 7);
      if (isA) gll16(Ap + (long)r * Kp + k0 + sch * 8, &As[tt * 512]);
      else     gll16(Bp + (long)r * Kp + k0 + sch * 8, &Bs[tt * 512]);
    }
    __syncthreads();
    #pragma unroll
    for (int km = 0; km < 2; ++km) {
      short8b af[FRM], bfv[FRN];
      #pragma unroll
      for (int i = 0; i < FRM; ++i) {
        int r = wm0 + i * 16 + rl;
        af[i] = *(const short8b*)&As[r * 64 + ((((km << 2) | cb) ^ (r & 7)) << 3)];
      }
      #pragma unroll
      for (int j = 0; j < FRN; ++j) {
        int r = wn0 + j * 16 + rl;
        bfv[j] = *(const short8b*)&Bs[r * 64 + ((((km << 2) | cb) ^ (r & 7)) << 3)];
      }
      #pragma unroll
      for (int i = 0; i < FRM; ++i)
        #pragma unroll
        for (int j = 0; j < FRN; ++j)
          acc[i][j] = __builtin_amdgcn_mfma_f32_16x16x32_bf16(af[i], bfv[j], acc[i][j], 0, 0, 0);
    }
    __syncthreads();
  }
  const int r4 = (lane >> 4) * 4, cl = lane & 15;
  #pragma unroll
  for (int i = 0; i < FRM; ++i) {
    #pragma unroll
    for (int j = 0; j < FRN; ++j) {
      int row0 = m0 + wm0 + i * 16 + r4;
      int col  = n0 + wn0 + j * 16 + cl;
      #pragma unroll
      for (int q = 0; q < 4; ++q) {
        long off = (long)bz * sC + (long)(row0 + q) * Np + col;
        float v = acc[i][j][q];
        if (mode & 1) v += cA * Aadd[off] + ((row0 + q) == col ? cI : 0.0f);
        if (mode & 2) Cf[off] = v;
        if (mode & 4) Cb[off] = f2bf(v);
      }
    }
  }
}

// ---------------- transpose -> bf16 K-major (out[c][r] = in[r][c]) ----------
template<typename TI>
__global__ __launch_bounds__(256) void trans_to_bfT(const TI* __restrict__ in, ushort* __restrict__ out,
                                                    int R, int C, int inStride, int outStride,
                                                    long sIn, long sOut)
{
  __shared__ float sm[32][33];
  const TI* ip = in + (long)blockIdx.z * sIn;
  ushort* op = out + (long)blockIdx.z * sOut;
  int c0 = blockIdx.x * 32, r0 = blockIdx.y * 32;
  int lx = threadIdx.x & 31, ly = threadIdx.x >> 5;
  #pragma unroll
  for (int yy = 0; yy < 4; ++yy) {
    int r = r0 + ly + yy * 8, c = c0 + lx;
    if (r < R && c < C) sm[ly + yy * 8][lx] = toF(ip[(long)r * inStride + c]);
  }
  __syncthreads();
  #pragma unroll
  for (int yy = 0; yy < 4; ++yy) {
    int orow = c0 + ly + yy * 8;   // original col
    int ocol = r0 + lx;            // original row
    if (orow < C && ocol < R) op[(long)orow * outStride + ocol] = f2bf(sm[lx][ly + yy * 8]);
  }
}

// ---------------- expm builders ----------------
__global__ __launch_bounds__(256) void build_A2(const float* __restrict__ Aflat, float* __restrict__ Af,
                                                ushort* __restrict__ Ab, ushort* __restrict__ An,
                                                int n, int Np, long aoff, long tri, float sc)
{
  const int b = blockIdx.y;
  const long nn = (long)Np * Np;
  const long id = (long)blockIdx.x * 256 + threadIdx.x;
  if (id >= nn) return;
  const int r = (int)(id / Np), c = (int)(id % Np);
  float v = 0.0f;
  if (r < n && c < n) {
    if (c > r)      v =  Aflat[aoff + b * tri + (long)r * (n - 1) - (long)r * (r - 1) / 2 + (c - r - 1)] * sc;
    else if (c < r) v = -Aflat[aoff + b * tri + (long)c * (n - 1) - (long)c * (c - 1) / 2 + (r - c - 1)] * sc;
  }
  long o = b * nn + id;
  Af[o] = v; Ab[o] = f2bf(v); An[o] = f2bf(-v);
}

__global__ __launch_bounds__(256) void axpy_q2(const ushort* __restrict__ A2b, const float* __restrict__ Af,
                                               ushort* __restrict__ Qb, int Np)
{
  const int b = blockIdx.y;
  const long nn = (long)Np * Np;
  const long id = (long)blockIdx.x * 256 + threadIdx.x;
  if (id >= nn) return;
  const int r = (int)(id / Np), c = (int)(id % Np);
  long o = b * nn + id;
  float v = (1.0f/40320.0f) * toF(A2b[o]) + (1.0f/5040.0f) * Af[o] + ((r == c) ? (1.0f/720.0f) : 0.0f);
  Qb[o] = f2bf(v);
}

__global__ __launch_bounds__(256) void extract_u2(const float* __restrict__ E, float* __restrict__ W,
                                                  int n, int dcut, int rowStride, long ubase, long ustride, long estride)
{
  const int b = blockIdx.y;
  const long tot = (long)n * dcut;
  const long id = (long)blockIdx.x * 256 + threadIdx.x;
  if (id >= tot) return;
  const int rr = (int)(id / dcut), aa = (int)(id % dcut);
  W[ubase + b * ustride + id] = E[b * estride + (long)rr * rowStride + aa];
}

// ---------------- small expm (n<=16), one block per step ----------------
struct SmallStep { int n, d0, dcut, s; long aoff; long uoff; };
struct SmallStep4 { SmallStep st[4]; };

__global__ __launch_bounds__(256) void expm_small_kernel(const float* __restrict__ Aflat,
                                                         float* __restrict__ W, SmallStep4 ps)
{
  SmallStep p = ps.st[blockIdx.x];
  const int n = p.n, nn = n * n;
  __shared__ float As[256], A2[256], Qa[256], Qb[256];
  const int tid = threadIdx.x;
  const int r = (tid < nn) ? (tid / n) : 0;
  const int c = (tid < nn) ? (tid % n) : 0;
  const float sc = 1.0f / (float)(1 << p.s);
  if (tid < nn) {
    float v = 0.0f;
    if (c > r)      v =  Aflat[p.aoff + (long)r*(n-1) - (long)r*(r-1)/2 + (c - r - 1)] * sc;
    else if (c < r) v = -Aflat[p.aoff + (long)c*(n-1) - (long)c*(c-1)/2 + (r - c - 1)] * sc;
    As[tid] = v;
  }
  __syncthreads();
  if (tid < nn) {
    float s2 = 0.0f;
    for (int k = 0; k < n; ++k) s2 += As[r*n+k] * As[k*n+c];
    A2[tid] = s2;
  }
  __syncthreads();
  if (tid < nn)
    Qa[tid] = (1.0f/40320.0f)*A2[tid] + (1.0f/5040.0f)*As[tid] + ((r==c) ? (1.0f/720.0f) : 0.0f);
  __syncthreads();
  float* q = Qa; float* qn = Qb;
  const float cis[3] = {1.0f/24.0f, 0.5f, 1.0f};
  const float cas[3] = {1.0f/120.0f, 1.0f/6.0f, 1.0f};
  #pragma unroll
  for (int it = 0; it < 3; ++it) {
    if (tid < nn) {
      float s2 = 0.0f;
      for (int k = 0; k < n; ++k) s2 += A2[r*n+k] * q[k*n+c];
      qn[tid] = s2 + cas[it]*As[tid] + ((r==c) ? cis[it] : 0.0f);
    }
    __syncthreads();
    float* t = q; q = qn; qn = t;
  }
  for (int it = 0; it < p.s; ++it) {
    float s2 = 0.0f;
    if (tid < nn) { for (int k = 0; k < n; ++k) s2 += q[r*n+k] * q[k*n+c]; }
    if (tid < nn) qn[tid] = s2;
    __syncthreads();
    float* t = q; q = qn; qn = t;
  }
  if (tid < n * p.dcut) {
    int rr = tid / p.dcut, aa = tid % p.dcut;
    W[p.uoff + tid] = q[rr*n + aa];
  }
}

// ---------------- legacy fp32 helpers (group B + steps 0-3) ----------------
__global__ __launch_bounds__(256) void build_A_kernel(const float* __restrict__ Aflat, float* __restrict__ A,
                                                      int n, long aoff, long tri, float sc)
{
  const int b = blockIdx.y;
  const long nn = (long)n * n;
  const long id = (long)blockIdx.x * 256 + threadIdx.x;
  if (id >= nn) return;
  const int r = (int)(id / n), c = (int)(id % n);
  float v = 0.0f;
  if (c > r)      v =  Aflat[aoff + b*tri + (long)r*(n-1) - (long)r*(r-1)/2 + (c - r - 1)] * sc;
  else if (c < r) v = -Aflat[aoff + b*tri + (long)c*(n-1) - (long)c*(c-1)/2 + (r - c - 1)] * sc;
  A[b*nn + id] = v;
}

__global__ __launch_bounds__(256) void axpy_q_kernel(const float* __restrict__ A2, const float* __restrict__ A,
                                                     float* __restrict__ Q, int n)
{
  const int b = blockIdx.y;
  const long nn = (long)n * n;
  const long id = (long)blockIdx.x * 256 + threadIdx.x;
  if (id >= nn) return;
  const int r = (int)(id / n), c = (int)(id % n);
  Q[b*nn + id] = (1.0f/40320.0f)*A2[b*nn + id] + (1.0f/5040.0f)*A[b*nn + id]
               + ((r==c) ? (1.0f/720.0f) : 0.0f);
}

template<int BM, int BN, int BK, int TM, int TN>
__global__ __launch_bounds__(256) void gemm_f32(
    const float* __restrict__ A, const float* __restrict__ B, float* __restrict__ C,
    const float* __restrict__ Aadd, float cA, float cI, int useEp,
    int M, int N, int K, long sA, long sB, long sC, long sAd)
{
  constexpr int PAD = 4;
  __shared__ float As[BK][BM + PAD];
  __shared__ float Bs[BK][BN + PAD];
  const int tid = threadIdx.x;
  const int bz = blockIdx.z;
  const float* Ap = A + (long)bz * sA;
  const float* Bp = B + (long)bz * sB;
  float* Cp = C + (long)bz * sC;
  const float* Adp = useEp ? (Aadd + (long)bz * sAd) : nullptr;
  const int m0 = blockIdx.y * BM, n0 = blockIdx.x * BN;
  constexpr int TX = BN / TN;
  const int tx = tid % TX, ty = tid / TX;
  float acc[TM][TN];
  #pragma unroll
  for (int i = 0; i < TM; ++i)
    #pragma unroll
    for (int j = 0; j < TN; ++j) acc[i][j] = 0.0f;

  const int a_m = tid / (BK / 4);
  const int a_k = (tid % (BK / 4)) * 4;
  const int b_k = tid / (BN / 4);
  const int b_n = (tid % (BN / 4)) * 4;

  for (int k0 = 0; k0 < K; k0 += BK) {
    float4 av = make_float4(0.f, 0.f, 0.f, 0.f);
    if (m0 + a_m < M && k0 + a_k < K)
      av = *(const float4*)(Ap + (long)(m0 + a_m) * K + k0 + a_k);
    As[a_k + 0][a_m] = av.x; As[a_k + 1][a_m] = av.y;
    As[a_k + 2][a_m] = av.z; As[a_k + 3][a_m] = av.w;
    float4 bv = make_float4(0.f, 0.f, 0.f, 0.f);
    if (k0 + b_k < K && n0 + b_n < N)
      bv = *(const float4*)(Bp + (long)(k0 + b_k) * N + n0 + b_n);
    *(float4*)&Bs[b_k][b_n] = bv;
    __syncthreads();
    #pragma unroll
    for (int kk = 0; kk < BK; ++kk) {
      float af[TM], bf[TN];
      #pragma unroll
      for (int i = 0; i < TM; i += 4) *(float4*)&af[i] = *(const float4*)&As[kk][ty*TM + i];
      #pragma unroll
      for (int j = 0; j < TN; j += 4) *(float4*)&bf[j] = *(const float4*)&Bs[kk][tx*TN + j];
      #pragma unroll
      for (int i = 0; i < TM; ++i)
        #pragma unroll
        for (int j = 0; j < TN; ++j)
          acc[i][j] = fmaf(af[i], bf[j], acc[i][j]);
    }
    __syncthreads();
  }
  #pragma unroll
  for (int i = 0; i < TM; ++i) {
    int row = m0 + ty*TM + i;
    if (row >= M) continue;
    #pragma unroll
    for (int j = 0; j < TN; ++j) {
      int col = n0 + tx*TN + j;
      if (col >= N) continue;
      float v = acc[i][j];
      if (useEp) v += cA * Adp[(long)row * N + col] + ((row == col) ? cI : 0.0f);
      Cp[(long)row * N + col] = v;
    }
  }
}

// ---------------- contraction kernels ----------------
__global__ __launch_bounds__(256) void k1_kernel2(const float* __restrict__ T, const float* __restrict__ U,
                                                  ushort* __restrict__ X2b, float* __restrict__ X2f,
                                                  int t1, int t2, int t3, int d0, int dcut,
                                                  int K, int Kp, int wf)
{
  extern __shared__ float lds[];
  float* Ts = lds;             // [i][n]  d0*t3
  float* Us = lds + d0 * t3;   // [i][a]  d0*dcut
  const int tid = threadIdx.x;
  const int bm = blockIdx.x;
  const long tstride = (long)t1 * t2 * t3;
  const long tbase = (long)bm * t3;
  for (int idx = tid; idx < d0 * t3; idx += 256) {
    int i = idx / t3, nn = idx % t3;
    Ts[idx] = T[(long)i * tstride + tbase + nn];
  }
  const int nout = dcut * t3;
  __syncthreads();
  for (int j = 0; j < d0; ++j) {
    for (int idx = tid; idx < d0 * dcut; idx += 256)
      Us[idx] = U[((long)(idx / dcut) * d0 + j) * dcut + (idx % dcut)];
    __syncthreads();
    for (int idx = tid; idx < nout; idx += 256) {
      int a = idx / t3, nn = idx % t3;
      float s = 0.0f;
      for (int i = 0; i < d0; ++i) s += Ts[i*t3 + nn] * Us[i*dcut + a];
      long row = (long)bm * dcut + a;
      int col = j * t3 + nn;
      X2b[row * Kp + col] = f2bf(s);
      if (wf) X2f[row * K + col] = s;
    }
    __syncthreads();
  }
  for (int idx = tid; idx < dcut * (Kp - K); idx += 256) {
    int a = idx / (Kp - K), cc = idx % (Kp - K);
    X2b[((long)bm * dcut + a) * Kp + K + cc] = 0;
  }
}

template<typename TY>
__global__ __launch_bounds__(256) void k3_kernel2(const TY* __restrict__ Y, const float* __restrict__ U,
                                                  float* __restrict__ Z, int t1, int t2, int t3, int d0, int dcut,
                                                  int Ystride)
{
  extern __shared__ float lds[];
  float* Ys = lds;             // [p][e]  d0*t3
  float* Us = lds + d0 * t3;   // [p][c]  d0*dcut
  const int tid = threadIdx.x;
  const int ba = blockIdx.x;
  const int b = ba / dcut, a = ba % dcut;
  const int nout = dcut * t3;
  float acc[4] = {0.f, 0.f, 0.f, 0.f};
  for (int m = 0; m < t2; ++m) {
    const long yrow = ((long)(b*t2 + m) * dcut + a) * Ystride;
    for (int idx = tid; idx < d0 * t3; idx += 256) Ys[idx] = toF(Y[yrow + idx]);
    for (int idx = tid; idx < d0 * dcut; idx += 256) Us[idx] = U[(long)m * d0 * dcut + idx];
    __syncthreads();
    #pragma unroll
    for (int o = 0; o < 4; ++o) {
      int idx = tid + o * 256;
      if (idx < nout) {
        int cc = idx / t3, e = idx % t3;
        float s = 0.0f;
        for (int p = 0; p < d0; ++p) s += Ys[p*t3 + e] * Us[p*dcut + cc];
        acc[o] += s;
      }
    }
    __syncthreads();
  }
  #pragma unroll
  for (int o = 0; o < 4; ++o) {
    int idx = tid + o * 256;
    if (idx < nout) {
      int cc = idx / t3, e = idx % t3;
      Z[(((long)a * t1 + b) * dcut + cc) * t3 + e] = acc[o];
    }
  }
}

// ---------------- reductions / permute / init ----------------
__global__ __launch_bounds__(256) void redmax1_kernel(const float* __restrict__ Z, long cnt, float* __restrict__ part)
{
  __shared__ float sm[256];
  float v = 0.0f;
  for (long i = (long)blockIdx.x * 256 + threadIdx.x; i < cnt; i += (long)gridDim.x * 256)
    v = fmaxf(v, fabsf(Z[i]));
  sm[threadIdx.x] = v; __syncthreads();
  for (int s = 128; s > 0; s >>= 1) {
    if ((int)threadIdx.x < s) sm[threadIdx.x] = fmaxf(sm[threadIdx.x], sm[threadIdx.x + s]);
    __syncthreads();
  }
  if (threadIdx.x == 0) part[blockIdx.x] = sm[0];
}

__global__ __launch_bounds__(256) void redmax2_kernel(const float* __restrict__ part, float* __restrict__ invlam,
                                                      float* __restrict__ fe, float w, float* __restrict__ dout)
{
  __shared__ float sm[256];
  sm[threadIdx.x] = part[threadIdx.x]; __syncthreads();
  for (int s = 128; s > 0; s >>= 1) {
    if ((int)threadIdx.x < s) sm[threadIdx.x] = fmaxf(sm[threadIdx.x], sm[threadIdx.x + s]);
    __syncthreads();
  }
  if (threadIdx.x == 0) {
    float lam = sm[0];
    invlam[0] = 1.0f / lam;
    float f = fe[0] - w * logf(lam);
    fe[0] = f;
    dout[0] = f;
  }
}

__global__ __launch_bounds__(256) void permute_scale_kernel(const float* __restrict__ Z, float* __restrict__ Tn,
                                                            const float* __restrict__ invlam, int t1, int t3, int dcut)
{
  extern __shared__ float lds[];
  const int tid = threadIdx.x;
  const int bc = blockIdx.x;
  const int b = bc / dcut, c = bc % dcut;
  const float s = invlam[0];
  const int tot = dcut * t3;
  for (int idx = tid; idx < tot; idx += 256) {
    int a = idx / t3, e = idx % t3;
    lds[idx] = Z[(((long)a * t1 + b) * dcut + c) * t3 + e] * s;
  }
  __syncthreads();
  const long ob = (long)bc * t3 * dcut;
  for (int idx = tid; idx < tot; idx += 256) {
    int e = idx / dcut, a = idx % dcut;
    Tn[ob + idx] = lds[a * t3 + e];
  }
}

__global__ void init_kernel(const float* __restrict__ T0, float* __restrict__ Tdst, float* __restrict__ fe)
{
  int t = threadIdx.x;
  if (t < 16) Tdst[t] = T0[t];
  if (t == 0) fe[0] = 0.0f;
}

// ============================================================================
extern "C" void kernel_launch(void* const* d_in, const int* in_sizes, int n_in,
                              void* d_out, int out_size, void* d_ws, size_t ws_size,
                              hipStream_t stream)
{
  const float* Aflat = (const float*)d_in[0];
  const float* T0    = (const float*)d_in[1];
  float* out = (float*)d_out;
  float* W = (float*)d_ws;
  (void)ws_size; (void)in_sizes; (void)n_in; (void)out_size;

  // ---- static plan ----
  const int SH_n[12]  = {4,4,16,16,256,256,784,784,784,784,784,784};
  const int SH_d0[12] = {2,2,4,4,16,16,28,28,28,28,28,28};
  const int SH_dc[12] = {4,4,16,16,28,28,28,28,28,28,28,28};
  long aoff[12]; { long o = 0; for (int i = 0; i < 12; ++i) { aoff[i] = o; o += (long)SH_n[i]*(SH_n[i]-1)/2; } }
  long uoff[12]; { long o = 1024; for (int i = 0; i < 12; ++i) { uoff[i] = o; o += (long)SH_d0[i]*SH_d0[i]*SH_dc[i]; } }
  int T1d[12], T2d[12], T3d[12], T0d[12];
  { int a=2,b=2,c=2,d=2;
    for (int i = 0; i < 12; ++i) { T0d[i]=a; T1d[i]=b; T2d[i]=c; T3d[i]=d;
      int dc = SH_dc[i]; int na=b, nb=dc, nc=d, nd=dc; a=na; b=nb; c=nc; d=nd; } }

  // ---- workspace layout (float units) ----
  const long FE = 0, INVLAM = 1, PART = 64;
  const long TA  = 147616;                 // Tcur (614656)
  const long TB  = TA + 614656;            // Tnext
  const long ZO  = TB + 614656;            // Z
  const long X2F = ZO + 614656;            // fp32 X2 (steps 0-3) 65536
  const long TTB = X2F + 65536;            // T^T bf16, 896*896 ush = 401408 fl
  const long SCR = TTB + 401408;           // 2,458,528
  // phase-2 (steps >=4)
  const long X2B = SCR;                    // 22016*896 ush = 9,863,168 fl
  const long YB  = SCR + 9863168;          // same size
  // phase-1A (expm n=784, batch 6) -- overlaps X2B/YB (sequential phases)
  const long P_Afp = SCR;                  // 6*802816 fl
  const long P_S4  = SCR + 4816896;
  const long P_Abf = SCR + 9633792;        // bf16 buffers: 6*802816 ush = 2,408,448 fl each
  const long P_ANb = P_Abf + 2408448;
  const long P_A2b = P_ANb + 2408448;
  const long P_Qp0 = P_A2b + 2408448;
  const long P_Qp1 = P_Qp0 + 2408448;
  const long P_QTb = P_Qp1 + 2408448;
  // phase-1B (expm n=256, fp32)
  const long P_Bb  = SCR + 24084480;       // 4 bufs * 2 batch * 65536

  const float c5 = 1.0f/120.0f, c4 = 1.0f/24.0f, c3 = 1.0f/6.0f, c2 = 0.5f;

  // ================= Phase 1: U matrices =================
  {
    SmallStep4 sp;
    const int ss[4] = {0,0,1,1};
    for (int i = 0; i < 4; ++i) {
      sp.st[i].n = SH_n[i]; sp.st[i].d0 = SH_d0[i]; sp.st[i].dcut = SH_dc[i];
      sp.st[i].s = ss[i]; sp.st[i].aoff = aoff[i]; sp.st[i].uoff = uoff[i];
    }
    expm_small_kernel<<<4, 256, 0, stream>>>(Aflat, W, sp);
  }

  // ---- group A: steps 6-11, n=784 -> Np=896, batch 6, s=4, bf16 MFMA ----
  {
    const int n = 784, Np = 896, bt = 6;
    const long NN = (long)Np * Np;         // 802816 (both fl and ush strides)
    float* Af = W + P_Afp;  float* S4 = W + P_S4;
    ushort* Ab = (ushort*)(W + P_Abf);  ushort* An = (ushort*)(W + P_ANb);
    ushort* A2b = (ushort*)(W + P_A2b);
    ushort* Q0 = (ushort*)(W + P_Qp0);  ushort* Q1 = (ushort*)(W + P_Qp1);
    ushort* QT = (ushort*)(W + P_QTb);
    dim3 ge((int)((NN + 255) / 256), bt);
    build_A2<<<ge, 256, 0, stream>>>(Aflat, Af, Ab, An, n, Np, aoff[6], 306936, 1.0f/16.0f);
    dim3 g(Np/64, Np/64, bt);
    dim3 gt(Np/32, Np/32, bt);
    // A2 = A @ A   (B-role: A^T row-major = -A)
    gemm_mfma<64,64><<<g,256,0,stream>>>(Ab, An, nullptr, A2b, nullptr, 0.f, 0.f, 4, Np, Np, NN, NN, NN);
    axpy_q2<<<ge, 256, 0, stream>>>(A2b, Af, Q0, Np);
    // Horner (commuted: Q@A2 == A2@Q; A2 symmetric => self K-major)
    gemm_mfma<64,64><<<g,256,0,stream>>>(Q0, A2b, nullptr, Q1, Af, c5, c4, 5, Np, Np, NN, NN, NN);
    gemm_mfma<64,64><<<g,256,0,stream>>>(Q1, A2b, nullptr, Q0, Af, c3, c2, 5, Np, Np, NN, NN, NN);
    gemm_mfma<64,64><<<g,256,0,stream>>>(Q0, A2b, nullptr, Q1, Af, 1.f, 1.f, 5, Np, Np, NN, NN, NN);
    // 4 squarings
    trans_to_bfT<ushort><<<gt,256,0,stream>>>(Q1, QT, Np, Np, Np, Np, NN, NN);
    gemm_mfma<64,64><<<g,256,0,stream>>>(Q1, QT, nullptr, Q0, nullptr, 0.f, 0.f, 4, Np, Np, NN, NN, NN);
    trans_to_bfT<ushort><<<gt,256,0,stream>>>(Q0, QT, Np, Np, Np, Np, NN, NN);
    gemm_mfma<64,64><<<g,256,0,stream>>>(Q0, QT, nullptr, Q1, nullptr, 0.f, 0.f, 4, Np, Np, NN, NN, NN);
    trans_to_bfT<ushort><<<gt,256,0,stream>>>(Q1, QT, Np, Np, Np, Np, NN, NN);
    gemm_mfma<64,64><<<g,256,0,stream>>>(Q1, QT, nullptr, Q0, nullptr, 0.f, 0.f, 4, Np, Np, NN, NN, NN);
    trans_to_bfT<ushort><<<gt,256,0,stream>>>(Q0, QT, Np, Np, Np, Np, NN, NN);
    gemm_mfma<64,64><<<g,256,0,stream>>>(Q0, QT, S4, nullptr, nullptr, 0.f, 0.f, 2, Np, Np, NN, NN, NN);
    extract_u2<<<dim3(86, bt), 256, 0, stream>>>(S4, W, n, 28, Np, uoff[6], 21952, NN);
  }

  // ---- group B: steps 4,5 (n=256, batch 2, s=3) fp32 exact ----
  {
    const int n = 256, bt = 2; const long st = 65536; const long tri = 32640;
    float* B_as = W + P_Bb;
    float* B_a2 = W + P_Bb + 131072;
    float* B_q1 = W + P_Bb + 262144;
    float* B_q2 = W + P_Bb + 393216;
    build_A_kernel<<<dim3(256, bt), 256, 0, stream>>>(Aflat, B_as, n, aoff[4], tri, 1.0f/8.0f);
    dim3 g(4, 4, bt);
    gemm_f32<64,64,16,4,4><<<g,256,0,stream>>>(B_as, B_as, B_a2, nullptr,0,0,0, n,n,n, st,st,st,st);
    axpy_q_kernel<<<dim3(256, bt), 256, 0, stream>>>(B_a2, B_as, B_q1, n);
    gemm_f32<64,64,16,4,4><<<g,256,0,stream>>>(B_a2, B_q1, B_q2, B_as, c5, c4, 1, n,n,n, st,st,st,st);
    gemm_f32<64,64,16,4,4><<<g,256,0,stream>>>(B_a2, B_q2, B_q1, B_as, c3, c2, 1, n,n,n, st,st,st,st);
    gemm_f32<64,64,16,4,4><<<g,256,0,stream>>>(B_a2, B_q1, B_q2, B_as, 1.f, 1.f, 1, n,n,n, st,st,st,st);
    gemm_f32<64,64,16,4,4><<<g,256,0,stream>>>(B_q2, B_q2, B_q1, nullptr,0,0,0, n,n,n, st,st,st,st);
    gemm_f32<64,64,16,4,4><<<g,256,0,stream>>>(B_q1, B_q1, B_q2, nullptr,0,0,0, n,n,n, st,st,st,st);
    gemm_f32<64,64,16,4,4><<<g,256,0,stream>>>(B_q2, B_q2, B_q1, nullptr,0,0,0, n,n,n, st,st,st,st);
    extract_u2<<<dim3(28, bt), 256, 0, stream>>>(B_q1, W, n, 28, n, uoff[4], 7168, st);
  }

  // ================= Phase 2: 12 RG steps =================
  float* Tcur = W + TA;
  float* Tnext = W + TB;
  init_kernel<<<1, 256, 0, stream>>>(T0, Tcur, W + FE);

  for (int i = 0; i < 12; ++i) {
    const int t1 = T1d[i], t2 = T2d[i], t3 = T3d[i], d0 = T0d[i], dc = SH_dc[i];
    const float* U = W + uoff[i];
    const int M = t1*t2*dc, K = d0*t3, N = t2*t3;

    if (i < 4) {
      // exact fp32 path
      const int lds1 = (d0*t3 + d0*dc) * (int)sizeof(float);
      k1_kernel2<<<t1*t2, 256, lds1, stream>>>(Tcur, U, (ushort*)(W + X2B), W + X2F,
                                               t1, t2, t3, d0, dc, K, K, 1);
      dim3 g2((N + 127) / 128, (M + 127) / 128, 1);
      gemm_f32<128,128,8,8,8><<<g2, 256, 0, stream>>>(W + X2F, Tcur, (float*)(W + YB), nullptr, 0, 0, 0,
                                                      M, N, K, 0, 0, 0, 0);
      const int lds3 = (d0*t3 + d0*dc) * (int)sizeof(float);
      k3_kernel2<float><<<t1*dc, 256, lds3, stream>>>((float*)(W + YB), U, W + ZO,
                                                      t1, t2, t3, d0, dc, N);
    } else {
      const int Kp = (K == 784) ? 896 : ((K == 448) ? 512 : K);
      const int Npd = (N == 784) ? 896 : ((N == 448) ? 512 : N);
      const int lds1 = (d0*t3 + d0*dc) * (int)sizeof(float);
      k1_kernel2<<<t1*t2, 256, lds1, stream>>>(Tcur, U, (ushort*)(W + X2B), W + X2F,
                                               t1, t2, t3, d0, dc, K, Kp, 0);
      trans_to_bfT<float><<<dim3((N + 31)/32, (K + 31)/32, 1), 256, 0, stream>>>(
          Tcur, (ushort*)(W + TTB), K, N, N, Kp, 0, 0);
      if (i >= 6) {
        dim3 gg(Npd/128, 22016/128, 1);
        gemm_mfma<128,128><<<gg,256,0,stream>>>((ushort*)(W + X2B), (ushort*)(W + TTB),
                                                nullptr, (ushort*)(W + YB), nullptr, 0.f, 0.f, 4,
                                                Npd, Kp, 0, 0, 0);
      } else {
        dim3 gg(Npd/64, M/64, 1);
        gemm_mfma<64,64><<<gg,256,0,stream>>>((ushort*)(W + X2B), (ushort*)(W + TTB),
                                              nullptr, (ushort*)(W + YB), nullptr, 0.f, 0.f, 4,
                                              Npd, Kp, 0, 0, 0);
      }
      const int lds3 = (d0*t3 + d0*dc) * (int)sizeof(float);
      k3_kernel2<ushort><<<t1*dc, 256, lds3, stream>>>((ushort*)(W + YB), U, W + ZO,
                                                       t1, t2, t3, d0, dc, Npd);
    }

    const long cnt = (long)dc * t1 * dc * t3;
    redmax1_kernel<<<256, 256, 0, stream>>>(W + ZO, cnt, W + PART);
    const float w = TEMPC / (float)(1 << (i + 1));
    redmax2_kernel<<<1, 256, 0, stream>>>(W + PART, W + INVLAM, W + FE, w, out);

    permute_scale_kernel<<<t1*dc, 256, dc*t3*(int)sizeof(float), stream>>>(W + ZO, Tnext, W + INVLAM, t1, t3, dc);

    float* tmp = Tcur; Tcur = Tnext; Tnext = tmp;
  }
}

// Round 3
// 2044.948 us; speedup vs baseline: 2.7759x; 1.4586x over previous
//
#include <hip/hip_runtime.h>

// ============================================================================
// HOTRG (2D Ising) — R3: K1/K3 contraction as MFMA GEMMs + permutes.
// Step (i>=4):  Ttk = T^T(k-major, K=64)           [transTk]
//               P[(j,a),(bm,n)] = Ut1 @ Ttk        [gemm_mfma 64x64]
//               X2[(bm,a),(j,n)] = permute(P)      [permuteP]
//               Tt = T^T (for GEMM2 B)             [trans_to_bfT]
//               Y[(bma),(pe)] = X2 @ Tt            [gemm_mfma 128x128]
//               Yp[(b,a,e),(m,p)] = permute(Y)     [permuteY]
//               Z2[(b,a,e),c] = Yp @ Ut3           [gemm_mfma 64x64]
//               lam/fe, T' = permute(Z2)/lam
// expm: Taylor-8 + s=2 scaling (bf16 MFMA for n=784, fp32 for n=256/small).
// ============================================================================

#define TEMPC 2.269f

typedef unsigned int uint32;
typedef short short8b __attribute__((ext_vector_type(8)));
typedef float f32x4 __attribute__((ext_vector_type(4)));

__device__ __forceinline__ ushort f2bf(float x) {
  uint32 u = __float_as_uint(x);
  u = (u + 0x7FFFu + ((u >> 16) & 1u)) >> 16;
  return (ushort)u;
}
__device__ __forceinline__ float toF(float x) { return x; }
__device__ __forceinline__ float toF(ushort h) { return __uint_as_float(((uint32)h) << 16); }

__device__ __forceinline__ void gll16(const ushort* g, ushort* l) {
  __builtin_amdgcn_global_load_lds((const __attribute__((address_space(1))) void*)g,
                                   (__attribute__((address_space(3))) void*)l, 16, 0, 0);
}

// ---------------- MFMA GEMM: C = A @ B; A row-major [M][Kp], Bt K-major [N][Kp]
// mode: 1=add cA*Aadd + cI*I, 2=write Cf (f32), 4=write Cb (bf16). Kp % 64 == 0.
template<int BM, int BN>
__global__ __launch_bounds__(256) void gemm_mfma(
    const ushort* __restrict__ A, const ushort* __restrict__ Bt,
    float* __restrict__ Cf, ushort* __restrict__ Cb,
    const float* __restrict__ Aadd, float cA, float cI, int mode,
    int Np, int Kp, long sA, long sB, long sC)
{
  constexpr int FRM = BM / 32, FRN = BN / 32;
  constexpr int LA = BM / 8, LB = BN / 8, LPW = (LA + LB) / 4;
  __shared__ __align__(16) ushort As[BM * 64];
  __shared__ __align__(16) ushort Bs[BN * 64];
  const int tid = threadIdx.x;
  const int wid = tid >> 6, lane = tid & 63;
  const int bz = blockIdx.z;
  const int m0 = blockIdx.y * BM, n0 = blockIdx.x * BN;
  const int wm0 = (wid >> 1) * (BM / 2), wn0 = (wid & 1) * (BN / 2);
  const int rl = lane & 15, cb = lane >> 4;
  const ushort* Ap = A + (long)bz * sA + (long)m0 * Kp;
  const ushort* Bp = Bt + (long)bz * sB + (long)n0 * Kp;

  f32x4 acc[FRM][FRN];
  #pragma unroll
  for (int i = 0; i < FRM; ++i)
    #pragma unroll
    for (int j = 0; j < FRN; ++j) { acc[i][j][0]=0.f; acc[i][j][1]=0.f; acc[i][j][2]=0.f; acc[i][j][3]=0.f; }

  for (int k0 = 0; k0 < Kp; k0 += 64) {
    #pragma unroll
    for (int t = 0; t < LPW; ++t) {
      int gl = wid * LPW + t;
      int isA = gl < LA;
      int tt = isA ? gl : gl - LA;
      int li = tt * 64 + lane;
      int r = li >> 3, ch = li & 7;
      int sch = ch ^ (r & 7);
      if (isA) gll16(Ap + (long)r * Kp + k0 + sch * 8, &As[tt * 512]);
      else     gll16(Bp + (long)r * Kp + k0 + sch * 8, &Bs[tt * 512]);
    }
    __syncthreads();
    #pragma unroll
    for (int km = 0; km < 2; ++km) {
      short8b af[FRM], bfv[FRN];
      #pragma unroll
      for (int i = 0; i < FRM; ++i) {
        int r = wm0 + i * 16 + rl;
        af[i] = *(const short8b*)&As[r * 64 + ((((km << 2) | cb) ^ (r & 7)) << 3)];
      }
      #pragma unroll
      for (int j = 0; j < FRN; ++j) {
        int r = wn0 + j * 16 + rl;
        bfv[j] = *(const short8b*)&Bs[r * 64 + ((((km << 2) | cb) ^ (r & 7)) << 3)];
      }
      #pragma unroll
      for (int i = 0; i < FRM; ++i)
        #pragma unroll
        for (int j = 0; j < FRN; ++j)
          acc[i][j] = __builtin_amdgcn_mfma_f32_16x16x32_bf16(af[i], bfv[j], acc[i][j], 0, 0, 0);
    }
    __syncthreads();
  }
  const int r4 = (lane >> 4) * 4, cl = lane & 15;
  #pragma unroll
  for (int i = 0; i < FRM; ++i) {
    #pragma unroll
    for (int j = 0; j < FRN; ++j) {
      int row0 = m0 + wm0 + i * 16 + r4;
      int col  = n0 + wn0 + j * 16 + cl;
      #pragma unroll
      for (int q = 0; q < 4; ++q) {
        long off = (long)bz * sC + (long)(row0 + q) * Np + col;
        float v = acc[i][j][q];
        if (mode & 1) v += cA * Aadd[off] + ((row0 + q) == col ? cI : 0.0f);
        if (mode & 2) Cf[off] = v;
        if (mode & 4) Cb[off] = f2bf(v);
      }
    }
  }
}

// ---------------- transpose -> bf16 K-major with zero K-pad ----------------
// out[c][r] = in[r][c]; out dims [C][outStride], cols r in [R, Rpad) zeroed.
template<typename TI>
__global__ __launch_bounds__(256) void trans_to_bfT(const TI* __restrict__ in, ushort* __restrict__ out,
                                                    int R, int C, int inStride, int outStride, int Rpad,
                                                    long sIn, long sOut)
{
  __shared__ float sm[32][33];
  const TI* ip = in + (long)blockIdx.z * sIn;
  ushort* op = out + (long)blockIdx.z * sOut;
  int c0 = blockIdx.x * 32, r0 = blockIdx.y * 32;
  int lx = threadIdx.x & 31, ly = threadIdx.x >> 5;
  #pragma unroll
  for (int yy = 0; yy < 4; ++yy) {
    int r = r0 + ly + yy * 8, c = c0 + lx;
    if (r < R && c < C) sm[ly + yy * 8][lx] = toF(ip[(long)r * inStride + c]);
  }
  __syncthreads();
  #pragma unroll
  for (int yy = 0; yy < 4; ++yy) {
    int orow = c0 + ly + yy * 8;   // original col
    int ocol = r0 + lx;            // original row
    if (orow < C && ocol < Rpad) {
      ushort v = 0;
      if (ocol < R) v = f2bf(sm[lx][ly + yy * 8]);
      op[(long)orow * outStride + ocol] = v;
    }
  }
}

// ---------------- K1/K3 helper builds ----------------
// Ttk[r][ii] = T[ii][r] (bf16, 64-wide, zero pad ii>=d0)
__global__ __launch_bounds__(256) void transTk_kernel(const float* __restrict__ T, ushort* __restrict__ out,
                                                      int d0, long R)
{
  long idx = (long)blockIdx.x * 256 + threadIdx.x;
  if (idx >= R * 64) return;
  long r = idx >> 6; int ii = (int)(idx & 63);
  ushort v = 0;
  if (ii < d0) v = f2bf(T[(long)ii * R + r]);
  out[idx] = v;
}

// Ut1[(j,a)][ii] = U[ii][j][a]; rows >= d0*dc and cols >= d0 zeroed. [Mpad][64]
__global__ __launch_bounds__(256) void build_ut1(const float* __restrict__ U, ushort* __restrict__ out,
                                                 int d0, int dc, int Mpad)
{
  int idx = blockIdx.x * 256 + threadIdx.x;
  if (idx >= Mpad * 64) return;
  int ja = idx >> 6, ii = idx & 63;
  ushort v = 0;
  if (ii < d0 && ja < d0 * dc) {
    int j = ja / dc, a = ja - j * dc;
    v = f2bf(U[((long)ii * d0 + j) * dc + a]);
  }
  out[idx] = v;
}

// Ut3[c][(m,p)] = U[(m,p)][c]; rows >= dc and cols >= d0*d0 zeroed. [64][Kp3]
__global__ __launch_bounds__(256) void build_ut3(const float* __restrict__ U, ushort* __restrict__ out,
                                                 int d0, int dc, int Kp3)
{
  int idx = blockIdx.x * 256 + threadIdx.x;
  if (idx >= 64 * Kp3) return;
  int c = idx / Kp3, mp = idx - c * Kp3;
  ushort v = 0;
  if (c < dc && mp < d0 * d0) v = f2bf(U[(long)mp * dc + c]);
  out[idx] = v;
}

// X2[(bm,a)][(j,n)] = P[(j,a)][(bm,n)]; cols >= d0*t3 zeroed (to Kp2)
__global__ __launch_bounds__(256) void permuteP_kernel(const ushort* __restrict__ P, ushort* __restrict__ X2,
                                                       int t3, int d0, int dc, long Np1, int Kp2)
{
  extern __shared__ char dynsm0[];
  ushort* sP = (ushort*)dynsm0;
  const int tid = threadIdx.x;
  const int bm = blockIdx.x;
  const int JA = d0 * dc;
  for (int idx = tid; idx < JA * t3; idx += 256) {
    int ja = idx / t3, n = idx - ja * t3;
    sP[idx] = P[(long)ja * Np1 + (long)bm * t3 + n];
  }
  __syncthreads();
  const int K = d0 * t3;
  for (int idx = tid; idx < dc * Kp2; idx += 256) {
    int a = idx / Kp2, col = idx - a * Kp2;
    ushort v = 0;
    if (col < K) { int j = col / t3, n = col - j * t3; v = sP[(j * dc + a) * t3 + n]; }
    X2[((long)bm * dc + a) * Kp2 + col] = v;
  }
}

// Yp[(b,a,e)][(m,p)] = Y[(b,m,a)][(p,e)]; col pad to Kp3 zeroed; row pad zero-filled.
__global__ __launch_bounds__(256) void permuteY_kernel(const ushort* __restrict__ Y, ushort* __restrict__ Yp,
                                                       int dc, int d0, int t3, int NpdY, int Kp3,
                                                       int nWork, long rowsValid, long Mpad3)
{
  extern __shared__ char dynsm1[];
  ushort* sY = (ushort*)dynsm1;
  const int tid = threadIdx.x;
  if ((int)blockIdx.x >= nWork) {   // pad-row filler block
    long tot = (Mpad3 - rowsValid) * Kp3;
    for (long idx = tid; idx < tot; idx += 256) Yp[rowsValid * Kp3 + idx] = 0;
    return;
  }
  const int blk = blockIdx.x;
  const int b = blk / dc, a = blk - b * dc;
  const int Wd = d0 * t3;
  for (int idx = tid; idx < d0 * Wd; idx += 256) {
    int m = idx / Wd, r = idx - m * Wd;
    sY[idx] = Y[((long)(b * d0 + m) * dc + a) * NpdY + r];
  }
  __syncthreads();
  const long obase = (long)blk * t3 * Kp3;
  const int DD = d0 * d0;
  for (int idx = tid; idx < t3 * Kp3; idx += 256) {
    int e = idx / Kp3, col = idx - e * Kp3;
    ushort v = 0;
    if (col < DD) { int m = col / d0, p = col - m * d0; v = sY[m * Wd + p * t3 + e]; }
    Yp[obase + idx] = v;
  }
}

// T'[b,c,e,a] = Z2[(b,a,e)][c] * invlam   (Z2 row stride 64)
__global__ __launch_bounds__(256) void permute_scale2_kernel(const float* __restrict__ Z2, float* __restrict__ Tn,
                                                             const float* __restrict__ invlam, int dc, int t3)
{
  extern __shared__ char dynsm2[];
  float* sm2 = (float*)dynsm2;
  const int tid = threadIdx.x;
  const int blk = blockIdx.x;            // b*dc + c
  const int b = blk / dc, c = blk - b * dc;
  const float s = invlam[0];
  for (int idx = tid; idx < dc * t3; idx += 256) {
    int a = idx / t3, e = idx - a * t3;
    sm2[idx] = Z2[(((long)(b * dc + a)) * t3 + e) * 64 + c] * s;
  }
  __syncthreads();
  const long ob = (long)blk * t3 * dc;
  for (int idx = tid; idx < t3 * dc; idx += 256) {
    int e = idx / dc, a = idx - e * dc;
    Tn[ob + idx] = sm2[a * t3 + e];
  }
}

// ---------------- expm builders (n=784 bf16 path) ----------------
__global__ __launch_bounds__(256) void build_A2(const float* __restrict__ Aflat, float* __restrict__ Af,
                                                ushort* __restrict__ Ab, ushort* __restrict__ An,
                                                int n, int Np, long aoff, long tri, float sc)
{
  const int b = blockIdx.y;
  const long nn = (long)Np * Np;
  const long id = (long)blockIdx.x * 256 + threadIdx.x;
  if (id >= nn) return;
  const int r = (int)(id / Np), c = (int)(id % Np);
  float v = 0.0f;
  if (r < n && c < n) {
    if (c > r)      v =  Aflat[aoff + b * tri + (long)r * (n - 1) - (long)r * (r - 1) / 2 + (c - r - 1)] * sc;
    else if (c < r) v = -Aflat[aoff + b * tri + (long)c * (n - 1) - (long)c * (c - 1) / 2 + (r - c - 1)] * sc;
  }
  long o = b * nn + id;
  Af[o] = v; Ab[o] = f2bf(v); An[o] = f2bf(-v);
}

__global__ __launch_bounds__(256) void axpy_q2(const ushort* __restrict__ A2b, const float* __restrict__ Af,
                                               ushort* __restrict__ Qb, int Np)
{
  const int b = blockIdx.y;
  const long nn = (long)Np * Np;
  const long id = (long)blockIdx.x * 256 + threadIdx.x;
  if (id >= nn) return;
  const int r = (int)(id / Np), c = (int)(id % Np);
  long o = b * nn + id;
  float v = (1.0f/40320.0f) * toF(A2b[o]) + (1.0f/5040.0f) * Af[o] + ((r == c) ? (1.0f/720.0f) : 0.0f);
  Qb[o] = f2bf(v);
}

__global__ __launch_bounds__(256) void extract_u2(const float* __restrict__ E, float* __restrict__ W,
                                                  int n, int dcut, int rowStride, long ubase, long ustride, long estride)
{
  const int b = blockIdx.y;
  const long tot = (long)n * dcut;
  const long id = (long)blockIdx.x * 256 + threadIdx.x;
  if (id >= tot) return;
  const int rr = (int)(id / dcut), aa = (int)(id % dcut);
  W[ubase + b * ustride + id] = E[b * estride + (long)rr * rowStride + aa];
}

// ---------------- small expm (n<=16), one block per step ----------------
struct SmallStep { int n, d0, dcut, s; long aoff; long uoff; };
struct SmallStep4 { SmallStep st[4]; };

__global__ __launch_bounds__(256) void expm_small_kernel(const float* __restrict__ Aflat,
                                                         float* __restrict__ W, SmallStep4 ps)
{
  SmallStep p = ps.st[blockIdx.x];
  const int n = p.n, nn = n * n;
  __shared__ float As[256], A2[256], Qa[256], Qb[256];
  const int tid = threadIdx.x;
  const int r = (tid < nn) ? (tid / n) : 0;
  const int c = (tid < nn) ? (tid % n) : 0;
  const float sc = 1.0f / (float)(1 << p.s);
  if (tid < nn) {
    float v = 0.0f;
    if (c > r)      v =  Aflat[p.aoff + (long)r*(n-1) - (long)r*(r-1)/2 + (c - r - 1)] * sc;
    else if (c < r) v = -Aflat[p.aoff + (long)c*(n-1) - (long)c*(c-1)/2 + (r - c - 1)] * sc;
    As[tid] = v;
  }
  __syncthreads();
  if (tid < nn) {
    float s2 = 0.0f;
    for (int k = 0; k < n; ++k) s2 += As[r*n+k] * As[k*n+c];
    A2[tid] = s2;
  }
  __syncthreads();
  if (tid < nn)
    Qa[tid] = (1.0f/40320.0f)*A2[tid] + (1.0f/5040.0f)*As[tid] + ((r==c) ? (1.0f/720.0f) : 0.0f);
  __syncthreads();
  float* q = Qa; float* qn = Qb;
  const float cis[3] = {1.0f/24.0f, 0.5f, 1.0f};
  const float cas[3] = {1.0f/120.0f, 1.0f/6.0f, 1.0f};
  #pragma unroll
  for (int it = 0; it < 3; ++it) {
    if (tid < nn) {
      float s2 = 0.0f;
      for (int k = 0; k < n; ++k) s2 += A2[r*n+k] * q[k*n+c];
      qn[tid] = s2 + cas[it]*As[tid] + ((r==c) ? cis[it] : 0.0f);
    }
    __syncthreads();
    float* t = q; q = qn; qn = t;
  }
  for (int it = 0; it < p.s; ++it) {
    float s2 = 0.0f;
    if (tid < nn) { for (int k = 0; k < n; ++k) s2 += q[r*n+k] * q[k*n+c]; }
    if (tid < nn) qn[tid] = s2;
    __syncthreads();
    float* t = q; q = qn; qn = t;
  }
  if (tid < n * p.dcut) {
    int rr = tid / p.dcut, aa = tid % p.dcut;
    W[p.uoff + tid] = q[rr*n + aa];
  }
}

// ---------------- fp32 helpers (group B + steps 0-3) ----------------
__global__ __launch_bounds__(256) void build_A_kernel(const float* __restrict__ Aflat, float* __restrict__ A,
                                                      int n, long aoff, long tri, float sc)
{
  const int b = blockIdx.y;
  const long nn = (long)n * n;
  const long id = (long)blockIdx.x * 256 + threadIdx.x;
  if (id >= nn) return;
  const int r = (int)(id / n), c = (int)(id % n);
  float v = 0.0f;
  if (c > r)      v =  Aflat[aoff + b*tri + (long)r*(n-1) - (long)r*(r-1)/2 + (c - r - 1)] * sc;
  else if (c < r) v = -Aflat[aoff + b*tri + (long)c*(n-1) - (long)c*(c-1)/2 + (r - c - 1)] * sc;
  A[b*nn + id] = v;
}

__global__ __launch_bounds__(256) void axpy_q_kernel(const float* __restrict__ A2, const float* __restrict__ A,
                                                     float* __restrict__ Q, int n)
{
  const int b = blockIdx.y;
  const long nn = (long)n * n;
  const long id = (long)blockIdx.x * 256 + threadIdx.x;
  if (id >= nn) return;
  const int r = (int)(id / n), c = (int)(id % n);
  Q[b*nn + id] = (1.0f/40320.0f)*A2[b*nn + id] + (1.0f/5040.0f)*A[b*nn + id]
               + ((r==c) ? (1.0f/720.0f) : 0.0f);
}

template<int BM, int BN, int BK, int TM, int TN>
__global__ __launch_bounds__(256) void gemm_f32(
    const float* __restrict__ A, const float* __restrict__ B, float* __restrict__ C,
    const float* __restrict__ Aadd, float cA, float cI, int useEp,
    int M, int N, int K, long sA, long sB, long sC, long sAd)
{
  constexpr int PAD = 4;
  __shared__ float As[BK][BM + PAD];
  __shared__ float Bs[BK][BN + PAD];
  const int tid = threadIdx.x;
  const int bz = blockIdx.z;
  const float* Ap = A + (long)bz * sA;
  const float* Bp = B + (long)bz * sB;
  float* Cp = C + (long)bz * sC;
  const float* Adp = useEp ? (Aadd + (long)bz * sAd) : nullptr;
  const int m0 = blockIdx.y * BM, n0 = blockIdx.x * BN;
  constexpr int TX = BN / TN;
  const int tx = tid % TX, ty = tid / TX;
  float acc[TM][TN];
  #pragma unroll
  for (int i = 0; i < TM; ++i)
    #pragma unroll
    for (int j = 0; j < TN; ++j) acc[i][j] = 0.0f;

  const int a_m = tid / (BK / 4);
  const int a_k = (tid % (BK / 4)) * 4;
  const int b_k = tid / (BN / 4);
  const int b_n = (tid % (BN / 4)) * 4;

  for (int k0 = 0; k0 < K; k0 += BK) {
    float4 av = make_float4(0.f, 0.f, 0.f, 0.f);
    if (m0 + a_m < M && k0 + a_k < K)
      av = *(const float4*)(Ap + (long)(m0 + a_m) * K + k0 + a_k);
    As[a_k + 0][a_m] = av.x; As[a_k + 1][a_m] = av.y;
    As[a_k + 2][a_m] = av.z; As[a_k + 3][a_m] = av.w;
    float4 bv = make_float4(0.f, 0.f, 0.f, 0.f);
    if (k0 + b_k < K && n0 + b_n < N)
      bv = *(const float4*)(Bp + (long)(k0 + b_k) * N + n0 + b_n);
    *(float4*)&Bs[b_k][b_n] = bv;
    __syncthreads();
    #pragma unroll
    for (int kk = 0; kk < BK; ++kk) {
      float af[TM], bf[TN];
      #pragma unroll
      for (int i = 0; i < TM; i += 4) *(float4*)&af[i] = *(const float4*)&As[kk][ty*TM + i];
      #pragma unroll
      for (int j = 0; j < TN; j += 4) *(float4*)&bf[j] = *(const float4*)&Bs[kk][tx*TN + j];
      #pragma unroll
      for (int i = 0; i < TM; ++i)
        #pragma unroll
        for (int j = 0; j < TN; ++j)
          acc[i][j] = fmaf(af[i], bf[j], acc[i][j]);
    }
    __syncthreads();
  }
  #pragma unroll
  for (int i = 0; i < TM; ++i) {
    int row = m0 + ty*TM + i;
    if (row >= M) continue;
    #pragma unroll
    for (int j = 0; j < TN; ++j) {
      int col = n0 + tx*TN + j;
      if (col >= N) continue;
      float v = acc[i][j];
      if (useEp) v += cA * Adp[(long)row * N + col] + ((row == col) ? cI : 0.0f);
      Cp[(long)row * N + col] = v;
    }
  }
}

// ---------------- fp32 contraction kernels (steps 0-3 only) ----------------
__global__ __launch_bounds__(256) void k1_kernel2(const float* __restrict__ T, const float* __restrict__ U,
                                                  float* __restrict__ X2f,
                                                  int t1, int t2, int t3, int d0, int dcut, int K)
{
  extern __shared__ char dynsm3[];
  float* lds = (float*)dynsm3;
  float* Ts = lds;
  float* Us = lds + d0 * t3;
  const int tid = threadIdx.x;
  const int bm = blockIdx.x;
  const long tstride = (long)t1 * t2 * t3;
  const long tbase = (long)bm * t3;
  for (int idx = tid; idx < d0 * t3; idx += 256) {
    int i = idx / t3, nn = idx % t3;
    Ts[idx] = T[(long)i * tstride + tbase + nn];
  }
  const int nout = dcut * t3;
  __syncthreads();
  for (int j = 0; j < d0; ++j) {
    for (int idx = tid; idx < d0 * dcut; idx += 256)
      Us[idx] = U[((long)(idx / dcut) * d0 + j) * dcut + (idx % dcut)];
    __syncthreads();
    for (int idx = tid; idx < nout; idx += 256) {
      int a = idx / t3, nn = idx % t3;
      float s = 0.0f;
      for (int i = 0; i < d0; ++i) s += Ts[i*t3 + nn] * Us[i*dcut + a];
      X2f[((long)bm * dcut + a) * K + j * t3 + nn] = s;
    }
    __syncthreads();
  }
}

__global__ __launch_bounds__(256) void k3_kernel2(const float* __restrict__ Y, const float* __restrict__ U,
                                                  float* __restrict__ Z, int t1, int t2, int t3, int d0, int dcut,
                                                  int Ystride)
{
  extern __shared__ char dynsm4[];
  float* lds = (float*)dynsm4;
  float* Ys = lds;
  float* Us = lds + d0 * t3;
  const int tid = threadIdx.x;
  const int ba = blockIdx.x;
  const int b = ba / dcut, a = ba % dcut;
  const int nout = dcut * t3;
  float acc[4] = {0.f, 0.f, 0.f, 0.f};
  for (int m = 0; m < t2; ++m) {
    const long yrow = ((long)(b*t2 + m) * dcut + a) * Ystride;
    for (int idx = tid; idx < d0 * t3; idx += 256) Ys[idx] = Y[yrow + idx];
    for (int idx = tid; idx < d0 * dcut; idx += 256) Us[idx] = U[(long)m * d0 * dcut + idx];
    __syncthreads();
    #pragma unroll
    for (int o = 0; o < 4; ++o) {
      int idx = tid + o * 256;
      if (idx < nout) {
        int cc = idx / t3, e = idx % t3;
        float s = 0.0f;
        for (int p = 0; p < d0; ++p) s += Ys[p*t3 + e] * Us[p*dcut + cc];
        acc[o] += s;
      }
    }
    __syncthreads();
  }
  #pragma unroll
  for (int o = 0; o < 4; ++o) {
    int idx = tid + o * 256;
    if (idx < nout) {
      int cc = idx / t3, e = idx % t3;
      Z[(((long)a * t1 + b) * dcut + cc) * t3 + e] = acc[o];
    }
  }
}

// ---------------- reductions / permute / init ----------------
__global__ __launch_bounds__(256) void redmax1_kernel(const float* __restrict__ Z, long cnt, float* __restrict__ part)
{
  __shared__ float sm[256];
  float v = 0.0f;
  for (long i = (long)blockIdx.x * 256 + threadIdx.x; i < cnt; i += (long)gridDim.x * 256)
    v = fmaxf(v, fabsf(Z[i]));
  sm[threadIdx.x] = v; __syncthreads();
  for (int s = 128; s > 0; s >>= 1) {
    if ((int)threadIdx.x < s) sm[threadIdx.x] = fmaxf(sm[threadIdx.x], sm[threadIdx.x + s]);
    __syncthreads();
  }
  if (threadIdx.x == 0) part[blockIdx.x] = sm[0];
}

__global__ __launch_bounds__(256) void redmax2_kernel(const float* __restrict__ part, float* __restrict__ invlam,
                                                      float* __restrict__ fe, float w, float* __restrict__ dout)
{
  __shared__ float sm[256];
  sm[threadIdx.x] = part[threadIdx.x]; __syncthreads();
  for (int s = 128; s > 0; s >>= 1) {
    if ((int)threadIdx.x < s) sm[threadIdx.x] = fmaxf(sm[threadIdx.x], sm[threadIdx.x + s]);
    __syncthreads();
  }
  if (threadIdx.x == 0) {
    float lam = sm[0];
    invlam[0] = 1.0f / lam;
    float f = fe[0] - w * logf(lam);
    fe[0] = f;
    dout[0] = f;
  }
}

__global__ __launch_bounds__(256) void permute_scale_kernel(const float* __restrict__ Z, float* __restrict__ Tn,
                                                            const float* __restrict__ invlam, int t1, int t3, int dcut)
{
  extern __shared__ char dynsm5[];
  float* lds = (float*)dynsm5;
  const int tid = threadIdx.x;
  const int bc = blockIdx.x;
  const int b = bc / dcut, c = bc % dcut;
  const float s = invlam[0];
  const int tot = dcut * t3;
  for (int idx = tid; idx < tot; idx += 256) {
    int a = idx / t3, e = idx % t3;
    lds[idx] = Z[(((long)a * t1 + b) * dcut + c) * t3 + e] * s;
  }
  __syncthreads();
  const long ob = (long)bc * t3 * dcut;
  for (int idx = tid; idx < tot; idx += 256) {
    int e = idx / dcut, a = idx % dcut;
    Tn[ob + idx] = lds[a * t3 + e];
  }
}

__global__ void init_kernel(const float* __restrict__ T0, float* __restrict__ Tdst, float* __restrict__ fe)
{
  int t = threadIdx.x;
  if (t < 16) Tdst[t] = T0[t];
  if (t == 0) fe[0] = 0.0f;
}

// ============================================================================
extern "C" void kernel_launch(void* const* d_in, const int* in_sizes, int n_in,
                              void* d_out, int out_size, void* d_ws, size_t ws_size,
                              hipStream_t stream)
{
  const float* Aflat = (const float*)d_in[0];
  const float* T0    = (const float*)d_in[1];
  float* out = (float*)d_out;
  float* W = (float*)d_ws;
  (void)ws_size; (void)in_sizes; (void)n_in; (void)out_size;

  // ---- static plan ----
  const int SH_n[12]  = {4,4,16,16,256,256,784,784,784,784,784,784};
  const int SH_d0[12] = {2,2,4,4,16,16,28,28,28,28,28,28};
  const int SH_dc[12] = {4,4,16,16,28,28,28,28,28,28,28,28};
  long aoff[12]; { long o = 0; for (int i = 0; i < 12; ++i) { aoff[i] = o; o += (long)SH_n[i]*(SH_n[i]-1)/2; } }
  long uoff[12]; { long o = 1024; for (int i = 0; i < 12; ++i) { uoff[i] = o; o += (long)SH_d0[i]*SH_d0[i]*SH_dc[i]; } }
  int T1d[12], T2d[12], T3d[12], T0d[12];
  { int a=2,b=2,c=2,d=2;
    for (int i = 0; i < 12; ++i) { T0d[i]=a; T1d[i]=b; T2d[i]=c; T3d[i]=d;
      int dc = SH_dc[i]; int na=b, nb=dc, nc=d, nd=dc; a=na; b=nb; c=nc; d=nd; } }

  // ---- workspace layout (float units) ----
  const long FE = 0, INVLAM = 1, PART = 64;
  const long TA   = 150016;
  const long TB   = TA + 614656;           // 764672
  const long Z2o  = TB + 614656;           // 1379328  (1,409,024 fl: 22016x64)
  const long TTK  = Z2o + 1409024;         // 2788352  (702,464 fl: 21952x64 ush)
  const long TTo  = TTK + 702464;          // 3490816  (401,408 fl: 896x896 ush)
  const long UT1o = TTo + 401408;          // 3892224  (8 slots x 832x64 ush)
  const long UT3o = UT1o + 212992;         // 4105216  (8 slots x 64x832 ush)
  const long BIG0 = 4318208;               // 9,158,656 fl  (P / Yp)
  const long BIG1 = BIG0 + 9158656;        // 13476864 (9,863,168 fl: X2 bf16 / X2F f32)
  const long BIG2 = BIG1 + 9863168;        // 23340032 (9,863,168 fl: Y bf16 / YF f32)
  // phase-1 overlay (inside BIG0..):
  const long P_Af  = BIG0;                 // 6x802816 fl
  const long P_S4  = BIG0 + 4816896;
  const long P_bf  = BIG0 + 9633792;       // 6 bf16 bufs, each 2,408,448 fl
  const long P_Ab  = P_bf;
  const long P_An  = P_bf + 2408448;
  const long P_A2b = P_bf + 2*2408448;
  const long P_Q0  = P_bf + 3*2408448;
  const long P_Q1  = P_bf + 4*2408448;
  const long P_QT  = P_bf + 5*2408448;
  const long P_Bb  = BIG0 + 24084480;      // group B: 4 bufs x 2 batch x 65536

  const float c5 = 1.0f/120.0f, c4 = 1.0f/24.0f, c3 = 1.0f/6.0f, c2 = 0.5f;

  ushort* TTKp = (ushort*)(W + TTK);
  ushort* Ttb  = (ushort*)(W + TTo);
  ushort* UT1p = (ushort*)(W + UT1o);
  ushort* UT3p = (ushort*)(W + UT3o);
  ushort* Pb   = (ushort*)(W + BIG0);
  ushort* Ypb  = (ushort*)(W + BIG0);
  ushort* X2b  = (ushort*)(W + BIG1);
  ushort* Yb   = (ushort*)(W + BIG2);
  float*  X2F_ = W + BIG1;
  float*  YF_  = W + BIG2;
  float*  Z2f  = W + Z2o;

  // ================= Phase 1: U matrices =================
  {
    SmallStep4 sp;
    const int ss[4] = {0,0,1,1};
    for (int i = 0; i < 4; ++i) {
      sp.st[i].n = SH_n[i]; sp.st[i].d0 = SH_d0[i]; sp.st[i].dcut = SH_dc[i];
      sp.st[i].s = ss[i]; sp.st[i].aoff = aoff[i]; sp.st[i].uoff = uoff[i];
    }
    expm_small_kernel<<<4, 256, 0, stream>>>(Aflat, W, sp);
  }

  // ---- group A: steps 6-11, n=784 -> Np=896, batch 6, s=2, bf16 MFMA ----
  {
    const int n = 784, Np = 896, bt = 6;
    const long NN = (long)Np * Np;
    float* Af = W + P_Af;  float* S4 = W + P_S4;
    ushort* Ab = (ushort*)(W + P_Ab);  ushort* An = (ushort*)(W + P_An);
    ushort* A2b = (ushort*)(W + P_A2b);
    ushort* Q0 = (ushort*)(W + P_Q0);  ushort* Q1 = (ushort*)(W + P_Q1);
    ushort* QT = (ushort*)(W + P_QT);
    dim3 ge((int)((NN + 255) / 256), bt);
    build_A2<<<ge, 256, 0, stream>>>(Aflat, Af, Ab, An, n, Np, aoff[6], 306936, 0.25f);
    dim3 g(Np/64, Np/64, bt);
    dim3 gt(Np/32, Np/32, bt);
    gemm_mfma<64,64><<<g,256,0,stream>>>(Ab, An, nullptr, A2b, nullptr, 0.f, 0.f, 4, Np, Np, NN, NN, NN);
    axpy_q2<<<ge, 256, 0, stream>>>(A2b, Af, Q0, Np);
    gemm_mfma<64,64><<<g,256,0,stream>>>(Q0, A2b, nullptr, Q1, Af, c5, c4, 5, Np, Np, NN, NN, NN);
    gemm_mfma<64,64><<<g,256,0,stream>>>(Q1, A2b, nullptr, Q0, Af, c3, c2, 5, Np, Np, NN, NN, NN);
    gemm_mfma<64,64><<<g,256,0,stream>>>(Q0, A2b, nullptr, Q1, Af, 1.f, 1.f, 5, Np, Np, NN, NN, NN);
    // 2 squarings (s=2)
    trans_to_bfT<ushort><<<gt,256,0,stream>>>(Q1, QT, Np, Np, Np, Np, Np, NN, NN);
    gemm_mfma<64,64><<<g,256,0,stream>>>(Q1, QT, nullptr, Q0, nullptr, 0.f, 0.f, 4, Np, Np, NN, NN, NN);
    trans_to_bfT<ushort><<<gt,256,0,stream>>>(Q0, QT, Np, Np, Np, Np, Np, NN, NN);
    gemm_mfma<64,64><<<g,256,0,stream>>>(Q0, QT, S4, nullptr, nullptr, 0.f, 0.f, 2, Np, Np, NN, NN, NN);
    extract_u2<<<dim3(86, bt), 256, 0, stream>>>(S4, W, n, 28, Np, uoff[6], 21952, NN);
  }

  // ---- group B: steps 4,5 (n=256, batch 2, s=2) fp32 exact ----
  {
    const int n = 256, bt = 2; const long st = 65536; const long tri = 32640;
    float* B_as = W + P_Bb;
    float* B_a2 = W + P_Bb + 131072;
    float* B_q1 = W + P_Bb + 262144;
    float* B_q2 = W + P_Bb + 393216;
    build_A_kernel<<<dim3(256, bt), 256, 0, stream>>>(Aflat, B_as, n, aoff[4], tri, 0.25f);
    dim3 g(4, 4, bt);
    gemm_f32<64,64,16,4,4><<<g,256,0,stream>>>(B_as, B_as, B_a2, nullptr,0,0,0, n,n,n, st,st,st,st);
    axpy_q_kernel<<<dim3(256, bt), 256, 0, stream>>>(B_a2, B_as, B_q1, n);
    gemm_f32<64,64,16,4,4><<<g,256,0,stream>>>(B_a2, B_q1, B_q2, B_as, c5, c4, 1, n,n,n, st,st,st,st);
    gemm_f32<64,64,16,4,4><<<g,256,0,stream>>>(B_a2, B_q2, B_q1, B_as, c3, c2, 1, n,n,n, st,st,st,st);
    gemm_f32<64,64,16,4,4><<<g,256,0,stream>>>(B_a2, B_q1, B_q2, B_as, 1.f, 1.f, 1, n,n,n, st,st,st,st);
    gemm_f32<64,64,16,4,4><<<g,256,0,stream>>>(B_q2, B_q2, B_q1, nullptr,0,0,0, n,n,n, st,st,st,st);
    gemm_f32<64,64,16,4,4><<<g,256,0,stream>>>(B_q1, B_q1, B_q2, nullptr,0,0,0, n,n,n, st,st,st,st);
    extract_u2<<<dim3(28, bt), 256, 0, stream>>>(B_q2, W, n, 28, n, uoff[4], 7168, st);
  }

  // ---- U-derived operands for steps 4..11 (Ut1: [832][64], Ut3: [64][Kp3]) ----
  for (int i = 4; i < 12; ++i) {
    const int d0 = T0d[i], dc = SH_dc[i];
    const int Kp3 = (d0*d0 + 63)/64*64;
    build_ut1<<<(832*64+255)/256, 256, 0, stream>>>(W + uoff[i], UT1p + (long)(i-4)*832*64, d0, dc, 832);
    build_ut3<<<(64*Kp3+255)/256, 256, 0, stream>>>(W + uoff[i], UT3p + (long)(i-4)*64*832, d0, dc, Kp3);
  }

  // ================= Phase 2: 12 RG steps =================
  float* Tcur = W + TA;
  float* Tnext = W + TB;
  init_kernel<<<1, 256, 0, stream>>>(T0, Tcur, W + FE);

  for (int i = 0; i < 12; ++i) {
    const int t1 = T1d[i], t2 = T2d[i], t3 = T3d[i], d0 = T0d[i], dc = SH_dc[i];
    const float* U = W + uoff[i];
    const int M = t1*t2*dc, K = d0*t3, N = t2*t3;
    long redCnt;

    if (i < 4) {
      const int lds1 = (d0*t3 + d0*dc) * (int)sizeof(float);
      k1_kernel2<<<t1*t2, 256, lds1, stream>>>(Tcur, U, X2F_, t1, t2, t3, d0, dc, K);
      dim3 g2((N + 127) / 128, (M + 127) / 128, 1);
      gemm_f32<128,128,8,8,8><<<g2, 256, 0, stream>>>(X2F_, Tcur, YF_, nullptr, 0, 0, 0,
                                                      M, N, K, 0, 0, 0, 0);
      const int lds3 = (d0*t3 + d0*dc) * (int)sizeof(float);
      k3_kernel2<<<t1*dc, 256, lds3, stream>>>(YF_, U, Z2f, t1, t2, t3, d0, dc, N);
      redCnt = (long)dc * t1 * dc * t3;
    } else {
      const int Kp2 = (K == 784) ? 896 : ((K == 448) ? 512 : 256);
      const int Npd = (N == 784) ? 896 : ((N == 448) ? 512 : 256);
      const long R1 = (long)t1 * t2 * t3;              // N of P-gemm (÷64 exact)
      const int Mpad1 = (d0*dc + 63)/64*64;            // 448 or 832
      const int Kp3 = (d0*d0 + 63)/64*64;              // 256 or 832
      const long rowsV = (long)t1 * dc * t3;
      const long Mpad3 = (rowsV + 127)/128*128;        // 7168 or 22016
      const int Mpad2 = (int)((M + 127)/128*128);      // 7168 / 12544 / 22016
      const ushort* Ut1_i = UT1p + (long)(i-4)*832*64;
      const ushort* Ut3_i = UT3p + (long)(i-4)*64*832;

      // K1 = Ut1 @ T^T  -> P -> permute -> X2
      transTk_kernel<<<(int)((R1*64 + 255)/256), 256, 0, stream>>>(Tcur, TTKp, d0, R1);
      gemm_mfma<64,64><<<dim3((int)(R1/64), Mpad1/64), 256, 0, stream>>>(
          Ut1_i, TTKp, nullptr, Pb, nullptr, 0.f, 0.f, 4, (int)R1, 64, 0, 0, 0);
      permuteP_kernel<<<t1*t2, 256, d0*dc*t3*2, stream>>>(Pb, X2b, t3, d0, dc, R1, Kp2);

      // GEMM2: Y = X2 @ T^T
      trans_to_bfT<float><<<dim3((N+31)/32, (Kp2+31)/32), 256, 0, stream>>>(
          Tcur, Ttb, K, N, N, Kp2, Kp2, 0, 0);
      gemm_mfma<128,128><<<dim3(Npd/128, Mpad2/128), 256, 0, stream>>>(
          X2b, Ttb, nullptr, Yb, nullptr, 0.f, 0.f, 4, Npd, Kp2, 0, 0, 0);

      // K3: permute Y -> Yp, then Z2 = Yp @ Ut3
      const int nWork = t1*dc;
      const int nb = nWork + ((Mpad3 > rowsV) ? 1 : 0);
      permuteY_kernel<<<nb, 256, d0*d0*t3*2, stream>>>(Yb, Ypb, dc, d0, t3, Npd, Kp3,
                                                       nWork, rowsV, Mpad3);
      gemm_mfma<64,64><<<dim3(1, (int)(Mpad3/64)), 256, 0, stream>>>(
          Ypb, Ut3_i, Z2f, nullptr, nullptr, 0.f, 0.f, 2, 64, Kp3, 0, 0, 0);
      redCnt = Mpad3 * 64;
    }

    redmax1_kernel<<<256, 256, 0, stream>>>(Z2f, redCnt, W + PART);
    const float w = TEMPC / (float)(1 << (i + 1));
    redmax2_kernel<<<1, 256, 0, stream>>>(W + PART, W + INVLAM, W + FE, w, out);

    if (i < 4) {
      permute_scale_kernel<<<t1*dc, 256, dc*t3*(int)sizeof(float), stream>>>(
          Z2f, Tnext, W + INVLAM, t1, t3, dc);
    } else {
      permute_scale2_kernel<<<t1*dc, 256, dc*t3*(int)sizeof(float), stream>>>(
          Z2f, Tnext, W + INVLAM, dc, t3);
    }

    float* tmp = Tcur; Tcur = Tnext; Tnext = tmp;
  }
}

// Round 4
// 1848.783 us; speedup vs baseline: 3.0704x; 1.1061x over previous
//
#include <hip/hip_runtime.h>

// ============================================================================
// HOTRG (2D Ising) — R4: fast vectorized permutes, bf16 T-state, trimmed expm.
// ============================================================================

#define TEMPC 2.269f

typedef unsigned int uint32;
typedef short short8b __attribute__((ext_vector_type(8)));
typedef float f32x4 __attribute__((ext_vector_type(4)));
typedef unsigned short ushort8v __attribute__((ext_vector_type(8)));

__device__ __forceinline__ ushort f2bf(float x) {
  uint32 u = __float_as_uint(x);
  u = (u + 0x7FFFu + ((u >> 16) & 1u)) >> 16;
  return (ushort)u;
}
__device__ __forceinline__ float toF(float x) { return x; }
__device__ __forceinline__ float toF(ushort h) { return __uint_as_float(((uint32)h) << 16); }

__device__ __forceinline__ void gll16(const ushort* g, ushort* l) {
  __builtin_amdgcn_global_load_lds((const __attribute__((address_space(1))) void*)g,
                                   (__attribute__((address_space(3))) void*)l, 16, 0, 0);
}

// ---------------- MFMA GEMM: C = A @ B; A row-major [M][Kp], Bt K-major [N][Kp]
template<int BM, int BN>
__global__ __launch_bounds__(256) void gemm_mfma(
    const ushort* __restrict__ A, const ushort* __restrict__ Bt,
    float* __restrict__ Cf, ushort* __restrict__ Cb,
    const float* __restrict__ Aadd, float cA, float cI, int mode,
    int Np, int Kp, long sA, long sB, long sC)
{
  constexpr int FRM = BM / 32, FRN = BN / 32;
  constexpr int LA = BM / 8, LB = BN / 8, LPW = (LA + LB) / 4;
  __shared__ __align__(16) ushort As[BM * 64];
  __shared__ __align__(16) ushort Bs[BN * 64];
  const int tid = threadIdx.x;
  const int wid = tid >> 6, lane = tid & 63;
  const int bz = blockIdx.z;
  const int m0 = blockIdx.y * BM, n0 = blockIdx.x * BN;
  const int wm0 = (wid >> 1) * (BM / 2), wn0 = (wid & 1) * (BN / 2);
  const int rl = lane & 15, cb = lane >> 4;
  const ushort* Ap = A + (long)bz * sA + (long)m0 * Kp;
  const ushort* Bp = Bt + (long)bz * sB + (long)n0 * Kp;

  f32x4 acc[FRM][FRN];
  #pragma unroll
  for (int i = 0; i < FRM; ++i)
    #pragma unroll
    for (int j = 0; j < FRN; ++j) { acc[i][j][0]=0.f; acc[i][j][1]=0.f; acc[i][j][2]=0.f; acc[i][j][3]=0.f; }

  for (int k0 = 0; k0 < Kp; k0 += 64) {
    #pragma unroll
    for (int t = 0; t < LPW; ++t) {
      int gl = wid * LPW + t;
      int isA = gl < LA;
      int tt = isA ? gl : gl - LA;
      int li = tt * 64 + lane;
      int r = li >> 3, ch = li & 7;
      int sch = ch ^ (r & 7);
      if (isA) gll16(Ap + (long)r * Kp + k0 + sch * 8, &As[tt * 512]);
      else     gll16(Bp + (long)r * Kp + k0 + sch * 8, &Bs[tt * 512]);
    }
    __syncthreads();
    #pragma unroll
    for (int km = 0; km < 2; ++km) {
      short8b af[FRM], bfv[FRN];
      #pragma unroll
      for (int i = 0; i < FRM; ++i) {
        int r = wm0 + i * 16 + rl;
        af[i] = *(const short8b*)&As[r * 64 + ((((km << 2) | cb) ^ (r & 7)) << 3)];
      }
      #pragma unroll
      for (int j = 0; j < FRN; ++j) {
        int r = wn0 + j * 16 + rl;
        bfv[j] = *(const short8b*)&Bs[r * 64 + ((((km << 2) | cb) ^ (r & 7)) << 3)];
      }
      #pragma unroll
      for (int i = 0; i < FRM; ++i)
        #pragma unroll
        for (int j = 0; j < FRN; ++j)
          acc[i][j] = __builtin_amdgcn_mfma_f32_16x16x32_bf16(af[i], bfv[j], acc[i][j], 0, 0, 0);
    }
    __syncthreads();
  }
  const int r4 = (lane >> 4) * 4, cl = lane & 15;
  #pragma unroll
  for (int i = 0; i < FRM; ++i) {
    #pragma unroll
    for (int j = 0; j < FRN; ++j) {
      int row0 = m0 + wm0 + i * 16 + r4;
      int col  = n0 + wn0 + j * 16 + cl;
      #pragma unroll
      for (int q = 0; q < 4; ++q) {
        long off = (long)bz * sC + (long)(row0 + q) * Np + col;
        float v = acc[i][j][q];
        if (mode & 1) v += cA * Aadd[off] + ((row0 + q) == col ? cI : 0.0f);
        if (mode & 2) Cf[off] = v;
        if (mode & 4) Cb[off] = f2bf(v);
      }
    }
  }
}

// ---------------- transpose -> bf16 K-major with zero K-pad ----------------
template<typename TI>
__global__ __launch_bounds__(256) void trans_to_bfT(const TI* __restrict__ in, ushort* __restrict__ out,
                                                    int R, int C, int inStride, int outStride, int Rpad,
                                                    long sIn, long sOut)
{
  __shared__ float sm[32][33];
  const TI* ip = in + (long)blockIdx.z * sIn;
  ushort* op = out + (long)blockIdx.z * sOut;
  int c0 = blockIdx.x * 32, r0 = blockIdx.y * 32;
  int lx = threadIdx.x & 31, ly = threadIdx.x >> 5;
  #pragma unroll
  for (int yy = 0; yy < 4; ++yy) {
    int r = r0 + ly + yy * 8, c = c0 + lx;
    if (r < R && c < C) sm[ly + yy * 8][lx] = toF(ip[(long)r * inStride + c]);
  }
  __syncthreads();
  #pragma unroll
  for (int yy = 0; yy < 4; ++yy) {
    int orow = c0 + ly + yy * 8;
    int ocol = r0 + lx;
    if (orow < C && ocol < Rpad) {
      ushort v = 0;
      if (ocol < R) v = f2bf(sm[lx][ly + yy * 8]);
      op[(long)orow * outStride + ocol] = v;
    }
  }
}

// ---------------- K1/K3 helper builds ----------------
template<typename TT>
__global__ __launch_bounds__(256) void transTk_kernel(const TT* __restrict__ T, ushort* __restrict__ out,
                                                      int d0, long R)
{
  long idx = (long)blockIdx.x * 256 + threadIdx.x;
  if (idx >= R * 64) return;
  long r = idx >> 6; int ii = (int)(idx & 63);
  ushort v = 0;
  if (ii < d0) v = f2bf(toF(T[(long)ii * R + r]));
  out[idx] = v;
}

__global__ __launch_bounds__(256) void build_ut1(const float* __restrict__ U, ushort* __restrict__ out,
                                                 int d0, int dc, int Mpad)
{
  int idx = blockIdx.x * 256 + threadIdx.x;
  if (idx >= Mpad * 64) return;
  int ja = idx >> 6, ii = idx & 63;
  ushort v = 0;
  if (ii < d0 && ja < d0 * dc) {
    int j = ja / dc, a = ja - j * dc;
    v = f2bf(U[((long)ii * d0 + j) * dc + a]);
  }
  out[idx] = v;
}

__global__ __launch_bounds__(256) void build_ut3(const float* __restrict__ U, ushort* __restrict__ out,
                                                 int d0, int dc, int Kp3)
{
  int idx = blockIdx.x * 256 + threadIdx.x;
  if (idx >= 64 * Kp3) return;
  int c = idx / Kp3, mp = idx - c * Kp3;
  ushort v = 0;
  if (c < dc && mp < d0 * d0) v = f2bf(U[(long)mp * dc + c]);
  out[idx] = v;
}

// ---- permuteP v2: X2[bm,a | j,n] = P[j,a | bm,n]; tiled fat-transpose ----
// grid: (bm_tiles, j_tiles, a);  LDS = 16 * 16*t3 ushorts
__global__ __launch_bounds__(256) void permutePv2(const ushort* __restrict__ P, ushort* __restrict__ X2,
                                                  int t3, int d0, int dc, long R1, int Kp2)
{
  extern __shared__ char dynA[];
  ushort* sm = (ushort*)dynA;
  const int tid = threadIdx.x;
  const int bm0 = blockIdx.x * 16;
  const int j0 = blockIdx.y * 16;
  const int a = blockIdx.z;
  const int Wr = 16 * t3;
  const int nv = Wr / 8;
  for (int idx = tid; idx < 16 * nv; idx += 256) {
    int j_l = idx / nv, v = idx - j_l * nv;
    ushort8v val{};
    int j = j0 + j_l;
    if (j < d0) {
      const ushort* src = P + (long)(j * dc + a) * R1 + (long)bm0 * t3;
      val = *(const ushort8v*)(src + v * 8);
    }
    *(ushort8v*)(sm + j_l * Wr + v * 8) = val;
  }
  __syncthreads();
  for (int idx = tid; idx < 16 * Wr; idx += 256) {
    int bm_l = idx / Wr, jn = idx - bm_l * Wr;
    int j_l = jn / t3, n = jn - j_l * t3;
    long row = (long)(bm0 + bm_l) * dc + a;
    X2[row * Kp2 + (long)j0 * t3 + jn] = sm[j_l * Wr + bm_l * t3 + n];
  }
}

__global__ __launch_bounds__(256) void zeroX2pad(ushort* __restrict__ X2, long rows, int K, int Kp2)
{
  const int w = Kp2 - K;
  long id = (long)blockIdx.x * 256 + threadIdx.x;
  if (id >= rows * w) return;
  long r = id / w; int c = (int)(id - r * w);
  X2[r * Kp2 + K + c] = 0;
}

// ---- permuteY v2: Yp[(b,a,e)][(m,p)] = Y[(b,m,a)][(p,e)]; vectorized ----
__global__ __launch_bounds__(256) void permuteYv2(const ushort* __restrict__ Y, ushort* __restrict__ Yp,
                                                  int dc, int d0, int t3, int NpdY, int Kp3,
                                                  int nWork, long rowsValid, long Mpad3)
{
  extern __shared__ char dynB[];
  ushort* sY = (ushort*)dynB;
  const int tid = threadIdx.x;
  if ((int)blockIdx.x >= nWork) {
    long tot = (Mpad3 - rowsValid) * Kp3 / 8;
    ushort8v z{};
    for (long v = tid; v < tot; v += 256)
      *(ushort8v*)(Yp + rowsValid * Kp3 + v * 8) = z;
    return;
  }
  const int blk = blockIdx.x;
  const int b = blk / dc, a = blk - b * dc;
  const int Wd = d0 * t3, wv = Wd / 8;
  for (int idx = tid; idx < d0 * wv; idx += 256) {
    int m = idx / wv, v = idx - m * wv;
    *(ushort8v*)(sY + m * Wd + v * 8) =
        *(const ushort8v*)(Y + ((long)(b * d0 + m) * dc + a) * NpdY + v * 8);
  }
  __syncthreads();
  const long obase = (long)blk * t3 * Kp3;
  const int DD = d0 * d0, kv = Kp3 / 8;
  for (int idx = tid; idx < t3 * kv; idx += 256) {
    int e = idx / kv, c8 = idx - e * kv;
    int col0 = c8 * 8;
    ushort8v v{};
    #pragma unroll
    for (int k = 0; k < 8; ++k) {
      int col = col0 + k;
      if (col < DD) { int m = col / d0, p = col - m * d0; v[k] = sY[m * Wd + p * t3 + e]; }
    }
    *(ushort8v*)(Yp + obase + (long)e * Kp3 + col0) = v;
  }
}

// ---- T'[b,c,e,a] (bf16) = Z2[(b,a,e)][c] * invlam; one block per b ----
__global__ __launch_bounds__(256) void permute_scale2b(const float* __restrict__ Z2, ushort* __restrict__ Tn,
                                                       const float* __restrict__ invlam, int dc, int t3)
{
  extern __shared__ char dynC[];
  ushort* sm = (ushort*)dynC;
  const int b = blockIdx.x;
  const int tid = threadIdx.x;
  const float s = invlam[0];
  const int tot = dc * t3 * dc;
  const int TD = t3 * dc;
  for (int idx = tid; idx < tot; idx += 256) {
    int a = idx / TD; int rem = idx - a * TD;
    int e = rem / dc; int c = rem - e * dc;
    float v = Z2[(((long)(b * dc + a)) * t3 + e) * 64 + c] * s;
    sm[(c * t3 + e) * dc + a] = f2bf(v);
  }
  __syncthreads();
  const long ob = (long)b * tot;
  for (int idx = tid; idx < tot / 8; idx += 256)
    *(ushort8v*)(Tn + ob + idx * 8) = *(ushort8v*)(sm + idx * 8);
}

// ---------------- expm builders (n=784 bf16 path) ----------------
__global__ __launch_bounds__(256) void build_A2(const float* __restrict__ Aflat, float* __restrict__ Af,
                                                ushort* __restrict__ Ab, ushort* __restrict__ An,
                                                int n, int Np, long aoff, long tri, float sc)
{
  const int b = blockIdx.y;
  const long nn = (long)Np * Np;
  const long id = (long)blockIdx.x * 256 + threadIdx.x;
  if (id >= nn) return;
  const int r = (int)(id / Np), c = (int)(id % Np);
  float v = 0.0f;
  if (r < n && c < n) {
    if (c > r)      v =  Aflat[aoff + b * tri + (long)r * (n - 1) - (long)r * (r - 1) / 2 + (c - r - 1)] * sc;
    else if (c < r) v = -Aflat[aoff + b * tri + (long)c * (n - 1) - (long)c * (c - 1) / 2 + (r - c - 1)] * sc;
  }
  long o = b * nn + id;
  Af[o] = v; Ab[o] = f2bf(v); An[o] = f2bf(-v);
}

__global__ __launch_bounds__(256) void axpy_q2(const ushort* __restrict__ A2b, const float* __restrict__ Af,
                                               ushort* __restrict__ Qb, int Np)
{
  const int b = blockIdx.y;
  const long nn = (long)Np * Np;
  const long id = (long)blockIdx.x * 256 + threadIdx.x;
  if (id >= nn) return;
  const int r = (int)(id / Np), c = (int)(id % Np);
  long o = b * nn + id;
  float v = (1.0f/40320.0f) * toF(A2b[o]) + (1.0f/5040.0f) * Af[o] + ((r == c) ? (1.0f/720.0f) : 0.0f);
  Qb[o] = f2bf(v);
}

__global__ __launch_bounds__(256) void extract_u2(const float* __restrict__ E, float* __restrict__ W,
                                                  int n, int dcut, int rowStride, long ubase, long ustride, long estride)
{
  const int b = blockIdx.y;
  const long tot = (long)n * dcut;
  const long id = (long)blockIdx.x * 256 + threadIdx.x;
  if (id >= tot) return;
  const int rr = (int)(id / dcut), aa = (int)(id % dcut);
  W[ubase + b * ustride + id] = E[b * estride + (long)rr * rowStride + aa];
}

// ---------------- small expm (n<=16) ----------------
struct SmallStep { int n, d0, dcut, s; long aoff; long uoff; };
struct SmallStep4 { SmallStep st[4]; };

__global__ __launch_bounds__(256) void expm_small_kernel(const float* __restrict__ Aflat,
                                                         float* __restrict__ W, SmallStep4 ps)
{
  SmallStep p = ps.st[blockIdx.x];
  const int n = p.n, nn = n * n;
  __shared__ float As[256], A2[256], Qa[256], Qb[256];
  const int tid = threadIdx.x;
  const int r = (tid < nn) ? (tid / n) : 0;
  const int c = (tid < nn) ? (tid % n) : 0;
  const float sc = 1.0f / (float)(1 << p.s);
  if (tid < nn) {
    float v = 0.0f;
    if (c > r)      v =  Aflat[p.aoff + (long)r*(n-1) - (long)r*(r-1)/2 + (c - r - 1)] * sc;
    else if (c < r) v = -Aflat[p.aoff + (long)c*(n-1) - (long)c*(c-1)/2 + (r - c - 1)] * sc;
    As[tid] = v;
  }
  __syncthreads();
  if (tid < nn) {
    float s2 = 0.0f;
    for (int k = 0; k < n; ++k) s2 += As[r*n+k] * As[k*n+c];
    A2[tid] = s2;
  }
  __syncthreads();
  if (tid < nn)
    Qa[tid] = (1.0f/40320.0f)*A2[tid] + (1.0f/5040.0f)*As[tid] + ((r==c) ? (1.0f/720.0f) : 0.0f);
  __syncthreads();
  float* q = Qa; float* qn = Qb;
  const float cis[3] = {1.0f/24.0f, 0.5f, 1.0f};
  const float cas[3] = {1.0f/120.0f, 1.0f/6.0f, 1.0f};
  #pragma unroll
  for (int it = 0; it < 3; ++it) {
    if (tid < nn) {
      float s2 = 0.0f;
      for (int k = 0; k < n; ++k) s2 += A2[r*n+k] * q[k*n+c];
      qn[tid] = s2 + cas[it]*As[tid] + ((r==c) ? cis[it] : 0.0f);
    }
    __syncthreads();
    float* t = q; q = qn; qn = t;
  }
  for (int it = 0; it < p.s; ++it) {
    float s2 = 0.0f;
    if (tid < nn) { for (int k = 0; k < n; ++k) s2 += q[r*n+k] * q[k*n+c]; }
    if (tid < nn) qn[tid] = s2;
    __syncthreads();
    float* t = q; q = qn; qn = t;
  }
  if (tid < n * p.dcut) {
    int rr = tid / p.dcut, aa = tid % p.dcut;
    W[p.uoff + tid] = q[rr*n + aa];
  }
}

// ---------------- fp32 helpers (group B + steps 0-3) ----------------
__global__ __launch_bounds__(256) void build_A_kernel(const float* __restrict__ Aflat, float* __restrict__ A,
                                                      int n, long aoff, long tri, float sc)
{
  const int b = blockIdx.y;
  const long nn = (long)n * n;
  const long id = (long)blockIdx.x * 256 + threadIdx.x;
  if (id >= nn) return;
  const int r = (int)(id / n), c = (int)(id % n);
  float v = 0.0f;
  if (c > r)      v =  Aflat[aoff + b*tri + (long)r*(n-1) - (long)r*(r-1)/2 + (c - r - 1)] * sc;
  else if (c < r) v = -Aflat[aoff + b*tri + (long)c*(n-1) - (long)c*(c-1)/2 + (r - c - 1)] * sc;
  A[b*nn + id] = v;
}

__global__ __launch_bounds__(256) void axpy_q_kernel(const float* __restrict__ A2, const float* __restrict__ A,
                                                     float* __restrict__ Q, int n)
{
  const int b = blockIdx.y;
  const long nn = (long)n * n;
  const long id = (long)blockIdx.x * 256 + threadIdx.x;
  if (id >= nn) return;
  const int r = (int)(id / n), c = (int)(id % n);
  Q[b*nn + id] = (1.0f/40320.0f)*A2[b*nn + id] + (1.0f/5040.0f)*A[b*nn + id]
               + ((r==c) ? (1.0f/720.0f) : 0.0f);
}

template<int BM, int BN, int BK, int TM, int TN>
__global__ __launch_bounds__(256) void gemm_f32(
    const float* __restrict__ A, const float* __restrict__ B, float* __restrict__ C,
    const float* __restrict__ Aadd, float cA, float cI, int useEp,
    int M, int N, int K, long sA, long sB, long sC, long sAd)
{
  constexpr int PAD = 4;
  __shared__ float As[BK][BM + PAD];
  __shared__ float Bs[BK][BN + PAD];
  const int tid = threadIdx.x;
  const int bz = blockIdx.z;
  const float* Ap = A + (long)bz * sA;
  const float* Bp = B + (long)bz * sB;
  float* Cp = C + (long)bz * sC;
  const float* Adp = useEp ? (Aadd + (long)bz * sAd) : nullptr;
  const int m0 = blockIdx.y * BM, n0 = blockIdx.x * BN;
  constexpr int TX = BN / TN;
  const int tx = tid % TX, ty = tid / TX;
  float acc[TM][TN];
  #pragma unroll
  for (int i = 0; i < TM; ++i)
    #pragma unroll
    for (int j = 0; j < TN; ++j) acc[i][j] = 0.0f;

  const int a_m = tid / (BK / 4);
  const int a_k = (tid % (BK / 4)) * 4;
  const int b_k = tid / (BN / 4);
  const int b_n = (tid % (BN / 4)) * 4;

  for (int k0 = 0; k0 < K; k0 += BK) {
    float4 av = make_float4(0.f, 0.f, 0.f, 0.f);
    if (m0 + a_m < M && k0 + a_k < K)
      av = *(const float4*)(Ap + (long)(m0 + a_m) * K + k0 + a_k);
    As[a_k + 0][a_m] = av.x; As[a_k + 1][a_m] = av.y;
    As[a_k + 2][a_m] = av.z; As[a_k + 3][a_m] = av.w;
    float4 bv = make_float4(0.f, 0.f, 0.f, 0.f);
    if (k0 + b_k < K && n0 + b_n < N)
      bv = *(const float4*)(Bp + (long)(k0 + b_k) * N + n0 + b_n);
    *(float4*)&Bs[b_k][b_n] = bv;
    __syncthreads();
    #pragma unroll
    for (int kk = 0; kk < BK; ++kk) {
      float af[TM], bf[TN];
      #pragma unroll
      for (int i = 0; i < TM; i += 4) *(float4*)&af[i] = *(const float4*)&As[kk][ty*TM + i];
      #pragma unroll
      for (int j = 0; j < TN; j += 4) *(float4*)&bf[j] = *(const float4*)&Bs[kk][tx*TN + j];
      #pragma unroll
      for (int i = 0; i < TM; ++i)
        #pragma unroll
        for (int j = 0; j < TN; ++j)
          acc[i][j] = fmaf(af[i], bf[j], acc[i][j]);
    }
    __syncthreads();
  }
  #pragma unroll
  for (int i = 0; i < TM; ++i) {
    int row = m0 + ty*TM + i;
    if (row >= M) continue;
    #pragma unroll
    for (int j = 0; j < TN; ++j) {
      int col = n0 + tx*TN + j;
      if (col >= N) continue;
      float v = acc[i][j];
      if (useEp) v += cA * Adp[(long)row * N + col] + ((row == col) ? cI : 0.0f);
      Cp[(long)row * N + col] = v;
    }
  }
}

// ---------------- fp32 contraction kernels (steps 0-3 only) ----------------
__global__ __launch_bounds__(256) void k1_kernel2(const float* __restrict__ T, const float* __restrict__ U,
                                                  float* __restrict__ X2f,
                                                  int t1, int t2, int t3, int d0, int dcut, int K)
{
  extern __shared__ char dyn3[];
  float* lds = (float*)dyn3;
  float* Ts = lds;
  float* Us = lds + d0 * t3;
  const int tid = threadIdx.x;
  const int bm = blockIdx.x;
  const long tstride = (long)t1 * t2 * t3;
  const long tbase = (long)bm * t3;
  for (int idx = tid; idx < d0 * t3; idx += 256) {
    int i = idx / t3, nn = idx % t3;
    Ts[idx] = T[(long)i * tstride + tbase + nn];
  }
  const int nout = dcut * t3;
  __syncthreads();
  for (int j = 0; j < d0; ++j) {
    for (int idx = tid; idx < d0 * dcut; idx += 256)
      Us[idx] = U[((long)(idx / dcut) * d0 + j) * dcut + (idx % dcut)];
    __syncthreads();
    for (int idx = tid; idx < nout; idx += 256) {
      int a = idx / t3, nn = idx % t3;
      float s = 0.0f;
      for (int i = 0; i < d0; ++i) s += Ts[i*t3 + nn] * Us[i*dcut + a];
      X2f[((long)bm * dcut + a) * K + j * t3 + nn] = s;
    }
    __syncthreads();
  }
}

__global__ __launch_bounds__(256) void k3_kernel2(const float* __restrict__ Y, const float* __restrict__ U,
                                                  float* __restrict__ Z, int t1, int t2, int t3, int d0, int dcut,
                                                  int Ystride)
{
  extern __shared__ char dyn4[];
  float* lds = (float*)dyn4;
  float* Ys = lds;
  float* Us = lds + d0 * t3;
  const int tid = threadIdx.x;
  const int ba = blockIdx.x;
  const int b = ba / dcut, a = ba % dcut;
  const int nout = dcut * t3;
  float acc[4] = {0.f, 0.f, 0.f, 0.f};
  for (int m = 0; m < t2; ++m) {
    const long yrow = ((long)(b*t2 + m) * dcut + a) * Ystride;
    for (int idx = tid; idx < d0 * t3; idx += 256) Ys[idx] = Y[yrow + idx];
    for (int idx = tid; idx < d0 * dcut; idx += 256) Us[idx] = U[(long)m * d0 * dcut + idx];
    __syncthreads();
    #pragma unroll
    for (int o = 0; o < 4; ++o) {
      int idx = tid + o * 256;
      if (idx < nout) {
        int cc = idx / t3, e = idx % t3;
        float s = 0.0f;
        for (int p = 0; p < d0; ++p) s += Ys[p*t3 + e] * Us[p*dcut + cc];
        acc[o] += s;
      }
    }
    __syncthreads();
  }
  #pragma unroll
  for (int o = 0; o < 4; ++o) {
    int idx = tid + o * 256;
    if (idx < nout) {
      int cc = idx / t3, e = idx % t3;
      Z[(((long)a * t1 + b) * dcut + cc) * t3 + e] = acc[o];
    }
  }
}

// ---------------- reductions / permute / init ----------------
__global__ __launch_bounds__(256) void redmax1_kernel(const float* __restrict__ Z, long cnt, float* __restrict__ part)
{
  __shared__ float sm[256];
  float v = 0.0f;
  for (long i = (long)blockIdx.x * 256 + threadIdx.x; i < cnt; i += (long)gridDim.x * 256)
    v = fmaxf(v, fabsf(Z[i]));
  sm[threadIdx.x] = v; __syncthreads();
  for (int s = 128; s > 0; s >>= 1) {
    if ((int)threadIdx.x < s) sm[threadIdx.x] = fmaxf(sm[threadIdx.x], sm[threadIdx.x + s]);
    __syncthreads();
  }
  if (threadIdx.x == 0) part[blockIdx.x] = sm[0];
}

__global__ __launch_bounds__(256) void redmax2_kernel(const float* __restrict__ part, float* __restrict__ invlam,
                                                      float* __restrict__ fe, float w, float* __restrict__ dout)
{
  __shared__ float sm[256];
  sm[threadIdx.x] = part[threadIdx.x]; __syncthreads();
  for (int s = 128; s > 0; s >>= 1) {
    if ((int)threadIdx.x < s) sm[threadIdx.x] = fmaxf(sm[threadIdx.x], sm[threadIdx.x + s]);
    __syncthreads();
  }
  if (threadIdx.x == 0) {
    float lam = sm[0];
    invlam[0] = 1.0f / lam;
    float f = fe[0] - w * logf(lam);
    fe[0] = f;
    dout[0] = f;
  }
}

__global__ __launch_bounds__(256) void permute_scale_kernel(const float* __restrict__ Z, float* __restrict__ Tn,
                                                            const float* __restrict__ invlam, int t1, int t3, int dcut)
{
  extern __shared__ char dyn5[];
  float* lds = (float*)dyn5;
  const int tid = threadIdx.x;
  const int bc = blockIdx.x;
  const int b = bc / dcut, c = bc % dcut;
  const float s = invlam[0];
  const int tot = dcut * t3;
  for (int idx = tid; idx < tot; idx += 256) {
    int a = idx / t3, e = idx % t3;
    lds[idx] = Z[(((long)a * t1 + b) * dcut + c) * t3 + e] * s;
  }
  __syncthreads();
  const long ob = (long)bc * t3 * dcut;
  for (int idx = tid; idx < tot; idx += 256) {
    int e = idx / dcut, a = idx % dcut;
    Tn[ob + idx] = lds[a * t3 + e];
  }
}

__global__ void init_kernel(const float* __restrict__ T0, float* __restrict__ Tdst, float* __restrict__ fe)
{
  int t = threadIdx.x;
  if (t < 16) Tdst[t] = T0[t];
  if (t == 0) fe[0] = 0.0f;
}

// ============================================================================
extern "C" void kernel_launch(void* const* d_in, const int* in_sizes, int n_in,
                              void* d_out, int out_size, void* d_ws, size_t ws_size,
                              hipStream_t stream)
{
  const float* Aflat = (const float*)d_in[0];
  const float* T0    = (const float*)d_in[1];
  float* out = (float*)d_out;
  float* W = (float*)d_ws;
  (void)ws_size; (void)in_sizes; (void)n_in; (void)out_size;

  const int SH_n[12]  = {4,4,16,16,256,256,784,784,784,784,784,784};
  const int SH_d0[12] = {2,2,4,4,16,16,28,28,28,28,28,28};
  const int SH_dc[12] = {4,4,16,16,28,28,28,28,28,28,28,28};
  long aoff[12]; { long o = 0; for (int i = 0; i < 12; ++i) { aoff[i] = o; o += (long)SH_n[i]*(SH_n[i]-1)/2; } }
  long uoff[12]; { long o = 1024; for (int i = 0; i < 12; ++i) { uoff[i] = o; o += (long)SH_d0[i]*SH_d0[i]*SH_dc[i]; } }
  int T1d[12], T2d[12], T3d[12], T0d[12];
  { int a=2,b=2,c=2,d=2;
    for (int i = 0; i < 12; ++i) { T0d[i]=a; T1d[i]=b; T2d[i]=c; T3d[i]=d;
      int dc = SH_dc[i]; int na=b, nb=dc, nc=d, nd=dc; a=na; b=nb; c=nc; d=nd; } }

  const long FE = 0, INVLAM = 1, PART = 64;
  const long TA   = 150016;
  const long TB   = TA + 614656;
  const long Z2o  = TB + 614656;           // 22016x64 f32
  const long TTK  = Z2o + 1409024;         // 21952x64 ush
  const long TTo  = TTK + 702464;          // 896x896 ush
  const long UT1o = TTo + 401408;
  const long UT3o = UT1o + 212992;
  const long BIG0 = 4318208;               // P / Yp
  const long BIG1 = BIG0 + 9158656;        // X2
  const long BIG2 = BIG1 + 9863168;        // Y
  const long P_Af  = BIG0;
  const long P_S4  = BIG0 + 4816896;       // 6 x 896x64 f32 (trimmed)
  const long P_bf  = BIG0 + 9633792;
  const long P_Ab  = P_bf;
  const long P_An  = P_bf + 2408448;
  const long P_A2b = P_bf + 2*2408448;
  const long P_Q0  = P_bf + 3*2408448;
  const long P_Q1  = P_bf + 4*2408448;
  const long P_QT  = P_bf + 5*2408448;
  const long P_Bb  = BIG0 + 24084480;

  const float c5 = 1.0f/120.0f, c4 = 1.0f/24.0f, c3 = 1.0f/6.0f, c2 = 0.5f;

  ushort* TTKp = (ushort*)(W + TTK);
  ushort* Ttb  = (ushort*)(W + TTo);
  ushort* UT1p = (ushort*)(W + UT1o);
  ushort* UT3p = (ushort*)(W + UT3o);
  ushort* Pb   = (ushort*)(W + BIG0);
  ushort* Ypb  = (ushort*)(W + BIG0);
  ushort* X2b  = (ushort*)(W + BIG1);
  ushort* Yb   = (ushort*)(W + BIG2);
  float*  X2F_ = W + BIG1;
  float*  YF_  = W + BIG2;
  float*  Z2f  = W + Z2o;

  // ================= Phase 1: U matrices =================
  {
    SmallStep4 sp;
    const int ss[4] = {0,0,1,1};
    for (int i = 0; i < 4; ++i) {
      sp.st[i].n = SH_n[i]; sp.st[i].d0 = SH_d0[i]; sp.st[i].dcut = SH_dc[i];
      sp.st[i].s = ss[i]; sp.st[i].aoff = aoff[i]; sp.st[i].uoff = uoff[i];
    }
    expm_small_kernel<<<4, 256, 0, stream>>>(Aflat, W, sp);
  }

  // ---- group A: steps 6-11 (n=784 -> Np=896, batch 6, s=2, Taylor-8) ----
  {
    const int n = 784, Np = 896, bt = 6;
    const long NN = (long)Np * Np;
    float* Af = W + P_Af;  float* S4 = W + P_S4;
    ushort* Ab = (ushort*)(W + P_Ab);  ushort* An = (ushort*)(W + P_An);
    ushort* A2b = (ushort*)(W + P_A2b);
    ushort* Q0 = (ushort*)(W + P_Q0);  ushort* Q1 = (ushort*)(W + P_Q1);
    ushort* QT = (ushort*)(W + P_QT);
    dim3 ge((int)((NN + 255) / 256), bt);
    build_A2<<<ge, 256, 0, stream>>>(Aflat, Af, Ab, An, n, Np, aoff[6], 306936, 0.25f);
    dim3 g(Np/64, Np/64, bt);
    dim3 gt(Np/32, Np/32, bt);
    gemm_mfma<64,64><<<g,256,0,stream>>>(Ab, An, nullptr, A2b, nullptr, 0.f, 0.f, 4, Np, Np, NN, NN, NN);
    axpy_q2<<<ge, 256, 0, stream>>>(A2b, Af, Q0, Np);
    gemm_mfma<64,64><<<g,256,0,stream>>>(Q0, A2b, nullptr, Q1, Af, c5, c4, 5, Np, Np, NN, NN, NN);
    gemm_mfma<64,64><<<g,256,0,stream>>>(Q1, A2b, nullptr, Q0, Af, c3, c2, 5, Np, Np, NN, NN, NN);
    gemm_mfma<64,64><<<g,256,0,stream>>>(Q0, A2b, nullptr, Q1, Af, 1.f, 1.f, 5, Np, Np, NN, NN, NN);
    // squaring 1 (full)
    trans_to_bfT<ushort><<<gt,256,0,stream>>>(Q1, QT, Np, Np, Np, Np, Np, NN, NN);
    gemm_mfma<64,64><<<g,256,0,stream>>>(Q1, QT, nullptr, Q0, nullptr, 0.f, 0.f, 4, Np, Np, NN, NN, NN);
    // squaring 2 (only first 64 columns needed)
    trans_to_bfT<ushort><<<dim3(2, Np/32, bt),256,0,stream>>>(Q0, QT, Np, 64, Np, Np, Np, NN, NN);
    gemm_mfma<64,64><<<dim3(1, Np/64, bt),256,0,stream>>>(Q0, QT, S4, nullptr, nullptr, 0.f, 0.f, 2,
                                                          64, Np, NN, NN, 57344);
    extract_u2<<<dim3(86, bt), 256, 0, stream>>>(S4, W, n, 28, 64, uoff[6], 21952, 57344);
  }

  // ---- group B: steps 4,5 (n=256, batch 2, s=2) fp32 exact ----
  {
    const int n = 256, bt = 2; const long st = 65536; const long tri = 32640;
    float* B_as = W + P_Bb;
    float* B_a2 = W + P_Bb + 131072;
    float* B_q1 = W + P_Bb + 262144;
    float* B_q2 = W + P_Bb + 393216;
    build_A_kernel<<<dim3(256, bt), 256, 0, stream>>>(Aflat, B_as, n, aoff[4], tri, 0.25f);
    dim3 g(4, 4, bt);
    gemm_f32<64,64,16,4,4><<<g,256,0,stream>>>(B_as, B_as, B_a2, nullptr,0,0,0, n,n,n, st,st,st,st);
    axpy_q_kernel<<<dim3(256, bt), 256, 0, stream>>>(B_a2, B_as, B_q1, n);
    gemm_f32<64,64,16,4,4><<<g,256,0,stream>>>(B_a2, B_q1, B_q2, B_as, c5, c4, 1, n,n,n, st,st,st,st);
    gemm_f32<64,64,16,4,4><<<g,256,0,stream>>>(B_a2, B_q2, B_q1, B_as, c3, c2, 1, n,n,n, st,st,st,st);
    gemm_f32<64,64,16,4,4><<<g,256,0,stream>>>(B_a2, B_q1, B_q2, B_as, 1.f, 1.f, 1, n,n,n, st,st,st,st);
    gemm_f32<64,64,16,4,4><<<g,256,0,stream>>>(B_q2, B_q2, B_q1, nullptr,0,0,0, n,n,n, st,st,st,st);
    gemm_f32<64,64,16,4,4><<<g,256,0,stream>>>(B_q1, B_q1, B_q2, nullptr,0,0,0, n,n,n, st,st,st,st);
    extract_u2<<<dim3(28, bt), 256, 0, stream>>>(B_q2, W, n, 28, n, uoff[4], 7168, st);
  }

  // ---- U-derived operands for steps 4..11 ----
  for (int i = 4; i < 12; ++i) {
    const int d0 = T0d[i], dc = SH_dc[i];
    const int Kp3 = (d0*d0 + 63)/64*64;
    build_ut1<<<(832*64+255)/256, 256, 0, stream>>>(W + uoff[i], UT1p + (long)(i-4)*832*64, d0, dc, 832);
    build_ut3<<<(64*Kp3+255)/256, 256, 0, stream>>>(W + uoff[i], UT3p + (long)(i-4)*64*832, d0, dc, Kp3);
  }

  // ================= Phase 2: 12 RG steps =================
  float* Tcur = W + TA;
  float* Tnext = W + TB;
  init_kernel<<<1, 256, 0, stream>>>(T0, Tcur, W + FE);

  for (int i = 0; i < 12; ++i) {
    const int t1 = T1d[i], t2 = T2d[i], t3 = T3d[i], d0 = T0d[i], dc = SH_dc[i];
    const float* U = W + uoff[i];
    const int M = t1*t2*dc, K = d0*t3, N = t2*t3;
    long redCnt;

    if (i < 4) {
      const int lds1 = (d0*t3 + d0*dc) * (int)sizeof(float);
      k1_kernel2<<<t1*t2, 256, lds1, stream>>>(Tcur, U, X2F_, t1, t2, t3, d0, dc, K);
      dim3 g2((N + 127) / 128, (M + 127) / 128, 1);
      gemm_f32<128,128,8,8,8><<<g2, 256, 0, stream>>>(X2F_, Tcur, YF_, nullptr, 0, 0, 0,
                                                      M, N, K, 0, 0, 0, 0);
      const int lds3 = (d0*t3 + d0*dc) * (int)sizeof(float);
      k3_kernel2<<<t1*dc, 256, lds3, stream>>>(YF_, U, Z2f, t1, t2, t3, d0, dc, N);
      redCnt = (long)dc * t1 * dc * t3;
    } else {
      const bool inBf = (i >= 5);                      // Tcur dtype
      const int Kp2 = (K == 784) ? 896 : ((K == 448) ? 512 : 256);
      const int Npd = (N == 784) ? 896 : ((N == 448) ? 512 : 256);
      const long R1 = (long)t1 * t2 * t3;
      const int Mpad1 = (d0*dc + 63)/64*64;
      const int Kp3 = (d0*d0 + 63)/64*64;
      const long rowsV = (long)t1 * dc * t3;
      const long Mpad3 = (rowsV + 127)/128*128;
      const int Mpad2 = (int)((M + 127)/128*128);
      const ushort* Ut1_i = UT1p + (long)(i-4)*832*64;
      const ushort* Ut3_i = UT3p + (long)(i-4)*64*832;

      // K1 = Ut1 @ T^T -> P -> tiled fat-transpose -> X2
      if (inBf) transTk_kernel<ushort><<<(int)((R1*64 + 255)/256), 256, 0, stream>>>(
          (const ushort*)Tcur, TTKp, d0, R1);
      else      transTk_kernel<float><<<(int)((R1*64 + 255)/256), 256, 0, stream>>>(
          Tcur, TTKp, d0, R1);
      gemm_mfma<64,64><<<dim3((int)(R1/64), Mpad1/64), 256, 0, stream>>>(
          Ut1_i, TTKp, nullptr, Pb, nullptr, 0.f, 0.f, 4, (int)R1, 64, 0, 0, 0);
      {
        int bmt = (t1*t2)/16, jt = (d0 + 15)/16;
        permutePv2<<<dim3(bmt, jt, dc), 256, 16*16*t3*2, stream>>>(Pb, X2b, t3, d0, dc, R1, Kp2);
        if (K < Kp2)
          zeroX2pad<<<(int)(((long)Mpad2*(Kp2-K) + 255)/256), 256, 0, stream>>>(X2b, Mpad2, K, Kp2);
      }

      // GEMM2: Y = X2 @ T^T
      if (inBf) trans_to_bfT<ushort><<<dim3((N+31)/32, (Kp2+31)/32), 256, 0, stream>>>(
          (const ushort*)Tcur, Ttb, K, N, N, Kp2, Kp2, 0, 0);
      else      trans_to_bfT<float><<<dim3((N+31)/32, (Kp2+31)/32), 256, 0, stream>>>(
          Tcur, Ttb, K, N, N, Kp2, Kp2, 0, 0);
      gemm_mfma<128,128><<<dim3(Npd/128, Mpad2/128), 256, 0, stream>>>(
          X2b, Ttb, nullptr, Yb, nullptr, 0.f, 0.f, 4, Npd, Kp2, 0, 0, 0);

      // K3: permute Y -> Yp, Z2 = Yp @ Ut3
      const int nWork = t1*dc;
      const int nb = nWork + ((Mpad3 > rowsV) ? 1 : 0);
      permuteYv2<<<nb, 256, d0*d0*t3*2, stream>>>(Yb, Ypb, dc, d0, t3, Npd, Kp3,
                                                  nWork, rowsV, Mpad3);
      gemm_mfma<64,64><<<dim3(1, (int)(Mpad3/64)), 256, 0, stream>>>(
          Ypb, Ut3_i, Z2f, nullptr, nullptr, 0.f, 0.f, 2, 64, Kp3, 0, 0, 0);
      redCnt = Mpad3 * 64;
    }

    redmax1_kernel<<<256, 256, 0, stream>>>(Z2f, redCnt, W + PART);
    const float w = TEMPC / (float)(1 << (i + 1));
    redmax2_kernel<<<1, 256, 0, stream>>>(W + PART, W + INVLAM, W + FE, w, out);

    if (i < 4) {
      permute_scale_kernel<<<t1*dc, 256, dc*t3*(int)sizeof(float), stream>>>(
          Z2f, Tnext, W + INVLAM, t1, t3, dc);
    } else {
      permute_scale2b<<<t1, 256, dc*t3*dc*2, stream>>>(
          Z2f, (ushort*)Tnext, W + INVLAM, dc, t3);
    }

    float* tmp = Tcur; Tcur = Tnext; Tnext = tmp;
  }
}

// Round 5
// 1689.944 us; speedup vs baseline: 3.3590x; 1.0940x over previous
//
#include <hip/hip_runtime.h>

// ============================================================================
// HOTRG (2D Ising) — R5: XCD-chunked swizzle in MFMA GEMMs, 128^2 expm tiles,
// fused absmax in Z-GEMM epilogue, regridded permute_scale.
// ============================================================================

#define TEMPC 2.269f

typedef unsigned int uint32;
typedef short short8b __attribute__((ext_vector_type(8)));
typedef float f32x4 __attribute__((ext_vector_type(4)));
typedef unsigned short ushort8v __attribute__((ext_vector_type(8)));

__device__ __forceinline__ ushort f2bf(float x) {
  uint32 u = __float_as_uint(x);
  u = (u + 0x7FFFu + ((u >> 16) & 1u)) >> 16;
  return (ushort)u;
}
__device__ __forceinline__ float toF(float x) { return x; }
__device__ __forceinline__ float toF(ushort h) { return __uint_as_float(((uint32)h) << 16); }

__device__ __forceinline__ void gll16(const ushort* g, ushort* l) {
  __builtin_amdgcn_global_load_lds((const __attribute__((address_space(1))) void*)g,
                                   (__attribute__((address_space(3))) void*)l, 16, 0, 0);
}

// ---------------- MFMA GEMM: C = A @ B; A row-major [M][Kp], Bt K-major [N][Kp]
// mode: 1=add cA*Aadd+cI*I, 2=write Cf (f32), 4=write Cb (bf16), 8=atomicMax |v|
// XCD-bijective chunked block swizzle (T1): same-A-panel blocks -> same XCD.
template<int BM, int BN>
__global__ __launch_bounds__(256) void gemm_mfma(
    const ushort* __restrict__ A, const ushort* __restrict__ Bt,
    float* __restrict__ Cf, ushort* __restrict__ Cb,
    const float* __restrict__ Aadd, float cA, float cI, int mode,
    float* __restrict__ lamOut,
    int Np, int Kp, long sA, long sB, long sC)
{
  constexpr int FRM = BM / 32, FRN = BN / 32;
  constexpr int LA = BM / 8, LB = BN / 8, LPW = (LA + LB) / 4;
  __shared__ __align__(16) ushort As[BM * 64];
  __shared__ __align__(16) ushort Bs[BN * 64];
  __shared__ float redsm[256];
  const int tid = threadIdx.x;
  const int wid = tid >> 6, lane = tid & 63;

  // bijective XCD-chunk swizzle over the flattened grid
  const long gxy = (long)gridDim.x * gridDim.y;
  const long tot = gxy * gridDim.z;
  const long flat = ((long)blockIdx.z * gridDim.y + blockIdx.y) * gridDim.x + blockIdx.x;
  const long q = tot >> 3, r = tot & 7;
  const long xcd = flat & 7, off = flat >> 3;
  const long swz = (xcd < r) ? (xcd * (q + 1) + off) : (r * (q + 1) + (xcd - r) * q + off);
  const int bz = (int)(swz / gxy);
  const long rem = swz - (long)bz * gxy;
  const int by = (int)(rem / gridDim.x);
  const int bx = (int)(rem - (long)by * gridDim.x);

  const int m0 = by * BM, n0 = bx * BN;
  const int wm0 = (wid >> 1) * (BM / 2), wn0 = (wid & 1) * (BN / 2);
  const int rl = lane & 15, cb = lane >> 4;
  const ushort* Ap = A + (long)bz * sA + (long)m0 * Kp;
  const ushort* Bp = Bt + (long)bz * sB + (long)n0 * Kp;

  f32x4 acc[FRM][FRN];
  #pragma unroll
  for (int i = 0; i < FRM; ++i)
    #pragma unroll
    for (int j = 0; j < FRN; ++j) { acc[i][j][0]=0.f; acc[i][j][1]=0.f; acc[i][j][2]=0.f; acc[i][j][3]=0.f; }

  for (int k0 = 0; k0 < Kp; k0 += 64) {
    #pragma unroll
    for (int t = 0; t < LPW; ++t) {
      int gl = wid * LPW + t;
      int isA = gl < LA;
      int tt = isA ? gl : gl - LA;
      int li = tt * 64 + lane;
      int rr = li >> 3, ch = li & 7;
      int sch = ch ^ (rr & 7);
      if (isA) gll16(Ap + (long)rr * Kp + k0 + sch * 8, &As[tt * 512]);
      else     gll16(Bp + (long)rr * Kp + k0 + sch * 8, &Bs[tt * 512]);
    }
    __syncthreads();
    #pragma unroll
    for (int km = 0; km < 2; ++km) {
      short8b af[FRM], bfv[FRN];
      #pragma unroll
      for (int i = 0; i < FRM; ++i) {
        int rr = wm0 + i * 16 + rl;
        af[i] = *(const short8b*)&As[rr * 64 + ((((km << 2) | cb) ^ (rr & 7)) << 3)];
      }
      #pragma unroll
      for (int j = 0; j < FRN; ++j) {
        int rr = wn0 + j * 16 + rl;
        bfv[j] = *(const short8b*)&Bs[rr * 64 + ((((km << 2) | cb) ^ (rr & 7)) << 3)];
      }
      #pragma unroll
      for (int i = 0; i < FRM; ++i)
        #pragma unroll
        for (int j = 0; j < FRN; ++j)
          acc[i][j] = __builtin_amdgcn_mfma_f32_16x16x32_bf16(af[i], bfv[j], acc[i][j], 0, 0, 0);
    }
    __syncthreads();
  }
  const int r4 = (lane >> 4) * 4, cl = lane & 15;
  float mx = 0.0f;
  #pragma unroll
  for (int i = 0; i < FRM; ++i) {
    #pragma unroll
    for (int j = 0; j < FRN; ++j) {
      int row0 = m0 + wm0 + i * 16 + r4;
      int col  = n0 + wn0 + j * 16 + cl;
      #pragma unroll
      for (int qq = 0; qq < 4; ++qq) {
        long off2 = (long)bz * sC + (long)(row0 + qq) * Np + col;
        float v = acc[i][j][qq];
        if (mode & 1) v += cA * Aadd[off2] + ((row0 + qq) == col ? cI : 0.0f);
        if (mode & 2) Cf[off2] = v;
        if (mode & 4) Cb[off2] = f2bf(v);
        if (mode & 8) mx = fmaxf(mx, fabsf(v));
      }
    }
  }
  if (mode & 8) {
    redsm[tid] = mx;
    __syncthreads();
    for (int s = 128; s > 0; s >>= 1) {
      if (tid < s) redsm[tid] = fmaxf(redsm[tid], redsm[tid + s]);
      __syncthreads();
    }
    if (tid == 0) atomicMax((unsigned*)lamOut, __float_as_uint(redsm[0]));
  }
}

// ---------------- transpose -> bf16 K-major with zero K-pad ----------------
template<typename TI>
__global__ __launch_bounds__(256) void trans_to_bfT(const TI* __restrict__ in, ushort* __restrict__ out,
                                                    int R, int C, int inStride, int outStride, int Rpad,
                                                    long sIn, long sOut)
{
  __shared__ float sm[32][33];
  const TI* ip = in + (long)blockIdx.z * sIn;
  ushort* op = out + (long)blockIdx.z * sOut;
  int c0 = blockIdx.x * 32, r0 = blockIdx.y * 32;
  int lx = threadIdx.x & 31, ly = threadIdx.x >> 5;
  #pragma unroll
  for (int yy = 0; yy < 4; ++yy) {
    int r = r0 + ly + yy * 8, c = c0 + lx;
    if (r < R && c < C) sm[ly + yy * 8][lx] = toF(ip[(long)r * inStride + c]);
  }
  __syncthreads();
  #pragma unroll
  for (int yy = 0; yy < 4; ++yy) {
    int orow = c0 + ly + yy * 8;
    int ocol = r0 + lx;
    if (orow < C && ocol < Rpad) {
      ushort v = 0;
      if (ocol < R) v = f2bf(sm[lx][ly + yy * 8]);
      op[(long)orow * outStride + ocol] = v;
    }
  }
}

// ---------------- K1/K3 helper builds ----------------
template<typename TT>
__global__ __launch_bounds__(256) void transTk_kernel(const TT* __restrict__ T, ushort* __restrict__ out,
                                                      int d0, long R)
{
  long idx = (long)blockIdx.x * 256 + threadIdx.x;
  if (idx >= R * 64) return;
  long r = idx >> 6; int ii = (int)(idx & 63);
  ushort v = 0;
  if (ii < d0) v = f2bf(toF(T[(long)ii * R + r]));
  out[idx] = v;
}

__global__ __launch_bounds__(256) void build_ut1(const float* __restrict__ U, ushort* __restrict__ out,
                                                 int d0, int dc, int Mpad)
{
  int idx = blockIdx.x * 256 + threadIdx.x;
  if (idx >= Mpad * 64) return;
  int ja = idx >> 6, ii = idx & 63;
  ushort v = 0;
  if (ii < d0 && ja < d0 * dc) {
    int j = ja / dc, a = ja - j * dc;
    v = f2bf(U[((long)ii * d0 + j) * dc + a]);
  }
  out[idx] = v;
}

__global__ __launch_bounds__(256) void build_ut3(const float* __restrict__ U, ushort* __restrict__ out,
                                                 int d0, int dc, int Kp3)
{
  int idx = blockIdx.x * 256 + threadIdx.x;
  if (idx >= 64 * Kp3) return;
  int c = idx / Kp3, mp = idx - c * Kp3;
  ushort v = 0;
  if (c < dc && mp < d0 * d0) v = f2bf(U[(long)mp * dc + c]);
  out[idx] = v;
}

// ---- permuteP v2: X2[bm,a | j,n] = P[j,a | bm,n]; tiled fat-transpose ----
__global__ __launch_bounds__(256) void permutePv2(const ushort* __restrict__ P, ushort* __restrict__ X2,
                                                  int t3, int d0, int dc, long R1, int Kp2)
{
  extern __shared__ char dynA[];
  ushort* sm = (ushort*)dynA;
  const int tid = threadIdx.x;
  const int bm0 = blockIdx.x * 16;
  const int j0 = blockIdx.y * 16;
  const int a = blockIdx.z;
  const int Wr = 16 * t3;
  const int nv = Wr / 8;
  for (int idx = tid; idx < 16 * nv; idx += 256) {
    int j_l = idx / nv, v = idx - j_l * nv;
    ushort8v val{};
    int j = j0 + j_l;
    if (j < d0) {
      const ushort* src = P + (long)(j * dc + a) * R1 + (long)bm0 * t3;
      val = *(const ushort8v*)(src + v * 8);
    }
    *(ushort8v*)(sm + j_l * Wr + v * 8) = val;
  }
  __syncthreads();
  for (int idx = tid; idx < 16 * Wr; idx += 256) {
    int bm_l = idx / Wr, jn = idx - bm_l * Wr;
    int j_l = jn / t3, n = jn - j_l * t3;
    long row = (long)(bm0 + bm_l) * dc + a;
    X2[row * Kp2 + (long)j0 * t3 + jn] = sm[j_l * Wr + bm_l * t3 + n];
  }
}

__global__ __launch_bounds__(256) void zeroX2pad(ushort* __restrict__ X2, long rows, int K, int Kp2)
{
  const int w = Kp2 - K;
  long id = (long)blockIdx.x * 256 + threadIdx.x;
  if (id >= rows * w) return;
  long r = id / w; int c = (int)(id - r * w);
  X2[r * Kp2 + K + c] = 0;
}

// ---- permuteY v2: Yp[(b,a,e)][(m,p)] = Y[(b,m,a)][(p,e)] ----
__global__ __launch_bounds__(256) void permuteYv2(const ushort* __restrict__ Y, ushort* __restrict__ Yp,
                                                  int dc, int d0, int t3, int NpdY, int Kp3,
                                                  int nWork, long rowsValid, long Mpad3)
{
  extern __shared__ char dynB[];
  ushort* sY = (ushort*)dynB;
  const int tid = threadIdx.x;
  if ((int)blockIdx.x >= nWork) {
    long tot = (Mpad3 - rowsValid) * Kp3 / 8;
    ushort8v z{};
    for (long v = tid; v < tot; v += 256)
      *(ushort8v*)(Yp + rowsValid * Kp3 + v * 8) = z;
    return;
  }
  const int blk = blockIdx.x;
  const int b = blk / dc, a = blk - b * dc;
  const int Wd = d0 * t3, wv = Wd / 8;
  for (int idx = tid; idx < d0 * wv; idx += 256) {
    int m = idx / wv, v = idx - m * wv;
    *(ushort8v*)(sY + m * Wd + v * 8) =
        *(const ushort8v*)(Y + ((long)(b * d0 + m) * dc + a) * NpdY + v * 8);
  }
  __syncthreads();
  const long obase = (long)blk * t3 * Kp3;
  const int DD = d0 * d0, kv = Kp3 / 8;
  for (int idx = tid; idx < t3 * kv; idx += 256) {
    int e = idx / kv, c8 = idx - e * kv;
    int col0 = c8 * 8;
    ushort8v v{};
    #pragma unroll
    for (int k = 0; k < 8; ++k) {
      int col = col0 + k;
      if (col < DD) { int m = col / d0, p = col - m * d0; v[k] = sY[m * Wd + p * t3 + e]; }
    }
    *(ushort8v*)(Yp + obase + (long)e * Kp3 + col0) = v;
  }
}

// ---- T'[b,c,e,a] (bf16) = Z2[(b,a,e)][c]*invlam; block=(b, c-chunk of 7) ----
__global__ __launch_bounds__(256) void permute_scale2c(const float* __restrict__ Z2, ushort* __restrict__ Tn,
                                                       const float* __restrict__ invlam, int dc, int t3)
{
  extern __shared__ char dynC[];
  ushort* sm = (ushort*)dynC;
  const int b = blockIdx.x;
  const int c0 = blockIdx.y * 7;
  const int tid = threadIdx.x;
  const float s = invlam[0];
  const int TD = t3 * dc;
  const int tot = dc * t3 * 7;
  for (int idx = tid; idx < tot; idx += 256) {
    int c7 = idx % 7; int rem = idx / 7;
    int e = rem % t3; int a = rem / t3;
    float v = Z2[(((long)(b * dc + a)) * t3 + e) * 64 + c0 + c7] * s;
    sm[(c7 * t3 + e) * dc + a] = f2bf(v);
  }
  __syncthreads();
  const long ob = (long)(b * dc + c0) * TD;
  for (int idx = tid; idx < tot / 8; idx += 256)
    *(ushort8v*)(Tn + ob + idx * 8) = *(ushort8v*)(sm + idx * 8);
}

// ---------------- expm builders (n=784 bf16 path) ----------------
__global__ __launch_bounds__(256) void build_A2(const float* __restrict__ Aflat, float* __restrict__ Af,
                                                ushort* __restrict__ Ab, ushort* __restrict__ An,
                                                int n, int Np, long aoff, long tri, float sc)
{
  const int b = blockIdx.y;
  const long nn = (long)Np * Np;
  const long id = (long)blockIdx.x * 256 + threadIdx.x;
  if (id >= nn) return;
  const int r = (int)(id / Np), c = (int)(id % Np);
  float v = 0.0f;
  if (r < n && c < n) {
    if (c > r)      v =  Aflat[aoff + b * tri + (long)r * (n - 1) - (long)r * (r - 1) / 2 + (c - r - 1)] * sc;
    else if (c < r) v = -Aflat[aoff + b * tri + (long)c * (n - 1) - (long)c * (c - 1) / 2 + (r - c - 1)] * sc;
  }
  long o = b * nn + id;
  Af[o] = v; Ab[o] = f2bf(v); An[o] = f2bf(-v);
}

__global__ __launch_bounds__(256) void axpy_q2(const ushort* __restrict__ A2b, const float* __restrict__ Af,
                                               ushort* __restrict__ Qb, int Np)
{
  const int b = blockIdx.y;
  const long nn = (long)Np * Np;
  const long id = (long)blockIdx.x * 256 + threadIdx.x;
  if (id >= nn) return;
  const int r = (int)(id / Np), c = (int)(id % Np);
  long o = b * nn + id;
  float v = (1.0f/40320.0f) * toF(A2b[o]) + (1.0f/5040.0f) * Af[o] + ((r == c) ? (1.0f/720.0f) : 0.0f);
  Qb[o] = f2bf(v);
}

__global__ __launch_bounds__(256) void extract_u2(const float* __restrict__ E, float* __restrict__ W,
                                                  int n, int dcut, int rowStride, long ubase, long ustride, long estride)
{
  const int b = blockIdx.y;
  const long tot = (long)n * dcut;
  const long id = (long)blockIdx.x * 256 + threadIdx.x;
  if (id >= tot) return;
  const int rr = (int)(id / dcut), aa = (int)(id % dcut);
  W[ubase + b * ustride + id] = E[b * estride + (long)rr * rowStride + aa];
}

// ---------------- small expm (n<=16) ----------------
struct SmallStep { int n, d0, dcut, s; long aoff; long uoff; };
struct SmallStep4 { SmallStep st[4]; };

__global__ __launch_bounds__(256) void expm_small_kernel(const float* __restrict__ Aflat,
                                                         float* __restrict__ W, SmallStep4 ps)
{
  SmallStep p = ps.st[blockIdx.x];
  const int n = p.n, nn = n * n;
  __shared__ float As[256], A2[256], Qa[256], Qb[256];
  const int tid = threadIdx.x;
  const int r = (tid < nn) ? (tid / n) : 0;
  const int c = (tid < nn) ? (tid % n) : 0;
  const float sc = 1.0f / (float)(1 << p.s);
  if (tid < nn) {
    float v = 0.0f;
    if (c > r)      v =  Aflat[p.aoff + (long)r*(n-1) - (long)r*(r-1)/2 + (c - r - 1)] * sc;
    else if (c < r) v = -Aflat[p.aoff + (long)c*(n-1) - (long)c*(c-1)/2 + (r - c - 1)] * sc;
    As[tid] = v;
  }
  __syncthreads();
  if (tid < nn) {
    float s2 = 0.0f;
    for (int k = 0; k < n; ++k) s2 += As[r*n+k] * As[k*n+c];
    A2[tid] = s2;
  }
  __syncthreads();
  if (tid < nn)
    Qa[tid] = (1.0f/40320.0f)*A2[tid] + (1.0f/5040.0f)*As[tid] + ((r==c) ? (1.0f/720.0f) : 0.0f);
  __syncthreads();
  float* q = Qa; float* qn = Qb;
  const float cis[3] = {1.0f/24.0f, 0.5f, 1.0f};
  const float cas[3] = {1.0f/120.0f, 1.0f/6.0f, 1.0f};
  #pragma unroll
  for (int it = 0; it < 3; ++it) {
    if (tid < nn) {
      float s2 = 0.0f;
      for (int k = 0; k < n; ++k) s2 += A2[r*n+k] * q[k*n+c];
      qn[tid] = s2 + cas[it]*As[tid] + ((r==c) ? cis[it] : 0.0f);
    }
    __syncthreads();
    float* t = q; q = qn; qn = t;
  }
  for (int it = 0; it < p.s; ++it) {
    float s2 = 0.0f;
    if (tid < nn) { for (int k = 0; k < n; ++k) s2 += q[r*n+k] * q[k*n+c]; }
    if (tid < nn) qn[tid] = s2;
    __syncthreads();
    float* t = q; q = qn; qn = t;
  }
  if (tid < n * p.dcut) {
    int rr = tid / p.dcut, aa = tid % p.dcut;
    W[p.uoff + tid] = q[rr*n + aa];
  }
}

// ---------------- fp32 helpers (group B + steps 0-3) ----------------
__global__ __launch_bounds__(256) void build_A_kernel(const float* __restrict__ Aflat, float* __restrict__ A,
                                                      int n, long aoff, long tri, float sc)
{
  const int b = blockIdx.y;
  const long nn = (long)n * n;
  const long id = (long)blockIdx.x * 256 + threadIdx.x;
  if (id >= nn) return;
  const int r = (int)(id / n), c = (int)(id % n);
  float v = 0.0f;
  if (c > r)      v =  Aflat[aoff + b*tri + (long)r*(n-1) - (long)r*(r-1)/2 + (c - r - 1)] * sc;
  else if (c < r) v = -Aflat[aoff + b*tri + (long)c*(n-1) - (long)c*(c-1)/2 + (r - c - 1)] * sc;
  A[b*nn + id] = v;
}

__global__ __launch_bounds__(256) void axpy_q_kernel(const float* __restrict__ A2, const float* __restrict__ A,
                                                     float* __restrict__ Q, int n)
{
  const int b = blockIdx.y;
  const long nn = (long)n * n;
  const long id = (long)blockIdx.x * 256 + threadIdx.x;
  if (id >= nn) return;
  const int r = (int)(id / n), c = (int)(id % n);
  Q[b*nn + id] = (1.0f/40320.0f)*A2[b*nn + id] + (1.0f/5040.0f)*A[b*nn + id]
               + ((r==c) ? (1.0f/720.0f) : 0.0f);
}

template<int BM, int BN, int BK, int TM, int TN>
__global__ __launch_bounds__(256) void gemm_f32(
    const float* __restrict__ A, const float* __restrict__ B, float* __restrict__ C,
    const float* __restrict__ Aadd, float cA, float cI, int useEp,
    int M, int N, int K, long sA, long sB, long sC, long sAd)
{
  constexpr int PAD = 4;
  __shared__ float As[BK][BM + PAD];
  __shared__ float Bs[BK][BN + PAD];
  const int tid = threadIdx.x;
  const int bz = blockIdx.z;
  const float* Ap = A + (long)bz * sA;
  const float* Bp = B + (long)bz * sB;
  float* Cp = C + (long)bz * sC;
  const float* Adp = useEp ? (Aadd + (long)bz * sAd) : nullptr;
  const int m0 = blockIdx.y * BM, n0 = blockIdx.x * BN;
  constexpr int TX = BN / TN;
  const int tx = tid % TX, ty = tid / TX;
  float acc[TM][TN];
  #pragma unroll
  for (int i = 0; i < TM; ++i)
    #pragma unroll
    for (int j = 0; j < TN; ++j) acc[i][j] = 0.0f;

  const int a_m = tid / (BK / 4);
  const int a_k = (tid % (BK / 4)) * 4;
  const int b_k = tid / (BN / 4);
  const int b_n = (tid % (BN / 4)) * 4;

  for (int k0 = 0; k0 < K; k0 += BK) {
    float4 av = make_float4(0.f, 0.f, 0.f, 0.f);
    if (m0 + a_m < M && k0 + a_k < K)
      av = *(const float4*)(Ap + (long)(m0 + a_m) * K + k0 + a_k);
    As[a_k + 0][a_m] = av.x; As[a_k + 1][a_m] = av.y;
    As[a_k + 2][a_m] = av.z; As[a_k + 3][a_m] = av.w;
    float4 bv = make_float4(0.f, 0.f, 0.f, 0.f);
    if (k0 + b_k < K && n0 + b_n < N)
      bv = *(const float4*)(Bp + (long)(k0 + b_k) * N + n0 + b_n);
    *(float4*)&Bs[b_k][b_n] = bv;
    __syncthreads();
    #pragma unroll
    for (int kk = 0; kk < BK; ++kk) {
      float af[TM], bf[TN];
      #pragma unroll
      for (int i = 0; i < TM; i += 4) *(float4*)&af[i] = *(const float4*)&As[kk][ty*TM + i];
      #pragma unroll
      for (int j = 0; j < TN; j += 4) *(float4*)&bf[j] = *(const float4*)&Bs[kk][tx*TN + j];
      #pragma unroll
      for (int i = 0; i < TM; ++i)
        #pragma unroll
        for (int j = 0; j < TN; ++j)
          acc[i][j] = fmaf(af[i], bf[j], acc[i][j]);
    }
    __syncthreads();
  }
  #pragma unroll
  for (int i = 0; i < TM; ++i) {
    int row = m0 + ty*TM + i;
    if (row >= M) continue;
    #pragma unroll
    for (int j = 0; j < TN; ++j) {
      int col = n0 + tx*TN + j;
      if (col >= N) continue;
      float v = acc[i][j];
      if (useEp) v += cA * Adp[(long)row * N + col] + ((row == col) ? cI : 0.0f);
      Cp[(long)row * N + col] = v;
    }
  }
}

// ---------------- fp32 contraction kernels (steps 0-3 only) ----------------
__global__ __launch_bounds__(256) void k1_kernel2(const float* __restrict__ T, const float* __restrict__ U,
                                                  float* __restrict__ X2f,
                                                  int t1, int t2, int t3, int d0, int dcut, int K)
{
  extern __shared__ char dyn3[];
  float* lds = (float*)dyn3;
  float* Ts = lds;
  float* Us = lds + d0 * t3;
  const int tid = threadIdx.x;
  const int bm = blockIdx.x;
  const long tstride = (long)t1 * t2 * t3;
  const long tbase = (long)bm * t3;
  for (int idx = tid; idx < d0 * t3; idx += 256) {
    int i = idx / t3, nn = idx % t3;
    Ts[idx] = T[(long)i * tstride + tbase + nn];
  }
  const int nout = dcut * t3;
  __syncthreads();
  for (int j = 0; j < d0; ++j) {
    for (int idx = tid; idx < d0 * dcut; idx += 256)
      Us[idx] = U[((long)(idx / dcut) * d0 + j) * dcut + (idx % dcut)];
    __syncthreads();
    for (int idx = tid; idx < nout; idx += 256) {
      int a = idx / t3, nn = idx % t3;
      float s = 0.0f;
      for (int i = 0; i < d0; ++i) s += Ts[i*t3 + nn] * Us[i*dcut + a];
      X2f[((long)bm * dcut + a) * K + j * t3 + nn] = s;
    }
    __syncthreads();
  }
}

__global__ __launch_bounds__(256) void k3_kernel2(const float* __restrict__ Y, const float* __restrict__ U,
                                                  float* __restrict__ Z, int t1, int t2, int t3, int d0, int dcut,
                                                  int Ystride)
{
  extern __shared__ char dyn4[];
  float* lds = (float*)dyn4;
  float* Ys = lds;
  float* Us = lds + d0 * t3;
  const int tid = threadIdx.x;
  const int ba = blockIdx.x;
  const int b = ba / dcut, a = ba % dcut;
  const int nout = dcut * t3;
  float acc[4] = {0.f, 0.f, 0.f, 0.f};
  for (int m = 0; m < t2; ++m) {
    const long yrow = ((long)(b*t2 + m) * dcut + a) * Ystride;
    for (int idx = tid; idx < d0 * t3; idx += 256) Ys[idx] = Y[yrow + idx];
    for (int idx = tid; idx < d0 * dcut; idx += 256) Us[idx] = U[(long)m * d0 * dcut + idx];
    __syncthreads();
    #pragma unroll
    for (int o = 0; o < 4; ++o) {
      int idx = tid + o * 256;
      if (idx < nout) {
        int cc = idx / t3, e = idx % t3;
        float s = 0.0f;
        for (int p = 0; p < d0; ++p) s += Ys[p*t3 + e] * Us[p*dcut + cc];
        acc[o] += s;
      }
    }
    __syncthreads();
  }
  #pragma unroll
  for (int o = 0; o < 4; ++o) {
    int idx = tid + o * 256;
    if (idx < nout) {
      int cc = idx / t3, e = idx % t3;
      Z[(((long)a * t1 + b) * dcut + cc) * t3 + e] = acc[o];
    }
  }
}

// ---------------- reductions / permute / init ----------------
__global__ __launch_bounds__(256) void redmax1_kernel(const float* __restrict__ Z, long cnt, float* __restrict__ part)
{
  __shared__ float sm[256];
  float v = 0.0f;
  for (long i = (long)blockIdx.x * 256 + threadIdx.x; i < cnt; i += (long)gridDim.x * 256)
    v = fmaxf(v, fabsf(Z[i]));
  sm[threadIdx.x] = v; __syncthreads();
  for (int s = 128; s > 0; s >>= 1) {
    if ((int)threadIdx.x < s) sm[threadIdx.x] = fmaxf(sm[threadIdx.x], sm[threadIdx.x + s]);
    __syncthreads();
  }
  if (threadIdx.x == 0) part[blockIdx.x] = sm[0];
}

__global__ __launch_bounds__(256) void redmax2_kernel(const float* __restrict__ part, float* __restrict__ invlam,
                                                      float* __restrict__ fe, float w, float* __restrict__ dout)
{
  __shared__ float sm[256];
  sm[threadIdx.x] = part[threadIdx.x]; __syncthreads();
  for (int s = 128; s > 0; s >>= 1) {
    if ((int)threadIdx.x < s) sm[threadIdx.x] = fmaxf(sm[threadIdx.x], sm[threadIdx.x + s]);
    __syncthreads();
  }
  if (threadIdx.x == 0) {
    float lam = sm[0];
    invlam[0] = 1.0f / lam;
    float f = fe[0] - w * logf(lam);
    fe[0] = f;
    dout[0] = f;
  }
}

__global__ void redmax2_atomic(unsigned* __restrict__ lamslot, float* __restrict__ invlam,
                               float* __restrict__ fe, float w, float* __restrict__ dout)
{
  if (threadIdx.x == 0) {
    float lam = __uint_as_float(*lamslot);
    *lamslot = 0u;
    invlam[0] = 1.0f / lam;
    float f = fe[0] - w * logf(lam);
    fe[0] = f;
    dout[0] = f;
  }
}

__global__ __launch_bounds__(256) void permute_scale_kernel(const float* __restrict__ Z, float* __restrict__ Tn,
                                                            const float* __restrict__ invlam, int t1, int t3, int dcut)
{
  extern __shared__ char dyn5[];
  float* lds = (float*)dyn5;
  const int tid = threadIdx.x;
  const int bc = blockIdx.x;
  const int b = bc / dcut, c = bc % dcut;
  const float s = invlam[0];
  const int tot = dcut * t3;
  for (int idx = tid; idx < tot; idx += 256) {
    int a = idx / t3, e = idx % t3;
    lds[idx] = Z[(((long)a * t1 + b) * dcut + c) * t3 + e] * s;
  }
  __syncthreads();
  const long ob = (long)bc * t3 * dcut;
  for (int idx = tid; idx < tot; idx += 256) {
    int e = idx / dcut, a = idx % dcut;
    Tn[ob + idx] = lds[a * t3 + e];
  }
}

__global__ void init_kernel(const float* __restrict__ T0, float* __restrict__ Tdst, float* __restrict__ fe,
                            unsigned* __restrict__ lamslot)
{
  int t = threadIdx.x;
  if (t < 16) Tdst[t] = T0[t];
  if (t == 0) { fe[0] = 0.0f; *lamslot = 0u; }
}

// ============================================================================
extern "C" void kernel_launch(void* const* d_in, const int* in_sizes, int n_in,
                              void* d_out, int out_size, void* d_ws, size_t ws_size,
                              hipStream_t stream)
{
  const float* Aflat = (const float*)d_in[0];
  const float* T0    = (const float*)d_in[1];
  float* out = (float*)d_out;
  float* W = (float*)d_ws;
  (void)ws_size; (void)in_sizes; (void)n_in; (void)out_size;

  const int SH_n[12]  = {4,4,16,16,256,256,784,784,784,784,784,784};
  const int SH_d0[12] = {2,2,4,4,16,16,28,28,28,28,28,28};
  const int SH_dc[12] = {4,4,16,16,28,28,28,28,28,28,28,28};
  long aoff[12]; { long o = 0; for (int i = 0; i < 12; ++i) { aoff[i] = o; o += (long)SH_n[i]*(SH_n[i]-1)/2; } }
  long uoff[12]; { long o = 1024; for (int i = 0; i < 12; ++i) { uoff[i] = o; o += (long)SH_d0[i]*SH_d0[i]*SH_dc[i]; } }
  int T1d[12], T2d[12], T3d[12], T0d[12];
  { int a=2,b=2,c=2,d=2;
    for (int i = 0; i < 12; ++i) { T0d[i]=a; T1d[i]=b; T2d[i]=c; T3d[i]=d;
      int dc = SH_dc[i]; int na=b, nb=dc, nc=d, nd=dc; a=na; b=nb; c=nc; d=nd; } }

  const long FE = 0, INVLAM = 1, LAM = 2, PART = 64;
  const long TA   = 150016;
  const long TB   = TA + 614656;
  const long Z2o  = TB + 614656;           // 22016x64 f32
  const long TTK  = Z2o + 1409024;         // 21952x64 ush
  const long TTo  = TTK + 702464;          // 896x896 ush
  const long UT1o = TTo + 401408;
  const long UT3o = UT1o + 212992;
  const long BIG0 = 4318208;               // P / Yp
  const long BIG1 = BIG0 + 9158656;        // X2
  const long BIG2 = BIG1 + 9863168;        // Y
  const long P_Af  = BIG0;
  const long P_S4  = BIG0 + 4816896;       // 6 x 896x64 f32 (trimmed)
  const long P_bf  = BIG0 + 9633792;
  const long P_Ab  = P_bf;
  const long P_An  = P_bf + 2408448;
  const long P_A2b = P_bf + 2*2408448;
  const long P_Q0  = P_bf + 3*2408448;
  const long P_Q1  = P_bf + 4*2408448;
  const long P_QT  = P_bf + 5*2408448;
  const long P_Bb  = BIG0 + 24084480;

  const float c5 = 1.0f/120.0f, c4 = 1.0f/24.0f, c3 = 1.0f/6.0f, c2 = 0.5f;

  ushort* TTKp = (ushort*)(W + TTK);
  ushort* Ttb  = (ushort*)(W + TTo);
  ushort* UT1p = (ushort*)(W + UT1o);
  ushort* UT3p = (ushort*)(W + UT3o);
  ushort* Pb   = (ushort*)(W + BIG0);
  ushort* Ypb  = (ushort*)(W + BIG0);
  ushort* X2b  = (ushort*)(W + BIG1);
  ushort* Yb   = (ushort*)(W + BIG2);
  float*  X2F_ = W + BIG1;
  float*  YF_  = W + BIG2;
  float*  Z2f  = W + Z2o;
  float*  lamS = W + LAM;

  // ================= Phase 1: U matrices =================
  {
    SmallStep4 sp;
    const int ss[4] = {0,0,1,1};
    for (int i = 0; i < 4; ++i) {
      sp.st[i].n = SH_n[i]; sp.st[i].d0 = SH_d0[i]; sp.st[i].dcut = SH_dc[i];
      sp.st[i].s = ss[i]; sp.st[i].aoff = aoff[i]; sp.st[i].uoff = uoff[i];
    }
    expm_small_kernel<<<4, 256, 0, stream>>>(Aflat, W, sp);
  }

  // ---- group A: steps 6-11 (n=784 -> Np=896, batch 6, s=2, Taylor-8) ----
  {
    const int n = 784, Np = 896, bt = 6;
    const long NN = (long)Np * Np;
    float* Af = W + P_Af;  float* S4 = W + P_S4;
    ushort* Ab = (ushort*)(W + P_Ab);  ushort* An = (ushort*)(W + P_An);
    ushort* A2b = (ushort*)(W + P_A2b);
    ushort* Q0 = (ushort*)(W + P_Q0);  ushort* Q1 = (ushort*)(W + P_Q1);
    ushort* QT = (ushort*)(W + P_QT);
    dim3 ge((int)((NN + 255) / 256), bt);
    build_A2<<<ge, 256, 0, stream>>>(Aflat, Af, Ab, An, n, Np, aoff[6], 306936, 0.25f);
    dim3 g(Np/128, Np/128, bt);
    dim3 gt(Np/32, Np/32, bt);
    gemm_mfma<128,128><<<g,256,0,stream>>>(Ab, An, nullptr, A2b, nullptr, 0.f, 0.f, 4, nullptr, Np, Np, NN, NN, NN);
    axpy_q2<<<ge, 256, 0, stream>>>(A2b, Af, Q0, Np);
    gemm_mfma<128,128><<<g,256,0,stream>>>(Q0, A2b, nullptr, Q1, Af, c5, c4, 5, nullptr, Np, Np, NN, NN, NN);
    gemm_mfma<128,128><<<g,256,0,stream>>>(Q1, A2b, nullptr, Q0, Af, c3, c2, 5, nullptr, Np, Np, NN, NN, NN);
    gemm_mfma<128,128><<<g,256,0,stream>>>(Q0, A2b, nullptr, Q1, Af, 1.f, 1.f, 5, nullptr, Np, Np, NN, NN, NN);
    // squaring 1 (full)
    trans_to_bfT<ushort><<<gt,256,0,stream>>>(Q1, QT, Np, Np, Np, Np, Np, NN, NN);
    gemm_mfma<128,128><<<g,256,0,stream>>>(Q1, QT, nullptr, Q0, nullptr, 0.f, 0.f, 4, nullptr, Np, Np, NN, NN, NN);
    // squaring 2 (only first 64 columns needed)
    trans_to_bfT<ushort><<<dim3(2, Np/32, bt),256,0,stream>>>(Q0, QT, Np, 64, Np, Np, Np, NN, NN);
    gemm_mfma<64,64><<<dim3(1, Np/64, bt),256,0,stream>>>(Q0, QT, S4, nullptr, nullptr, 0.f, 0.f, 2,
                                                          nullptr, 64, Np, NN, NN, 57344);
    extract_u2<<<dim3(86, bt), 256, 0, stream>>>(S4, W, n, 28, 64, uoff[6], 21952, 57344);
  }

  // ---- group B: steps 4,5 (n=256, batch 2, s=2) fp32 exact ----
  {
    const int n = 256, bt = 2; const long st = 65536; const long tri = 32640;
    float* B_as = W + P_Bb;
    float* B_a2 = W + P_Bb + 131072;
    float* B_q1 = W + P_Bb + 262144;
    float* B_q2 = W + P_Bb + 393216;
    build_A_kernel<<<dim3(256, bt), 256, 0, stream>>>(Aflat, B_as, n, aoff[4], tri, 0.25f);
    dim3 g(4, 4, bt);
    gemm_f32<64,64,16,4,4><<<g,256,0,stream>>>(B_as, B_as, B_a2, nullptr,0,0,0, n,n,n, st,st,st,st);
    axpy_q_kernel<<<dim3(256, bt), 256, 0, stream>>>(B_a2, B_as, B_q1, n);
    gemm_f32<64,64,16,4,4><<<g,256,0,stream>>>(B_a2, B_q1, B_q2, B_as, c5, c4, 1, n,n,n, st,st,st,st);
    gemm_f32<64,64,16,4,4><<<g,256,0,stream>>>(B_a2, B_q2, B_q1, B_as, c3, c2, 1, n,n,n, st,st,st,st);
    gemm_f32<64,64,16,4,4><<<g,256,0,stream>>>(B_a2, B_q1, B_q2, B_as, 1.f, 1.f, 1, n,n,n, st,st,st,st);
    gemm_f32<64,64,16,4,4><<<g,256,0,stream>>>(B_q2, B_q2, B_q1, nullptr,0,0,0, n,n,n, st,st,st,st);
    gemm_f32<64,64,16,4,4><<<g,256,0,stream>>>(B_q1, B_q1, B_q2, nullptr,0,0,0, n,n,n, st,st,st,st);
    extract_u2<<<dim3(28, bt), 256, 0, stream>>>(B_q2, W, n, 28, n, uoff[4], 7168, st);
  }

  // ---- U-derived operands for steps 4..11 ----
  for (int i = 4; i < 12; ++i) {
    const int d0 = T0d[i], dc = SH_dc[i];
    const int Kp3 = (d0*d0 + 63)/64*64;
    build_ut1<<<(832*64+255)/256, 256, 0, stream>>>(W + uoff[i], UT1p + (long)(i-4)*832*64, d0, dc, 832);
    build_ut3<<<(64*Kp3+255)/256, 256, 0, stream>>>(W + uoff[i], UT3p + (long)(i-4)*64*832, d0, dc, Kp3);
  }

  // ================= Phase 2: 12 RG steps =================
  float* Tcur = W + TA;
  float* Tnext = W + TB;
  init_kernel<<<1, 256, 0, stream>>>(T0, Tcur, W + FE, (unsigned*)lamS);

  for (int i = 0; i < 12; ++i) {
    const int t1 = T1d[i], t2 = T2d[i], t3 = T3d[i], d0 = T0d[i], dc = SH_dc[i];
    const float* U = W + uoff[i];
    const int M = t1*t2*dc, K = d0*t3, N = t2*t3;
    const float w = TEMPC / (float)(1 << (i + 1));

    if (i < 4) {
      const int lds1 = (d0*t3 + d0*dc) * (int)sizeof(float);
      k1_kernel2<<<t1*t2, 256, lds1, stream>>>(Tcur, U, X2F_, t1, t2, t3, d0, dc, K);
      dim3 g2((N + 127) / 128, (M + 127) / 128, 1);
      gemm_f32<128,128,8,8,8><<<g2, 256, 0, stream>>>(X2F_, Tcur, YF_, nullptr, 0, 0, 0,
                                                      M, N, K, 0, 0, 0, 0);
      const int lds3 = (d0*t3 + d0*dc) * (int)sizeof(float);
      k3_kernel2<<<t1*dc, 256, lds3, stream>>>(YF_, U, Z2f, t1, t2, t3, d0, dc, N);
      const long redCnt = (long)dc * t1 * dc * t3;
      redmax1_kernel<<<256, 256, 0, stream>>>(Z2f, redCnt, W + PART);
      redmax2_kernel<<<1, 256, 0, stream>>>(W + PART, W + INVLAM, W + FE, w, out);
      permute_scale_kernel<<<t1*dc, 256, dc*t3*(int)sizeof(float), stream>>>(
          Z2f, Tnext, W + INVLAM, t1, t3, dc);
    } else {
      const bool inBf = (i >= 5);
      const int Kp2 = (K == 784) ? 896 : ((K == 448) ? 512 : 256);
      const int Npd = (N == 784) ? 896 : ((N == 448) ? 512 : 256);
      const long R1 = (long)t1 * t2 * t3;
      const int Mpad1 = (d0*dc + 63)/64*64;
      const int Kp3 = (d0*d0 + 63)/64*64;
      const long rowsV = (long)t1 * dc * t3;
      const long Mpad3 = (rowsV + 127)/128*128;
      const int Mpad2 = (int)((M + 127)/128*128);
      const ushort* Ut1_i = UT1p + (long)(i-4)*832*64;
      const ushort* Ut3_i = UT3p + (long)(i-4)*64*832;

      // K1 = Ut1 @ T^T -> P -> tiled fat-transpose -> X2
      if (inBf) transTk_kernel<ushort><<<(int)((R1*64 + 255)/256), 256, 0, stream>>>(
          (const ushort*)Tcur, TTKp, d0, R1);
      else      transTk_kernel<float><<<(int)((R1*64 + 255)/256), 256, 0, stream>>>(
          Tcur, TTKp, d0, R1);
      gemm_mfma<64,64><<<dim3((int)(R1/64), Mpad1/64), 256, 0, stream>>>(
          Ut1_i, TTKp, nullptr, Pb, nullptr, 0.f, 0.f, 4, nullptr, (int)R1, 64, 0, 0, 0);
      {
        int bmt = (t1*t2)/16, jt = (d0 + 15)/16;
        permutePv2<<<dim3(bmt, jt, dc), 256, 16*16*t3*2, stream>>>(Pb, X2b, t3, d0, dc, R1, Kp2);
        if (K < Kp2)
          zeroX2pad<<<(int)(((long)Mpad2*(Kp2-K) + 255)/256), 256, 0, stream>>>(X2b, Mpad2, K, Kp2);
      }

      // GEMM2: Y = X2 @ T^T
      if (inBf) trans_to_bfT<ushort><<<dim3((N+31)/32, (Kp2+31)/32), 256, 0, stream>>>(
          (const ushort*)Tcur, Ttb, K, N, N, Kp2, Kp2, 0, 0);
      else      trans_to_bfT<float><<<dim3((N+31)/32, (Kp2+31)/32), 256, 0, stream>>>(
          Tcur, Ttb, K, N, N, Kp2, Kp2, 0, 0);
      gemm_mfma<128,128><<<dim3(Npd/128, Mpad2/128), 256, 0, stream>>>(
          X2b, Ttb, nullptr, Yb, nullptr, 0.f, 0.f, 4, nullptr, Npd, Kp2, 0, 0, 0);

      // K3: permute Y -> Yp, Z2 = Yp @ Ut3 (+fused absmax)
      const int nWork = t1*dc;
      const int nb = nWork + ((Mpad3 > rowsV) ? 1 : 0);
      permuteYv2<<<nb, 256, d0*d0*t3*2, stream>>>(Yb, Ypb, dc, d0, t3, Npd, Kp3,
                                                  nWork, rowsV, Mpad3);
      gemm_mfma<64,64><<<dim3(1, (int)(Mpad3/64)), 256, 0, stream>>>(
          Ypb, Ut3_i, Z2f, nullptr, nullptr, 0.f, 0.f, 10, lamS, 64, Kp3, 0, 0, 0);

      redmax2_atomic<<<1, 64, 0, stream>>>((unsigned*)lamS, W + INVLAM, W + FE, w, out);
      permute_scale2c<<<dim3(t1, 4), 256, 7*t3*dc*2, stream>>>(
          Z2f, (ushort*)Tnext, W + INVLAM, dc, t3);
    }

    float* tmp = Tcur; Tcur = Tnext; Tnext = tmp;
  }
}

// Round 6
// 1248.630 us; speedup vs baseline: 4.5462x; 1.3534x over previous
//
#include <hip/hip_runtime.h>

// ============================================================================
// HOTRG (2D Ising) — R6: P-direct GEMM2 A-read (no X2), fused K3 (permute+
// GEMM+absmax in one kernel), fe/lam folded into permute_scale, bf16 group-B
// expm, batched U-operand builds.
// ============================================================================

#define TEMPC 2.269f

typedef unsigned int uint32;
typedef short short8b __attribute__((ext_vector_type(8)));
typedef float f32x4 __attribute__((ext_vector_type(4)));
typedef unsigned short ushort8v __attribute__((ext_vector_type(8)));

__device__ __forceinline__ ushort f2bf(float x) {
  uint32 u = __float_as_uint(x);
  u = (u + 0x7FFFu + ((u >> 16) & 1u)) >> 16;
  return (ushort)u;
}
__device__ __forceinline__ float toF(float x) { return x; }
__device__ __forceinline__ float toF(ushort h) { return __uint_as_float(((uint32)h) << 16); }

__device__ __forceinline__ void gll16(const ushort* g, ushort* l) {
  __builtin_amdgcn_global_load_lds((const __attribute__((address_space(1))) void*)g,
                                   (__attribute__((address_space(3))) void*)l, 16, 0, 0);
}

// ---------------- MFMA GEMM ----------------
// C = A @ B; B K-major [N][Kp]. A row-major [M][Kp] (PD=false) or P-layout
// (PD=true): A(r,k) = P[((k>>npl)*dcD + r%dcD)*sP + (r/dcD)<<npl | (k&npad-1)].
// mode: 1=add cA*Aadd+cI*I, 2=write Cf(f32), 4=write Cb(bf16).
template<int BM, int BN, bool PD>
__global__ __launch_bounds__(256) void gemm_mfma(
    const ushort* __restrict__ A, const ushort* __restrict__ Bt,
    float* __restrict__ Cf, ushort* __restrict__ Cb,
    const float* __restrict__ Aadd, float cA, float cI, int mode,
    int Np, int Kp, long sA, long sB, long sC,
    int sP, int npl, int dcD)
{
  constexpr int FRM = BM / 32, FRN = BN / 32;
  constexpr int LA = BM / 8, LB = BN / 8, LPW = (LA + LB) / 4;
  __shared__ __align__(16) ushort As[BM * 64];
  __shared__ __align__(16) ushort Bs[BN * 64];
  const int tid = threadIdx.x;
  const int wid = tid >> 6, lane = tid & 63;

  // bijective XCD-chunk swizzle over flattened grid
  const long gxy = (long)gridDim.x * gridDim.y;
  const long tot = gxy * gridDim.z;
  const long flat = ((long)blockIdx.z * gridDim.y + blockIdx.y) * gridDim.x + blockIdx.x;
  const long q = tot >> 3, r = tot & 7;
  const long xcd = flat & 7, off = flat >> 3;
  const long swz = (xcd < r) ? (xcd * (q + 1) + off) : (r * (q + 1) + (xcd - r) * q + off);
  const int bz = (int)(swz / gxy);
  const long rem = swz - (long)bz * gxy;
  const int by = (int)(rem / gridDim.x);
  const int bx = (int)(rem - (long)by * gridDim.x);

  const int m0 = by * BM, n0 = bx * BN;
  const int wm0 = (wid >> 1) * (BM / 2), wn0 = (wid & 1) * (BN / 2);
  const int rl = lane & 15, cb = lane >> 4;
  const ushort* Ap = A + (long)bz * sA + (long)m0 * Kp;
  const ushort* Bp = Bt + (long)bz * sB + (long)n0 * Kp;

  int pdBase[LPW];
  int dsp = 0;
  if (PD) {
    dsp = dcD * sP;
    const int npad = 1 << npl;
    #pragma unroll
    for (int t = 0; t < LPW; ++t) {
      int gl = wid * LPW + t;
      pdBase[t] = 0;
      if (gl < LA) {
        int li = gl * 64 + lane;
        int rr = li >> 3, ch = li & 7;
        int sch = ch ^ (rr & 7);
        int row = m0 + rr;
        int bmq = row / dcD, rm = row - bmq * dcD;
        int joff = (sch * 8) >> npl, noff = (sch * 8) & (npad - 1);
        pdBase[t] = (joff * dcD + rm) * sP + bmq * npad + noff;
      }
    }
  }

  f32x4 acc[FRM][FRN];
  #pragma unroll
  for (int i = 0; i < FRM; ++i)
    #pragma unroll
    for (int j = 0; j < FRN; ++j) { acc[i][j][0]=0.f; acc[i][j][1]=0.f; acc[i][j][2]=0.f; acc[i][j][3]=0.f; }

  for (int k0 = 0; k0 < Kp; k0 += 64) {
    #pragma unroll
    for (int t = 0; t < LPW; ++t) {
      int gl = wid * LPW + t;
      int isA = gl < LA;
      int tt = isA ? gl : gl - LA;
      int li = tt * 64 + lane;
      int rr = li >> 3, ch = li & 7;
      int sch = ch ^ (rr & 7);
      if (isA) {
        if (PD) gll16(A + (long)pdBase[t] + (long)(k0 >> npl) * dsp, &As[tt * 512]);
        else    gll16(Ap + (long)rr * Kp + k0 + sch * 8, &As[tt * 512]);
      } else {
        gll16(Bp + (long)rr * Kp + k0 + sch * 8, &Bs[tt * 512]);
      }
    }
    __syncthreads();
    #pragma unroll
    for (int km = 0; km < 2; ++km) {
      short8b af[FRM], bfv[FRN];
      #pragma unroll
      for (int i = 0; i < FRM; ++i) {
        int rr = wm0 + i * 16 + rl;
        af[i] = *(const short8b*)&As[rr * 64 + ((((km << 2) | cb) ^ (rr & 7)) << 3)];
      }
      #pragma unroll
      for (int j = 0; j < FRN; ++j) {
        int rr = wn0 + j * 16 + rl;
        bfv[j] = *(const short8b*)&Bs[rr * 64 + ((((km << 2) | cb) ^ (rr & 7)) << 3)];
      }
      #pragma unroll
      for (int i = 0; i < FRM; ++i)
        #pragma unroll
        for (int j = 0; j < FRN; ++j)
          acc[i][j] = __builtin_amdgcn_mfma_f32_16x16x32_bf16(af[i], bfv[j], acc[i][j], 0, 0, 0);
    }
    __syncthreads();
  }
  const int r4 = (lane >> 4) * 4, cl = lane & 15;
  #pragma unroll
  for (int i = 0; i < FRM; ++i) {
    #pragma unroll
    for (int j = 0; j < FRN; ++j) {
      int row0 = m0 + wm0 + i * 16 + r4;
      int col  = n0 + wn0 + j * 16 + cl;
      #pragma unroll
      for (int qq = 0; qq < 4; ++qq) {
        long off2 = (long)bz * sC + (long)(row0 + qq) * Np + col;
        float v = acc[i][j][qq];
        if (mode & 1) v += cA * Aadd[off2] + ((row0 + qq) == col ? cI : 0.0f);
        if (mode & 2) Cf[off2] = v;
        if (mode & 4) Cb[off2] = f2bf(v);
      }
    }
  }
}

// ---------------- transpose -> bf16 K-major with zero K-pad (expm use) ------
template<typename TI>
__global__ __launch_bounds__(256) void trans_to_bfT(const TI* __restrict__ in, ushort* __restrict__ out,
                                                    int R, int C, int inStride, int outStride, int Rpad,
                                                    long sIn, long sOut)
{
  __shared__ float sm[32][33];
  const TI* ip = in + (long)blockIdx.z * sIn;
  ushort* op = out + (long)blockIdx.z * sOut;
  int c0 = blockIdx.x * 32, r0 = blockIdx.y * 32;
  int lx = threadIdx.x & 31, ly = threadIdx.x >> 5;
  #pragma unroll
  for (int yy = 0; yy < 4; ++yy) {
    int r = r0 + ly + yy * 8, c = c0 + lx;
    if (r < R && c < C) sm[ly + yy * 8][lx] = toF(ip[(long)r * inStride + c]);
  }
  __syncthreads();
  #pragma unroll
  for (int yy = 0; yy < 4; ++yy) {
    int orow = c0 + ly + yy * 8;
    int ocol = r0 + lx;
    if (orow < C && ocol < Rpad) {
      ushort v = 0;
      if (ocol < R) v = f2bf(sm[lx][ly + yy * 8]);
      op[(long)orow * outStride + ocol] = v;
    }
  }
}

// ---------------- step operand builders ----------------
// Ttk[(bm<<npl | n)][ii] = T[ii][(bm,n)]; zero for ii>=d0 or n>=t3.
template<typename TT>
__global__ __launch_bounds__(256) void transTk2(const TT* __restrict__ T, ushort* __restrict__ out,
                                                int d0, int t3, int npl, long R1, long R1p)
{
  long idx = (long)blockIdx.x * 256 + threadIdx.x;
  if (idx >= R1p * 64) return;
  long rp = idx >> 6; int ii = (int)(idx & 63);
  long bm = rp >> npl; int n = (int)(rp & ((1 << npl) - 1));
  ushort v = 0;
  if (ii < d0 && n < t3) v = f2bf(toF(T[(long)ii * R1 + bm * t3 + n]));
  out[idx] = v;
}

// B2[(p*t3+e)][(j<<npl | n)] = T[((j*t3+n)*t2+p)*t3+e]; n>=t3 -> 0.
template<typename TI>
__global__ __launch_bounds__(256) void build_B2(const TI* __restrict__ in, ushort* __restrict__ out,
                                                int t2, int t3, int d0, int npl, int Kp2, int Nr)
{
  __shared__ float sm[32][33];
  const int npad = 1 << npl;
  int oc0 = blockIdx.x * 32, or0 = blockIdx.y * 32;
  int lx = threadIdx.x & 31, ly = threadIdx.x >> 5;
  #pragma unroll
  for (int yy = 0; yy < 4; ++yy) {
    int ocol = oc0 + ly + yy * 8;
    int orow = or0 + lx;
    float v = 0.f;
    int j = ocol >> npl, n = ocol & (npad - 1);
    if (n < t3 && orow < Nr && j < d0) {
      int p = orow / t3, e = orow - p * t3;
      v = toF(in[((long)(j * t3 + n) * t2 + p) * t3 + e]);
    }
    sm[ly + yy * 8][lx] = v;
  }
  __syncthreads();
  #pragma unroll
  for (int yy = 0; yy < 4; ++yy) {
    int orow = or0 + ly + yy * 8;
    int ocol = oc0 + lx;
    if (orow < Nr) out[(long)orow * Kp2 + ocol] = f2bf(sm[lx][ly + yy * 8]);
  }
}

// Ut1[(j,a)][ii] = U[ii][j][a]; batched over blockIdx.y.
__global__ __launch_bounds__(256) void build_ut1(const float* __restrict__ U, ushort* __restrict__ out,
                                                 int d0, int dc, int Mpad, long uStr, long oStr)
{
  const int bt = blockIdx.y;
  int idx = blockIdx.x * 256 + threadIdx.x;
  if (idx >= Mpad * 64) return;
  int ja = idx >> 6, ii = idx & 63;
  ushort v = 0;
  if (ii < d0 && ja < d0 * dc) {
    int j = ja / dc, a = ja - j * dc;
    v = f2bf(U[bt * uStr + ((long)ii * d0 + j) * dc + a]);
  }
  out[bt * oStr + idx] = v;
}

// Ut3[c][(m,p)] = U[(m,p)][c]; rows>=dc and cols>=d0*d0 zeroed; batched.
__global__ __launch_bounds__(256) void build_ut3(const float* __restrict__ U, ushort* __restrict__ out,
                                                 int d0, int dc, int Kp3, long uStr, long oStr)
{
  const int bt = blockIdx.y;
  int idx = blockIdx.x * 256 + threadIdx.x;
  if (idx >= 64 * Kp3) return;
  int c = idx / Kp3, mp = idx - c * Kp3;
  ushort v = 0;
  if (c < dc && mp < d0 * d0) v = f2bf(U[bt * uStr + (long)mp * dc + c]);
  out[bt * oStr + idx] = v;
}

// ---------------- fused K3: Z[(b,a,e)][c] = sum_{m,p} Y * U3, absmax ----
template<int KPG>
__global__ __launch_bounds__(256) void k3_fused(
    const ushort* __restrict__ Y, const ushort* __restrict__ Ut3,
    float* __restrict__ Z2, unsigned* __restrict__ lamslot,
    int d0, int t2, int t3, int dc, int NpY)
{
  __shared__ __align__(16) ushort sYt[32 * KPG];
  const int tid = threadIdx.x;
  const int wid = tid >> 6, lane = tid & 63;
  const int b = blockIdx.x / dc, a = blockIdx.x - b * dc;
  for (int i8 = tid; i8 < 32 * KPG / 8; i8 += 256) *(ushort8v*)&sYt[i8 * 8] = ushort8v{};
  __syncthreads();
  const int nv = NpY / 8;
  for (int idx = tid; idx < t2 * nv; idx += 256) {
    int m = idx / nv, v = idx - m * nv;
    int col0 = v * 8;
    ushort8v val = *(const ushort8v*)(Y + ((long)(b * t2 + m) * dc + a) * NpY + col0);
    #pragma unroll
    for (int u = 0; u < 8; ++u) {
      int col = col0 + u;
      int p = (t3 == 16) ? (col >> 4) : ((col * 9363) >> 18);
      if (p < t2) {
        int e = col - p * t3;
        int k = m * d0 + p;
        sYt[e * KPG + ((((k >> 3) ^ (e & 7)) << 3) | (k & 7))] = val[u];
      }
    }
  }
  __syncthreads();
  const int kpw = KPG / 4, k0w = wid * kpw;
  const int rl = lane & 15, cb = lane >> 4;
  f32x4 acc[2][2];
  #pragma unroll
  for (int i = 0; i < 2; ++i)
    #pragma unroll
    for (int j = 0; j < 2; ++j) { acc[i][j][0]=0.f; acc[i][j][1]=0.f; acc[i][j][2]=0.f; acc[i][j][3]=0.f; }
  for (int kk = 0; kk < kpw; kk += 32) {
    int kb = k0w + kk + cb * 8;
    short8b af[2], bfv[2];
    #pragma unroll
    for (int i = 0; i < 2; ++i) {
      int e = i * 16 + rl;
      af[i] = *(const short8b*)&sYt[e * KPG + (((kb >> 3) ^ (e & 7)) << 3)];
      bfv[i] = *(const short8b*)(Ut3 + (long)(i * 16 + rl) * KPG + kb);
    }
    #pragma unroll
    for (int i = 0; i < 2; ++i)
      #pragma unroll
      for (int j = 0; j < 2; ++j)
        acc[i][j] = __builtin_amdgcn_mfma_f32_16x16x32_bf16(af[i], bfv[j], acc[i][j], 0, 0, 0);
  }
  __syncthreads();
  float* Lp = (float*)sYt;
  #pragma unroll
  for (int i = 0; i < 2; ++i)
    #pragma unroll
    for (int j = 0; j < 2; ++j)
      #pragma unroll
      for (int qq = 0; qq < 4; ++qq) {
        int e32 = i * 16 + (lane >> 4) * 4 + qq;
        int c32 = j * 16 + (lane & 15);
        Lp[wid * 1024 + e32 * 32 + c32] = acc[i][j][qq];
      }
  __syncthreads();
  float mx = 0.f;
  for (int idx = tid; idx < 1024; idx += 256) {
    float z = Lp[idx] + Lp[1024 + idx] + Lp[2048 + idx] + Lp[3072 + idx];
    int e = idx >> 5, c = idx & 31;
    if (e < t3 && c < dc) {
      Z2[((long)(b * dc + a) * t3 + e) * 64 + c] = z;
      mx = fmaxf(mx, fabsf(z));
    }
  }
  __syncthreads();
  Lp[tid] = mx;
  __syncthreads();
  for (int s = 128; s > 0; s >>= 1) {
    if (tid < s) Lp[tid] = fmaxf(Lp[tid], Lp[tid + s]);
    __syncthreads();
  }
  if (tid == 0) atomicMax(lamslot, __float_as_uint(Lp[0]));
}

// ---- T'[b,c,e,a](bf16) = Z2/lam; fe/out update by block (0,0) ----
__global__ __launch_bounds__(256) void permute_scale2d(const float* __restrict__ Z2, ushort* __restrict__ Tn,
                                                       const unsigned* __restrict__ lamslot,
                                                       float* __restrict__ fe, float w, float* __restrict__ dout,
                                                       int dc, int t3)
{
  extern __shared__ char dynC[];
  ushort* sm = (ushort*)dynC;
  const int b = blockIdx.x;
  const int c0 = blockIdx.y * 7;
  const int tid = threadIdx.x;
  const float lam = __uint_as_float(*lamslot);
  const float s = 1.0f / lam;
  if (b == 0 && blockIdx.y == 0 && tid == 0) {
    float f = fe[0] - w * logf(lam);
    fe[0] = f; dout[0] = f;
  }
  const int TD = t3 * dc;
  const int tot = dc * t3 * 7;
  for (int idx = tid; idx < tot; idx += 256) {
    int c7 = idx % 7; int rm = idx / 7;
    int e = rm % t3; int a = rm / t3;
    float v = Z2[(((long)(b * dc + a)) * t3 + e) * 64 + c0 + c7] * s;
    sm[(c7 * t3 + e) * dc + a] = f2bf(v);
  }
  __syncthreads();
  const long ob = (long)(b * dc + c0) * TD;
  for (int idx = tid; idx < tot / 8; idx += 256)
    *(ushort8v*)(Tn + ob + idx * 8) = *(ushort8v*)(sm + idx * 8);
}

// ---------------- expm builders (bf16 MFMA path) ----------------
__global__ __launch_bounds__(256) void build_A2(const float* __restrict__ Aflat, float* __restrict__ Af,
                                                ushort* __restrict__ Ab, ushort* __restrict__ An,
                                                int n, int Np, long aoff, long tri, float sc)
{
  const int b = blockIdx.y;
  const long nn = (long)Np * Np;
  const long id = (long)blockIdx.x * 256 + threadIdx.x;
  if (id >= nn) return;
  const int r = (int)(id / Np), c = (int)(id % Np);
  float v = 0.0f;
  if (r < n && c < n) {
    if (c > r)      v =  Aflat[aoff + b * tri + (long)r * (n - 1) - (long)r * (r - 1) / 2 + (c - r - 1)] * sc;
    else if (c < r) v = -Aflat[aoff + b * tri + (long)c * (n - 1) - (long)c * (c - 1) / 2 + (r - c - 1)] * sc;
  }
  long o = b * nn + id;
  Af[o] = v; Ab[o] = f2bf(v); An[o] = f2bf(-v);
}

__global__ __launch_bounds__(256) void axpy_q2(const ushort* __restrict__ A2b, const float* __restrict__ Af,
                                               ushort* __restrict__ Qb, int Np)
{
  const int b = blockIdx.y;
  const long nn = (long)Np * Np;
  const long id = (long)blockIdx.x * 256 + threadIdx.x;
  if (id >= nn) return;
  const int r = (int)(id / Np), c = (int)(id % Np);
  long o = b * nn + id;
  float v = (1.0f/40320.0f) * toF(A2b[o]) + (1.0f/5040.0f) * Af[o] + ((r == c) ? (1.0f/720.0f) : 0.0f);
  Qb[o] = f2bf(v);
}

__global__ __launch_bounds__(256) void extract_u2(const float* __restrict__ E, float* __restrict__ W,
                                                  int n, int dcut, int rowStride, long ubase, long ustride, long estride)
{
  const int b = blockIdx.y;
  const long tot = (long)n * dcut;
  const long id = (long)blockIdx.x * 256 + threadIdx.x;
  if (id >= tot) return;
  const int rr = (int)(id / dcut), aa = (int)(id % dcut);
  W[ubase + b * ustride + id] = E[b * estride + (long)rr * rowStride + aa];
}

// ---------------- small expm (n<=16) ----------------
struct SmallStep { int n, d0, dcut, s; long aoff; long uoff; };
struct SmallStep4 { SmallStep st[4]; };

__global__ __launch_bounds__(256) void expm_small_kernel(const float* __restrict__ Aflat,
                                                         float* __restrict__ W, SmallStep4 ps)
{
  SmallStep p = ps.st[blockIdx.x];
  const int n = p.n, nn = n * n;
  __shared__ float As[256], A2[256], Qa[256], Qb[256];
  const int tid = threadIdx.x;
  const int r = (tid < nn) ? (tid / n) : 0;
  const int c = (tid < nn) ? (tid % n) : 0;
  const float sc = 1.0f / (float)(1 << p.s);
  if (tid < nn) {
    float v = 0.0f;
    if (c > r)      v =  Aflat[p.aoff + (long)r*(n-1) - (long)r*(r-1)/2 + (c - r - 1)] * sc;
    else if (c < r) v = -Aflat[p.aoff + (long)c*(n-1) - (long)c*(c-1)/2 + (r - c - 1)] * sc;
    As[tid] = v;
  }
  __syncthreads();
  if (tid < nn) {
    float s2 = 0.0f;
    for (int k = 0; k < n; ++k) s2 += As[r*n+k] * As[k*n+c];
    A2[tid] = s2;
  }
  __syncthreads();
  if (tid < nn)
    Qa[tid] = (1.0f/40320.0f)*A2[tid] + (1.0f/5040.0f)*As[tid] + ((r==c) ? (1.0f/720.0f) : 0.0f);
  __syncthreads();
  float* qp = Qa; float* qn = Qb;
  const float cis[3] = {1.0f/24.0f, 0.5f, 1.0f};
  const float cas[3] = {1.0f/120.0f, 1.0f/6.0f, 1.0f};
  #pragma unroll
  for (int it = 0; it < 3; ++it) {
    if (tid < nn) {
      float s2 = 0.0f;
      for (int k = 0; k < n; ++k) s2 += A2[r*n+k] * qp[k*n+c];
      qn[tid] = s2 + cas[it]*As[tid] + ((r==c) ? cis[it] : 0.0f);
    }
    __syncthreads();
    float* t = qp; qp = qn; qn = t;
  }
  for (int it = 0; it < p.s; ++it) {
    float s2 = 0.0f;
    if (tid < nn) { for (int k = 0; k < n; ++k) s2 += qp[r*n+k] * qp[k*n+c]; }
    if (tid < nn) qn[tid] = s2;
    __syncthreads();
    float* t = qp; qp = qn; qn = t;
  }
  if (tid < n * p.dcut) {
    int rr = tid / p.dcut, aa = tid % p.dcut;
    W[p.uoff + tid] = qp[rr*n + aa];
  }
}

// ---------------- fp32 GEMM (steps 0-3 only) ----------------
template<int BM, int BN, int BK, int TM, int TN>
__global__ __launch_bounds__(256) void gemm_f32(
    const float* __restrict__ A, const float* __restrict__ B, float* __restrict__ C,
    int M, int N, int K)
{
  constexpr int PAD = 4;
  __shared__ float As[BK][BM + PAD];
  __shared__ float Bs[BK][BN + PAD];
  const int tid = threadIdx.x;
  const int m0 = blockIdx.y * BM, n0 = blockIdx.x * BN;
  constexpr int TX = BN / TN;
  const int tx = tid % TX, ty = tid / TX;
  float acc[TM][TN];
  #pragma unroll
  for (int i = 0; i < TM; ++i)
    #pragma unroll
    for (int j = 0; j < TN; ++j) acc[i][j] = 0.0f;

  const int a_m = tid / (BK / 4);
  const int a_k = (tid % (BK / 4)) * 4;
  const int b_k = tid / (BN / 4);
  const int b_n = (tid % (BN / 4)) * 4;

  for (int k0 = 0; k0 < K; k0 += BK) {
    float4 av = make_float4(0.f, 0.f, 0.f, 0.f);
    if (m0 + a_m < M && k0 + a_k < K)
      av = *(const float4*)(A + (long)(m0 + a_m) * K + k0 + a_k);
    As[a_k + 0][a_m] = av.x; As[a_k + 1][a_m] = av.y;
    As[a_k + 2][a_m] = av.z; As[a_k + 3][a_m] = av.w;
    float4 bv = make_float4(0.f, 0.f, 0.f, 0.f);
    if (k0 + b_k < K && n0 + b_n < N)
      bv = *(const float4*)(B + (long)(k0 + b_k) * N + n0 + b_n);
    *(float4*)&Bs[b_k][b_n] = bv;
    __syncthreads();
    #pragma unroll
    for (int kk = 0; kk < BK; ++kk) {
      float af[TM], bf[TN];
      #pragma unroll
      for (int i = 0; i < TM; i += 4) *(float4*)&af[i] = *(const float4*)&As[kk][ty*TM + i];
      #pragma unroll
      for (int j = 0; j < TN; j += 4) *(float4*)&bf[j] = *(const float4*)&Bs[kk][tx*TN + j];
      #pragma unroll
      for (int i = 0; i < TM; ++i)
        #pragma unroll
        for (int j = 0; j < TN; ++j)
          acc[i][j] = fmaf(af[i], bf[j], acc[i][j]);
    }
    __syncthreads();
  }
  #pragma unroll
  for (int i = 0; i < TM; ++i) {
    int row = m0 + ty*TM + i;
    if (row >= M) continue;
    #pragma unroll
    for (int j = 0; j < TN; ++j) {
      int col = n0 + tx*TN + j;
      if (col >= N) continue;
      C[(long)row * N + col] = acc[i][j];
    }
  }
}

// ---------------- fp32 contraction kernels (steps 0-3 only) ----------------
__global__ __launch_bounds__(256) void k1_kernel2(const float* __restrict__ T, const float* __restrict__ U,
                                                  float* __restrict__ X2f,
                                                  int t1, int t2, int t3, int d0, int dcut, int K)
{
  extern __shared__ char dyn3[];
  float* lds = (float*)dyn3;
  float* Ts = lds;
  float* Us = lds + d0 * t3;
  const int tid = threadIdx.x;
  const int bm = blockIdx.x;
  const long tstride = (long)t1 * t2 * t3;
  const long tbase = (long)bm * t3;
  for (int idx = tid; idx < d0 * t3; idx += 256) {
    int i = idx / t3, nn = idx % t3;
    Ts[idx] = T[(long)i * tstride + tbase + nn];
  }
  const int nout = dcut * t3;
  __syncthreads();
  for (int j = 0; j < d0; ++j) {
    for (int idx = tid; idx < d0 * dcut; idx += 256)
      Us[idx] = U[((long)(idx / dcut) * d0 + j) * dcut + (idx % dcut)];
    __syncthreads();
    for (int idx = tid; idx < nout; idx += 256) {
      int a = idx / t3, nn = idx % t3;
      float s = 0.0f;
      for (int i = 0; i < d0; ++i) s += Ts[i*t3 + nn] * Us[i*dcut + a];
      X2f[((long)bm * dcut + a) * K + j * t3 + nn] = s;
    }
    __syncthreads();
  }
}

__global__ __launch_bounds__(256) void k3_kernel2(const float* __restrict__ Y, const float* __restrict__ U,
                                                  float* __restrict__ Z, int t1, int t2, int t3, int d0, int dcut,
                                                  int Ystride)
{
  extern __shared__ char dyn4[];
  float* lds = (float*)dyn4;
  float* Ys = lds;
  float* Us = lds + d0 * t3;
  const int tid = threadIdx.x;
  const int ba = blockIdx.x;
  const int b = ba / dcut, a = ba % dcut;
  const int nout = dcut * t3;
  float acc[4] = {0.f, 0.f, 0.f, 0.f};
  for (int m = 0; m < t2; ++m) {
    const long yrow = ((long)(b*t2 + m) * dcut + a) * Ystride;
    for (int idx = tid; idx < d0 * t3; idx += 256) Ys[idx] = Y[yrow + idx];
    for (int idx = tid; idx < d0 * dcut; idx += 256) Us[idx] = U[(long)m * d0 * dcut + idx];
    __syncthreads();
    #pragma unroll
    for (int o = 0; o < 4; ++o) {
      int idx = tid + o * 256;
      if (idx < nout) {
        int cc = idx / t3, e = idx % t3;
        float s = 0.0f;
        for (int p = 0; p < d0; ++p) s += Ys[p*t3 + e] * Us[p*dcut + cc];
        acc[o] += s;
      }
    }
    __syncthreads();
  }
  #pragma unroll
  for (int o = 0; o < 4; ++o) {
    int idx = tid + o * 256;
    if (idx < nout) {
      int cc = idx / t3, e = idx % t3;
      Z[(((long)a * t1 + b) * dcut + cc) * t3 + e] = acc[o];
    }
  }
}

// ---------------- reductions / permute / init (steps 0-3) ----------------
__global__ __launch_bounds__(256) void redmax1_kernel(const float* __restrict__ Z, long cnt, float* __restrict__ part)
{
  __shared__ float sm[256];
  float v = 0.0f;
  for (long i = (long)blockIdx.x * 256 + threadIdx.x; i < cnt; i += (long)gridDim.x * 256)
    v = fmaxf(v, fabsf(Z[i]));
  sm[threadIdx.x] = v; __syncthreads();
  for (int s = 128; s > 0; s >>= 1) {
    if ((int)threadIdx.x < s) sm[threadIdx.x] = fmaxf(sm[threadIdx.x], sm[threadIdx.x + s]);
    __syncthreads();
  }
  if (threadIdx.x == 0) part[blockIdx.x] = sm[0];
}

__global__ __launch_bounds__(256) void redmax2_kernel(const float* __restrict__ part, float* __restrict__ invlam,
                                                      float* __restrict__ fe, float w, float* __restrict__ dout)
{
  __shared__ float sm[256];
  sm[threadIdx.x] = part[threadIdx.x]; __syncthreads();
  for (int s = 128; s > 0; s >>= 1) {
    if ((int)threadIdx.x < s) sm[threadIdx.x] = fmaxf(sm[threadIdx.x], sm[threadIdx.x + s]);
    __syncthreads();
  }
  if (threadIdx.x == 0) {
    float lam = sm[0];
    invlam[0] = 1.0f / lam;
    float f = fe[0] - w * logf(lam);
    fe[0] = f;
    dout[0] = f;
  }
}

__global__ __launch_bounds__(256) void permute_scale_kernel(const float* __restrict__ Z, float* __restrict__ Tn,
                                                            const float* __restrict__ invlam, int t1, int t3, int dcut)
{
  extern __shared__ char dyn5[];
  float* lds = (float*)dyn5;
  const int tid = threadIdx.x;
  const int bc = blockIdx.x;
  const int b = bc / dcut, c = bc % dcut;
  const float s = invlam[0];
  const int tot = dcut * t3;
  for (int idx = tid; idx < tot; idx += 256) {
    int a = idx / t3, e = idx % t3;
    lds[idx] = Z[(((long)a * t1 + b) * dcut + c) * t3 + e] * s;
  }
  __syncthreads();
  const long ob = (long)bc * t3 * dcut;
  for (int idx = tid; idx < tot; idx += 256) {
    int e = idx / dcut, a = idx % dcut;
    Tn[ob + idx] = lds[a * t3 + e];
  }
}

__global__ void init_kernel(const float* __restrict__ T0, float* __restrict__ Tdst, float* __restrict__ W)
{
  int t = threadIdx.x;
  if (t < 16) Tdst[t] = T0[t];
  if (t == 0) W[0] = 0.0f;                               // FE
  if (t >= 8 && t < 20) ((unsigned*)W)[t] = 0u;          // 12 lam slots
}

// ============================================================================
extern "C" void kernel_launch(void* const* d_in, const int* in_sizes, int n_in,
                              void* d_out, int out_size, void* d_ws, size_t ws_size,
                              hipStream_t stream)
{
  const float* Aflat = (const float*)d_in[0];
  const float* T0    = (const float*)d_in[1];
  float* out = (float*)d_out;
  float* W = (float*)d_ws;
  (void)ws_size; (void)in_sizes; (void)n_in; (void)out_size;

  const int SH_n[12]  = {4,4,16,16,256,256,784,784,784,784,784,784};
  const int SH_d0[12] = {2,2,4,4,16,16,28,28,28,28,28,28};
  const int SH_dc[12] = {4,4,16,16,28,28,28,28,28,28,28,28};
  long aoff[12]; { long o = 0; for (int i = 0; i < 12; ++i) { aoff[i] = o; o += (long)SH_n[i]*(SH_n[i]-1)/2; } }
  long uoff[12]; { long o = 1024; for (int i = 0; i < 12; ++i) { uoff[i] = o; o += (long)SH_d0[i]*SH_d0[i]*SH_dc[i]; } }
  int T1d[12], T2d[12], T3d[12], T0d[12];
  { int a=2,b=2,c=2,d=2;
    for (int i = 0; i < 12; ++i) { T0d[i]=a; T1d[i]=b; T2d[i]=c; T3d[i]=d;
      int dc = SH_dc[i]; int na=b, nb=dc, nc=d, nd=dc; a=na; b=nb; c=nc; d=nd; } }

  // ---- workspace layout (float units) ----
  const long FE = 0, INVLAM = 1, LAMV = 8, PART = 64;
  const long TA   = 150016;
  const long TB   = TA + 614656;           // 764672
  const long Z2o  = TB + 614656;           // 1379328 (1,409,024)
  const long TTK  = Z2o + 1409024;         // 2788352 (802,816 fl = R1p x 64 ush)
  const long TTo  = TTK + 802816;          // 3591168 (401,408 fl: B2 896x896 ush)
  const long UT1o = TTo + 401408;          // 3992576 (212,992 fl)
  const long UT3o = UT1o + 212992;         // 4205568 (229,376 fl: 8 x 64x896 ush)
  const long BIG0 = UT3o + 229376;         // 4434944: P (10,436,608 fl)
  const long BIG2 = BIG0 + 10500000;       // Y (9,863,168 fl)
  const long X2F  = BIG2 + 9863168;        // steps<4 X2 (65,536)
  const long YFo  = X2F + 100000;          // steps<4 Y (65,536)
  // phase-1 overlay (time-disjoint with P/Y):
  const long P_Af  = BIG0;                 // 6 x 802816
  const long P_S4  = BIG0 + 4816896;       // 6 x 896x64 f32
  const long P_bf  = BIG0 + 5200000;       // 6 bf16 bufs x 2,408,448
  const long P_Ab  = P_bf;
  const long P_An  = P_bf + 2408448;
  const long P_A2b = P_bf + 2*2408448;
  const long P_Q0  = P_bf + 3*2408448;
  const long P_Q1  = P_bf + 4*2408448;
  const long P_QT  = P_bf + 5*2408448;
  const long P_Bb  = BIG0 + 19700000;      // group-B overlay
  const long B_Af  = P_Bb;                 // 2 x 65536 f32
  const long B_S4  = P_Bb + 131072;        // 2 x 256x64 f32
  const long B_Ab  = P_Bb + 163840;        // bf16 bufs: 2x65536 ush = 65536 fl each
  const long B_An  = B_Ab + 65536;
  const long B_A2b = B_An + 65536;
  const long B_Q0  = B_A2b + 65536;
  const long B_Q1  = B_Q0 + 65536;
  const long B_QT  = B_Q1 + 65536;

  const float c5 = 1.0f/120.0f, c4 = 1.0f/24.0f, c3 = 1.0f/6.0f, c2 = 0.5f;

  ushort* TTKp = (ushort*)(W + TTK);
  ushort* B2b  = (ushort*)(W + TTo);
  ushort* UT1p = (ushort*)(W + UT1o);
  ushort* UT3p = (ushort*)(W + UT3o);
  ushort* Pb   = (ushort*)(W + BIG0);
  ushort* Yb   = (ushort*)(W + BIG2);
  float*  X2F_ = W + X2F;
  float*  YF_  = W + YFo;
  float*  Z2f  = W + Z2o;
  unsigned* lamV = (unsigned*)(W + LAMV);

  // ================= Phase 1: U matrices =================
  {
    SmallStep4 sp;
    const int ss[4] = {0,0,1,1};
    for (int i = 0; i < 4; ++i) {
      sp.st[i].n = SH_n[i]; sp.st[i].d0 = SH_d0[i]; sp.st[i].dcut = SH_dc[i];
      sp.st[i].s = ss[i]; sp.st[i].aoff = aoff[i]; sp.st[i].uoff = uoff[i];
    }
    expm_small_kernel<<<4, 256, 0, stream>>>(Aflat, W, sp);
  }

  // ---- group A: steps 6-11 (n=784 -> Np=896, batch 6, s=2, Taylor-8) ----
  {
    const int n = 784, Np = 896, bt = 6;
    const long NN = (long)Np * Np;
    float* Af = W + P_Af;  float* S4 = W + P_S4;
    ushort* Ab = (ushort*)(W + P_Ab);  ushort* An = (ushort*)(W + P_An);
    ushort* A2b = (ushort*)(W + P_A2b);
    ushort* Q0 = (ushort*)(W + P_Q0);  ushort* Q1 = (ushort*)(W + P_Q1);
    ushort* QT = (ushort*)(W + P_QT);
    dim3 ge((int)((NN + 255) / 256), bt);
    build_A2<<<ge, 256, 0, stream>>>(Aflat, Af, Ab, An, n, Np, aoff[6], 306936, 0.25f);
    dim3 g(Np/128, Np/128, bt);
    dim3 gt(Np/32, Np/32, bt);
    gemm_mfma<128,128,false><<<g,256,0,stream>>>(Ab, An, nullptr, A2b, nullptr, 0.f, 0.f, 4, Np, Np, NN, NN, NN, 0,0,1);
    axpy_q2<<<ge, 256, 0, stream>>>(A2b, Af, Q0, Np);
    gemm_mfma<128,128,false><<<g,256,0,stream>>>(Q0, A2b, nullptr, Q1, Af, c5, c4, 5, Np, Np, NN, NN, NN, 0,0,1);
    gemm_mfma<128,128,false><<<g,256,0,stream>>>(Q1, A2b, nullptr, Q0, Af, c3, c2, 5, Np, Np, NN, NN, NN, 0,0,1);
    gemm_mfma<128,128,false><<<g,256,0,stream>>>(Q0, A2b, nullptr, Q1, Af, 1.f, 1.f, 5, Np, Np, NN, NN, NN, 0,0,1);
    trans_to_bfT<ushort><<<gt,256,0,stream>>>(Q1, QT, Np, Np, Np, Np, Np, NN, NN);
    gemm_mfma<128,128,false><<<g,256,0,stream>>>(Q1, QT, nullptr, Q0, nullptr, 0.f, 0.f, 4, Np, Np, NN, NN, NN, 0,0,1);
    trans_to_bfT<ushort><<<dim3(2, Np/32, bt),256,0,stream>>>(Q0, QT, Np, 64, Np, Np, Np, NN, NN);
    gemm_mfma<64,64,false><<<dim3(1, Np/64, bt),256,0,stream>>>(Q0, QT, S4, nullptr, nullptr, 0.f, 0.f, 2,
                                                                64, Np, NN, NN, 57344, 0,0,1);
    extract_u2<<<dim3(86, bt), 256, 0, stream>>>(S4, W, n, 28, 64, uoff[6], 21952, 57344);
  }

  // ---- group B: steps 4,5 (n=256, batch 2, s=2) bf16 MFMA ----
  {
    const int n = 256, Np = 256, bt = 2;
    const long NN = (long)Np * Np;
    float* Af = W + B_Af;  float* S4 = W + B_S4;
    ushort* Ab = (ushort*)(W + B_Ab);  ushort* An = (ushort*)(W + B_An);
    ushort* A2b = (ushort*)(W + B_A2b);
    ushort* Q0 = (ushort*)(W + B_Q0);  ushort* Q1 = (ushort*)(W + B_Q1);
    ushort* QT = (ushort*)(W + B_QT);
    dim3 ge((int)((NN + 255) / 256), bt);
    build_A2<<<ge, 256, 0, stream>>>(Aflat, Af, Ab, An, n, Np, aoff[4], 32640, 0.25f);
    dim3 g(Np/128, Np/128, bt);
    dim3 gt(Np/32, Np/32, bt);
    gemm_mfma<128,128,false><<<g,256,0,stream>>>(Ab, An, nullptr, A2b, nullptr, 0.f, 0.f, 4, Np, Np, NN, NN, NN, 0,0,1);
    axpy_q2<<<ge, 256, 0, stream>>>(A2b, Af, Q0, Np);
    gemm_mfma<128,128,false><<<g,256,0,stream>>>(Q0, A2b, nullptr, Q1, Af, c5, c4, 5, Np, Np, NN, NN, NN, 0,0,1);
    gemm_mfma<128,128,false><<<g,256,0,stream>>>(Q1, A2b, nullptr, Q0, Af, c3, c2, 5, Np, Np, NN, NN, NN, 0,0,1);
    gemm_mfma<128,128,false><<<g,256,0,stream>>>(Q0, A2b, nullptr, Q1, Af, 1.f, 1.f, 5, Np, Np, NN, NN, NN, 0,0,1);
    trans_to_bfT<ushort><<<gt,256,0,stream>>>(Q1, QT, Np, Np, Np, Np, Np, NN, NN);
    gemm_mfma<128,128,false><<<g,256,0,stream>>>(Q1, QT, nullptr, Q0, nullptr, 0.f, 0.f, 4, Np, Np, NN, NN, NN, 0,0,1);
    trans_to_bfT<ushort><<<dim3(2, Np/32, bt),256,0,stream>>>(Q0, QT, Np, 64, Np, Np, Np, NN, NN);
    gemm_mfma<64,64,false><<<dim3(1, Np/64, bt),256,0,stream>>>(Q0, QT, S4, nullptr, nullptr, 0.f, 0.f, 2,
                                                                64, Np, NN, NN, 16384, 0,0,1);
    extract_u2<<<dim3(28, bt), 256, 0, stream>>>(S4, W, n, 28, 64, uoff[4], 7168, 16384);
  }

  // ---- U-derived operands, batched: steps 4-5 and 6-11 ----
  build_ut1<<<dim3(208, 2), 256, 0, stream>>>(W + uoff[4], UT1p, 16, 28, 832, 7168, 832*64);
  build_ut1<<<dim3(208, 6), 256, 0, stream>>>(W + uoff[6], UT1p + 2L*832*64, 28, 28, 832, 21952, 832*64);
  build_ut3<<<dim3(64, 2), 256, 0, stream>>>(W + uoff[4], UT3p, 16, 28, 256, 7168, 64*896);
  build_ut3<<<dim3(224, 6), 256, 0, stream>>>(W + uoff[6], UT3p + 2L*64*896, 28, 28, 896, 21952, 64*896);

  // ================= Phase 2: 12 RG steps =================
  float* Tcur = W + TA;
  float* Tnext = W + TB;
  init_kernel<<<1, 256, 0, stream>>>(T0, Tcur, W);

  for (int i = 0; i < 12; ++i) {
    const int t1 = T1d[i], t2 = T2d[i], t3 = T3d[i], d0 = T0d[i], dc = SH_dc[i];
    const float* U = W + uoff[i];
    const int M = t1*t2*dc, K = d0*t3, N = t2*t3;
    const float w = TEMPC / (float)(1 << (i + 1));

    if (i < 4) {
      const int lds1 = (d0*t3 + d0*dc) * (int)sizeof(float);
      k1_kernel2<<<t1*t2, 256, lds1, stream>>>(Tcur, U, X2F_, t1, t2, t3, d0, dc, K);
      dim3 g2((N + 127) / 128, (M + 127) / 128, 1);
      gemm_f32<128,128,8,8,8><<<g2, 256, 0, stream>>>(X2F_, Tcur, YF_, M, N, K);
      const int lds3 = (d0*t3 + d0*dc) * (int)sizeof(float);
      k3_kernel2<<<t1*dc, 256, lds3, stream>>>(YF_, U, Z2f, t1, t2, t3, d0, dc, N);
      const long redCnt = (long)dc * t1 * dc * t3;
      redmax1_kernel<<<256, 256, 0, stream>>>(Z2f, redCnt, W + PART);
      redmax2_kernel<<<1, 256, 0, stream>>>(W + PART, W + INVLAM, W + FE, w, out);
      permute_scale_kernel<<<t1*dc, 256, dc*t3*(int)sizeof(float), stream>>>(
          Z2f, Tnext, W + INVLAM, t1, t3, dc);
    } else {
      const bool inBf = (i >= 5);
      const int npl = (t3 == 16) ? 4 : 5;
      const int npad = 1 << npl;
      const int Kp2 = d0 * npad;                       // 256 / 512 / 896
      const int Npd = (N + 127) / 128 * 128;           // 256 / 512 / 896
      const long R1 = (long)t1 * t2 * t3;
      const long R1p = (long)t1 * t2 * npad;
      const int Mpad1 = (d0*dc + 63)/64*64;            // 448 / 832
      const int Mpad2 = (M + 127)/128*128;
      const ushort* Ut1_i = UT1p + (long)(i-4)*832*64;
      const ushort* Ut3_i = UT3p + (long)(i-4)*64*896;
      unsigned* lam_i = lamV + (i - 4);

      // K1: Ttk (n-padded) -> P = Ut1 @ Ttk
      if (inBf) transTk2<ushort><<<(int)((R1p*64 + 255)/256), 256, 0, stream>>>(
          (const ushort*)Tcur, TTKp, d0, t3, npl, R1, R1p);
      else      transTk2<float><<<(int)((R1p*64 + 255)/256), 256, 0, stream>>>(
          Tcur, TTKp, d0, t3, npl, R1, R1p);
      gemm_mfma<64,64,false><<<dim3((int)(R1p/64), Mpad1/64), 256, 0, stream>>>(
          Ut1_i, TTKp, nullptr, Pb, nullptr, 0.f, 0.f, 4, (int)R1p, 64, 0, 0, 0, 0, 0, 1);

      // B2 (K-remapped T^T), then GEMM2 reading A directly from P
      if (inBf) build_B2<ushort><<<dim3(Kp2/32, (N + 31)/32), 256, 0, stream>>>(
          (const ushort*)Tcur, B2b, t2, t3, d0, npl, Kp2, N);
      else      build_B2<float><<<dim3(Kp2/32, (N + 31)/32), 256, 0, stream>>>(
          Tcur, B2b, t2, t3, d0, npl, Kp2, N);
      gemm_mfma<128,128,true><<<dim3(Npd/128, Mpad2/128), 256, 0, stream>>>(
          Pb, B2b, nullptr, Yb, nullptr, 0.f, 0.f, 4, Npd, Kp2, 0, 0, 0,
          (int)R1p, npl, dc);

      // fused K3 (+absmax) then permute+scale (+fe update)
      if (d0 == 16) k3_fused<256><<<t1*dc, 256, 0, stream>>>(Yb, Ut3_i, Z2f, lam_i, d0, t2, t3, dc, Npd);
      else          k3_fused<896><<<t1*dc, 256, 0, stream>>>(Yb, Ut3_i, Z2f, lam_i, d0, t2, t3, dc, Npd);
      permute_scale2d<<<dim3(t1, 4), 256, 7*t3*dc*2, stream>>>(
          Z2f, (ushort*)Tnext, lam_i, W + FE, w, out, dc, t3);
    }

    float* tmp = Tcur; Tcur = Tnext; Tnext = tmp;
  }
}

// Round 7
// 1181.030 us; speedup vs baseline: 4.8064x; 1.0572x over previous
//
#include <hip/hip_runtime.h>

// ============================================================================
// HOTRG (2D Ising) — R7: expm s=1 (one fewer full GEMM+transpose), steps 0-2
// fused into one single-block kernel, step 3 moved to unified bf16 MFMA path,
// fp32 step machinery removed. ~81 dispatches.
// ============================================================================

#define TEMPC 2.269f

typedef unsigned int uint32;
typedef short short8b __attribute__((ext_vector_type(8)));
typedef float f32x4 __attribute__((ext_vector_type(4)));
typedef unsigned short ushort8v __attribute__((ext_vector_type(8)));

__device__ __forceinline__ ushort f2bf(float x) {
  uint32 u = __float_as_uint(x);
  u = (u + 0x7FFFu + ((u >> 16) & 1u)) >> 16;
  return (ushort)u;
}
__device__ __forceinline__ float toF(float x) { return x; }
__device__ __forceinline__ float toF(ushort h) { return __uint_as_float(((uint32)h) << 16); }

__device__ __forceinline__ void gll16(const ushort* g, ushort* l) {
  __builtin_amdgcn_global_load_lds((const __attribute__((address_space(1))) void*)g,
                                   (__attribute__((address_space(3))) void*)l, 16, 0, 0);
}

// ---------------- MFMA GEMM ----------------
// C = A @ B; B K-major [N][Kp]. A row-major [M][Kp] (PD=false) or P-layout
// (PD=true): A(r,k) = P[((k>>npl)*dcD + r%dcD)*sP + (r/dcD)<<npl | (k&npad-1)].
// mode: 1=add cA*Aadd+cI*I, 2=write Cf(f32), 4=write Cb(bf16).
template<int BM, int BN, bool PD>
__global__ __launch_bounds__(256) void gemm_mfma(
    const ushort* __restrict__ A, const ushort* __restrict__ Bt,
    float* __restrict__ Cf, ushort* __restrict__ Cb,
    const float* __restrict__ Aadd, float cA, float cI, int mode,
    int Np, int Kp, long sA, long sB, long sC,
    int sP, int npl, int dcD)
{
  constexpr int FRM = BM / 32, FRN = BN / 32;
  constexpr int LA = BM / 8, LB = BN / 8, LPW = (LA + LB) / 4;
  __shared__ __align__(16) ushort As[BM * 64];
  __shared__ __align__(16) ushort Bs[BN * 64];
  const int tid = threadIdx.x;
  const int wid = tid >> 6, lane = tid & 63;

  // bijective XCD-chunk swizzle over flattened grid
  const long gxy = (long)gridDim.x * gridDim.y;
  const long tot = gxy * gridDim.z;
  const long flat = ((long)blockIdx.z * gridDim.y + blockIdx.y) * gridDim.x + blockIdx.x;
  const long q = tot >> 3, r = tot & 7;
  const long xcd = flat & 7, off = flat >> 3;
  const long swz = (xcd < r) ? (xcd * (q + 1) + off) : (r * (q + 1) + (xcd - r) * q + off);
  const int bz = (int)(swz / gxy);
  const long rem = swz - (long)bz * gxy;
  const int by = (int)(rem / gridDim.x);
  const int bx = (int)(rem - (long)by * gridDim.x);

  const int m0 = by * BM, n0 = bx * BN;
  const int wm0 = (wid >> 1) * (BM / 2), wn0 = (wid & 1) * (BN / 2);
  const int rl = lane & 15, cb = lane >> 4;
  const ushort* Ap = A + (long)bz * sA + (long)m0 * Kp;
  const ushort* Bp = Bt + (long)bz * sB + (long)n0 * Kp;

  int pdBase[LPW];
  int dsp = 0;
  if (PD) {
    dsp = dcD * sP;
    const int npad = 1 << npl;
    #pragma unroll
    for (int t = 0; t < LPW; ++t) {
      int gl = wid * LPW + t;
      pdBase[t] = 0;
      if (gl < LA) {
        int li = gl * 64 + lane;
        int rr = li >> 3, ch = li & 7;
        int sch = ch ^ (rr & 7);
        int row = m0 + rr;
        int bmq = row / dcD, rm = row - bmq * dcD;
        int joff = (sch * 8) >> npl, noff = (sch * 8) & (npad - 1);
        pdBase[t] = (joff * dcD + rm) * sP + bmq * npad + noff;
      }
    }
  }

  f32x4 acc[FRM][FRN];
  #pragma unroll
  for (int i = 0; i < FRM; ++i)
    #pragma unroll
    for (int j = 0; j < FRN; ++j) { acc[i][j][0]=0.f; acc[i][j][1]=0.f; acc[i][j][2]=0.f; acc[i][j][3]=0.f; }

  for (int k0 = 0; k0 < Kp; k0 += 64) {
    #pragma unroll
    for (int t = 0; t < LPW; ++t) {
      int gl = wid * LPW + t;
      int isA = gl < LA;
      int tt = isA ? gl : gl - LA;
      int li = tt * 64 + lane;
      int rr = li >> 3, ch = li & 7;
      int sch = ch ^ (rr & 7);
      if (isA) {
        if (PD) gll16(A + (long)pdBase[t] + (long)(k0 >> npl) * dsp, &As[tt * 512]);
        else    gll16(Ap + (long)rr * Kp + k0 + sch * 8, &As[tt * 512]);
      } else {
        gll16(Bp + (long)rr * Kp + k0 + sch * 8, &Bs[tt * 512]);
      }
    }
    __syncthreads();
    #pragma unroll
    for (int km = 0; km < 2; ++km) {
      short8b af[FRM], bfv[FRN];
      #pragma unroll
      for (int i = 0; i < FRM; ++i) {
        int rr = wm0 + i * 16 + rl;
        af[i] = *(const short8b*)&As[rr * 64 + ((((km << 2) | cb) ^ (rr & 7)) << 3)];
      }
      #pragma unroll
      for (int j = 0; j < FRN; ++j) {
        int rr = wn0 + j * 16 + rl;
        bfv[j] = *(const short8b*)&Bs[rr * 64 + ((((km << 2) | cb) ^ (rr & 7)) << 3)];
      }
      #pragma unroll
      for (int i = 0; i < FRM; ++i)
        #pragma unroll
        for (int j = 0; j < FRN; ++j)
          acc[i][j] = __builtin_amdgcn_mfma_f32_16x16x32_bf16(af[i], bfv[j], acc[i][j], 0, 0, 0);
    }
    __syncthreads();
  }
  const int r4 = (lane >> 4) * 4, cl = lane & 15;
  #pragma unroll
  for (int i = 0; i < FRM; ++i) {
    #pragma unroll
    for (int j = 0; j < FRN; ++j) {
      int row0 = m0 + wm0 + i * 16 + r4;
      int col  = n0 + wn0 + j * 16 + cl;
      #pragma unroll
      for (int qq = 0; qq < 4; ++qq) {
        long off2 = (long)bz * sC + (long)(row0 + qq) * Np + col;
        float v = acc[i][j][qq];
        if (mode & 1) v += cA * Aadd[off2] + ((row0 + qq) == col ? cI : 0.0f);
        if (mode & 2) Cf[off2] = v;
        if (mode & 4) Cb[off2] = f2bf(v);
      }
    }
  }
}

// ---------------- transpose -> bf16 K-major with zero K-pad (expm) ----------
template<typename TI>
__global__ __launch_bounds__(256) void trans_to_bfT(const TI* __restrict__ in, ushort* __restrict__ out,
                                                    int R, int C, int inStride, int outStride, int Rpad,
                                                    long sIn, long sOut)
{
  __shared__ float sm[32][33];
  const TI* ip = in + (long)blockIdx.z * sIn;
  ushort* op = out + (long)blockIdx.z * sOut;
  int c0 = blockIdx.x * 32, r0 = blockIdx.y * 32;
  int lx = threadIdx.x & 31, ly = threadIdx.x >> 5;
  #pragma unroll
  for (int yy = 0; yy < 4; ++yy) {
    int r = r0 + ly + yy * 8, c = c0 + lx;
    if (r < R && c < C) sm[ly + yy * 8][lx] = toF(ip[(long)r * inStride + c]);
  }
  __syncthreads();
  #pragma unroll
  for (int yy = 0; yy < 4; ++yy) {
    int orow = c0 + ly + yy * 8;
    int ocol = r0 + lx;
    if (orow < C && ocol < Rpad) {
      ushort v = 0;
      if (ocol < R) v = f2bf(sm[lx][ly + yy * 8]);
      op[(long)orow * outStride + ocol] = v;
    }
  }
}

// ---------------- step operand builders ----------------
// Ttk[(bm<<npl | n)][ii] = T[ii][(bm,n)]; zero for ii>=d0 or n>=t3.
template<typename TT>
__global__ __launch_bounds__(256) void transTk2(const TT* __restrict__ T, ushort* __restrict__ out,
                                                int d0, int t3, int npl, long R1, long R1p)
{
  long idx = (long)blockIdx.x * 256 + threadIdx.x;
  if (idx >= R1p * 64) return;
  long rp = idx >> 6; int ii = (int)(idx & 63);
  long bm = rp >> npl; int n = (int)(rp & ((1 << npl) - 1));
  ushort v = 0;
  if (ii < d0 && n < t3) v = f2bf(toF(T[(long)ii * R1 + bm * t3 + n]));
  out[idx] = v;
}

// B2[(p*t3+e)][(j<<npl | n)] = T[((j*t3+n)*t2+p)*t3+e]; n>=t3 -> 0.
template<typename TI>
__global__ __launch_bounds__(256) void build_B2(const TI* __restrict__ in, ushort* __restrict__ out,
                                                int t2, int t3, int d0, int npl, int Kp2, int Nr)
{
  __shared__ float sm[32][33];
  const int npad = 1 << npl;
  int oc0 = blockIdx.x * 32, or0 = blockIdx.y * 32;
  int lx = threadIdx.x & 31, ly = threadIdx.x >> 5;
  #pragma unroll
  for (int yy = 0; yy < 4; ++yy) {
    int ocol = oc0 + ly + yy * 8;
    int orow = or0 + lx;
    float v = 0.f;
    int j = ocol >> npl, n = ocol & (npad - 1);
    if (n < t3 && orow < Nr && j < d0) {
      int p = orow / t3, e = orow - p * t3;
      v = toF(in[((long)(j * t3 + n) * t2 + p) * t3 + e]);
    }
    sm[ly + yy * 8][lx] = v;
  }
  __syncthreads();
  #pragma unroll
  for (int yy = 0; yy < 4; ++yy) {
    int orow = or0 + ly + yy * 8;
    int ocol = oc0 + lx;
    if (orow < Nr) out[(long)orow * Kp2 + ocol] = f2bf(sm[lx][ly + yy * 8]);
  }
}

__global__ __launch_bounds__(256) void build_ut1(const float* __restrict__ U, ushort* __restrict__ out,
                                                 int d0, int dc, int Mpad, long uStr, long oStr)
{
  const int bt = blockIdx.y;
  int idx = blockIdx.x * 256 + threadIdx.x;
  if (idx >= Mpad * 64) return;
  int ja = idx >> 6, ii = idx & 63;
  ushort v = 0;
  if (ii < d0 && ja < d0 * dc) {
    int j = ja / dc, a = ja - j * dc;
    v = f2bf(U[bt * uStr + ((long)ii * d0 + j) * dc + a]);
  }
  out[bt * oStr + idx] = v;
}

__global__ __launch_bounds__(256) void build_ut3(const float* __restrict__ U, ushort* __restrict__ out,
                                                 int d0, int dc, int Kp3, long uStr, long oStr)
{
  const int bt = blockIdx.y;
  int idx = blockIdx.x * 256 + threadIdx.x;
  if (idx >= 64 * Kp3) return;
  int c = idx / Kp3, mp = idx - c * Kp3;
  ushort v = 0;
  if (c < dc && mp < d0 * d0) v = f2bf(U[bt * uStr + (long)mp * dc + c]);
  out[bt * oStr + idx] = v;
}

// ---------------- fused K3: Z[(b,a,e)][c] = sum_{m,p} Y * U3, absmax ----
template<int KPG>
__global__ __launch_bounds__(256) void k3_fused(
    const ushort* __restrict__ Y, const ushort* __restrict__ Ut3,
    float* __restrict__ Z2, unsigned* __restrict__ lamslot,
    int d0, int t2, int t3, int dc, int NpY)
{
  constexpr int LDSN = (32 * KPG < 8192) ? 8192 : 32 * KPG;
  __shared__ __align__(16) ushort sYt[LDSN];
  const int tid = threadIdx.x;
  const int wid = tid >> 6, lane = tid & 63;
  const int b = blockIdx.x / dc, a = blockIdx.x - b * dc;
  for (int i8 = tid; i8 < 32 * KPG / 8; i8 += 256) *(ushort8v*)&sYt[i8 * 8] = ushort8v{};
  __syncthreads();
  const int nv = NpY / 8;
  for (int idx = tid; idx < t2 * nv; idx += 256) {
    int m = idx / nv, v = idx - m * nv;
    int col0 = v * 8;
    ushort8v val = *(const ushort8v*)(Y + ((long)(b * t2 + m) * dc + a) * NpY + col0);
    #pragma unroll
    for (int u = 0; u < 8; ++u) {
      int col = col0 + u;
      int p = (t3 == 16) ? (col >> 4) : ((col * 9363) >> 18);
      if (p < t2) {
        int e = col - p * t3;
        int k = m * d0 + p;
        sYt[e * KPG + ((((k >> 3) ^ (e & 7)) << 3) | (k & 7))] = val[u];
      }
    }
  }
  __syncthreads();
  const int kpw = KPG / 4, k0w = wid * kpw;
  const int rl = lane & 15, cb = lane >> 4;
  f32x4 acc[2][2];
  #pragma unroll
  for (int i = 0; i < 2; ++i)
    #pragma unroll
    for (int j = 0; j < 2; ++j) { acc[i][j][0]=0.f; acc[i][j][1]=0.f; acc[i][j][2]=0.f; acc[i][j][3]=0.f; }
  for (int kk = 0; kk < kpw; kk += 32) {
    int kb = k0w + kk + cb * 8;
    short8b af[2], bfv[2];
    #pragma unroll
    for (int i = 0; i < 2; ++i) {
      int e = i * 16 + rl;
      af[i] = *(const short8b*)&sYt[e * KPG + (((kb >> 3) ^ (e & 7)) << 3)];
      bfv[i] = *(const short8b*)(Ut3 + (long)(i * 16 + rl) * KPG + kb);
    }
    #pragma unroll
    for (int i = 0; i < 2; ++i)
      #pragma unroll
      for (int j = 0; j < 2; ++j)
        acc[i][j] = __builtin_amdgcn_mfma_f32_16x16x32_bf16(af[i], bfv[j], acc[i][j], 0, 0, 0);
  }
  __syncthreads();
  float* Lp = (float*)sYt;
  #pragma unroll
  for (int i = 0; i < 2; ++i)
    #pragma unroll
    for (int j = 0; j < 2; ++j)
      #pragma unroll
      for (int qq = 0; qq < 4; ++qq) {
        int e32 = i * 16 + (lane >> 4) * 4 + qq;
        int c32 = j * 16 + (lane & 15);
        Lp[wid * 1024 + e32 * 32 + c32] = acc[i][j][qq];
      }
  __syncthreads();
  float mx = 0.f;
  for (int idx = tid; idx < 1024; idx += 256) {
    float z = Lp[idx] + Lp[1024 + idx] + Lp[2048 + idx] + Lp[3072 + idx];
    int e = idx >> 5, c = idx & 31;
    if (e < t3 && c < dc) {
      Z2[((long)(b * dc + a) * t3 + e) * 64 + c] = z;
      mx = fmaxf(mx, fabsf(z));
    }
  }
  __syncthreads();
  Lp[tid] = mx;
  __syncthreads();
  for (int s = 128; s > 0; s >>= 1) {
    if (tid < s) Lp[tid] = fmaxf(Lp[tid], Lp[tid + s]);
    __syncthreads();
  }
  if (tid == 0) atomicMax(lamslot, __float_as_uint(Lp[0]));
}

// ---- T'[b,c,e,a](bf16) = Z2/lam; fe/out update by block (0,0) ----
__global__ __launch_bounds__(256) void permute_scale2d(const float* __restrict__ Z2, ushort* __restrict__ Tn,
                                                       const unsigned* __restrict__ lamslot,
                                                       float* __restrict__ fe, float w, float* __restrict__ dout,
                                                       int dc, int t3, int chunk)
{
  extern __shared__ char dynC[];
  ushort* sm = (ushort*)dynC;
  const int b = blockIdx.x;
  const int c0 = blockIdx.y * chunk;
  const int tid = threadIdx.x;
  const float lam = __uint_as_float(*lamslot);
  const float s = 1.0f / lam;
  if (b == 0 && blockIdx.y == 0 && tid == 0) {
    float f = fe[0] - w * logf(lam);
    fe[0] = f; dout[0] = f;
  }
  const int TD = t3 * dc;
  const int tot = dc * t3 * chunk;
  for (int idx = tid; idx < tot; idx += 256) {
    int c7 = idx % chunk; int rm = idx / chunk;
    int e = rm % t3; int a = rm / t3;
    float v = Z2[(((long)(b * dc + a)) * t3 + e) * 64 + c0 + c7] * s;
    sm[(c7 * t3 + e) * dc + a] = f2bf(v);
  }
  __syncthreads();
  const long ob = (long)(b * dc + c0) * TD;
  for (int idx = tid; idx < tot / 8; idx += 256)
    *(ushort8v*)(Tn + ob + idx * 8) = *(ushort8v*)(sm + idx * 8);
}

// ---------------- expm builders (bf16 MFMA path) ----------------
__global__ __launch_bounds__(256) void build_A2(const float* __restrict__ Aflat, float* __restrict__ Af,
                                                ushort* __restrict__ Ab, ushort* __restrict__ An,
                                                int n, int Np, long aoff, long tri, float sc)
{
  const int b = blockIdx.y;
  const long nn = (long)Np * Np;
  const long id = (long)blockIdx.x * 256 + threadIdx.x;
  if (id >= nn) return;
  const int r = (int)(id / Np), c = (int)(id % Np);
  float v = 0.0f;
  if (r < n && c < n) {
    if (c > r)      v =  Aflat[aoff + b * tri + (long)r * (n - 1) - (long)r * (r - 1) / 2 + (c - r - 1)] * sc;
    else if (c < r) v = -Aflat[aoff + b * tri + (long)c * (n - 1) - (long)c * (c - 1) / 2 + (r - c - 1)] * sc;
  }
  long o = b * nn + id;
  Af[o] = v; Ab[o] = f2bf(v); An[o] = f2bf(-v);
}

__global__ __launch_bounds__(256) void axpy_q2(const ushort* __restrict__ A2b, const float* __restrict__ Af,
                                               ushort* __restrict__ Qb, int Np)
{
  const int b = blockIdx.y;
  const long nn = (long)Np * Np;
  const long id = (long)blockIdx.x * 256 + threadIdx.x;
  if (id >= nn) return;
  const int r = (int)(id / Np), c = (int)(id % Np);
  long o = b * nn + id;
  float v = (1.0f/40320.0f) * toF(A2b[o]) + (1.0f/5040.0f) * Af[o] + ((r == c) ? (1.0f/720.0f) : 0.0f);
  Qb[o] = f2bf(v);
}

__global__ __launch_bounds__(256) void extract_u2(const float* __restrict__ E, float* __restrict__ W,
                                                  int n, int dcut, int rowStride, long ubase, long ustride, long estride)
{
  const int b = blockIdx.y;
  const long tot = (long)n * dcut;
  const long id = (long)blockIdx.x * 256 + threadIdx.x;
  if (id >= tot) return;
  const int rr = (int)(id / dcut), aa = (int)(id % dcut);
  W[ubase + b * ustride + id] = E[b * estride + (long)rr * rowStride + aa];
}

// ---------------- small expm (n<=16) ----------------
struct SmallStep { int n, d0, dcut, s; long aoff; long uoff; };
struct SmallStep4 { SmallStep st[4]; };

__global__ __launch_bounds__(256) void expm_small_kernel(const float* __restrict__ Aflat,
                                                         float* __restrict__ W, SmallStep4 ps)
{
  SmallStep p = ps.st[blockIdx.x];
  const int n = p.n, nn = n * n;
  __shared__ float As[256], A2[256], Qa[256], Qb[256];
  const int tid = threadIdx.x;
  const int r = (tid < nn) ? (tid / n) : 0;
  const int c = (tid < nn) ? (tid % n) : 0;
  const float sc = 1.0f / (float)(1 << p.s);
  if (tid < nn) {
    float v = 0.0f;
    if (c > r)      v =  Aflat[p.aoff + (long)r*(n-1) - (long)r*(r-1)/2 + (c - r - 1)] * sc;
    else if (c < r) v = -Aflat[p.aoff + (long)c*(n-1) - (long)c*(c-1)/2 + (r - c - 1)] * sc;
    As[tid] = v;
  }
  __syncthreads();
  if (tid < nn) {
    float s2 = 0.0f;
    for (int k = 0; k < n; ++k) s2 += As[r*n+k] * As[k*n+c];
    A2[tid] = s2;
  }
  __syncthreads();
  if (tid < nn)
    Qa[tid] = (1.0f/40320.0f)*A2[tid] + (1.0f/5040.0f)*As[tid] + ((r==c) ? (1.0f/720.0f) : 0.0f);
  __syncthreads();
  float* qp = Qa; float* qn = Qb;
  const float cis[3] = {1.0f/24.0f, 0.5f, 1.0f};
  const float cas[3] = {1.0f/120.0f, 1.0f/6.0f, 1.0f};
  #pragma unroll
  for (int it = 0; it < 3; ++it) {
    if (tid < nn) {
      float s2 = 0.0f;
      for (int k = 0; k < n; ++k) s2 += A2[r*n+k] * qp[k*n+c];
      qn[tid] = s2 + cas[it]*As[tid] + ((r==c) ? cis[it] : 0.0f);
    }
    __syncthreads();
    float* t = qp; qp = qn; qn = t;
  }
  for (int it = 0; it < p.s; ++it) {
    float s2 = 0.0f;
    if (tid < nn) { for (int k = 0; k < n; ++k) s2 += qp[r*n+k] * qp[k*n+c]; }
    if (tid < nn) qn[tid] = s2;
    __syncthreads();
    float* t = qp; qp = qn; qn = t;
  }
  if (tid < n * p.dcut) {
    int rr = tid / p.dcut, aa = tid % p.dcut;
    W[p.uoff + tid] = qp[rr*n + aa];
  }
}

// ---------------- steps 0-2 fused: one block, fp32, full RG steps ----------
__global__ __launch_bounds__(256) void small_steps_kernel(
    const float* __restrict__ T0in, const float* __restrict__ Wu,
    long u0, long u1, long u2, float* __restrict__ Tout, float* __restrict__ fe)
{
  __shared__ float Tb[256], X2[4096], Yb[4096], Zb[4096], red[256];
  const int tid = threadIdx.x;
  const int D0[3]={2,2,4}, Tt1[3]={2,4,4}, Tt2[3]={2,2,4}, Tt3[3]={2,4,4}, DCv[3]={4,4,16};
  const long UO[3]={u0,u1,u2};
  if (tid < 16) Tb[tid] = T0in[tid];
  float feacc = 0.0f;
  __syncthreads();
  for (int st = 0; st < 3; ++st) {
    const int d0=D0[st], t1=Tt1[st], t2=Tt2[st], t3=Tt3[st], dc=DCv[st];
    const int M = t1*t2*dc, K = d0*t3, N = t2*t3;
    const int R = t1*t2*t3;
    const float* U = Wu + UO[st];
    for (int idx = tid; idx < M*K; idx += 256) {
      int row = idx / K, k = idx - row*K;
      int bm = row / dc, a = row - bm*dc;
      int j = k / t3, n = k - j*t3;
      float s = 0.f;
      for (int i2 = 0; i2 < d0; ++i2)
        s += Tb[i2*R + bm*t3 + n] * U[(i2*d0 + j)*dc + a];
      X2[idx] = s;
    }
    __syncthreads();
    for (int idx = tid; idx < M*N; idx += 256) {
      int row = idx / N, col = idx - row*N;
      float s = 0.f;
      for (int k = 0; k < K; ++k) s += X2[row*K + k] * Tb[k*N + col];
      Yb[idx] = s;
    }
    __syncthreads();
    const int ZS = dc*t1*dc*t3;
    for (int idx = tid; idx < ZS; idx += 256) {
      int e = idx % t3; int r2 = idx / t3;
      int c = r2 % dc; int r3 = r2 / dc;
      int b = r3 % t1; int a = r3 / t1;
      float s = 0.f;
      for (int m = 0; m < t2; ++m)
        for (int p = 0; p < t2; ++p)
          s += Yb[((b*t2 + m)*dc + a)*N + p*t3 + e] * U[(m*d0 + p)*dc + c];
      Zb[idx] = s;
    }
    __syncthreads();
    float mx = 0.f;
    for (int idx = tid; idx < ZS; idx += 256) mx = fmaxf(mx, fabsf(Zb[idx]));
    red[tid] = mx; __syncthreads();
    for (int s2 = 128; s2 > 0; s2 >>= 1) {
      if (tid < s2) red[tid] = fmaxf(red[tid], red[tid + s2]);
      __syncthreads();
    }
    float lam = red[0];
    feacc -= (TEMPC / (float)(1 << (st + 1))) * logf(lam);
    float inv = 1.0f / lam;
    __syncthreads();
    const int TS = t1*dc*t3*dc;
    for (int idx = tid; idx < TS; idx += 256) {
      int a = idx % dc; int r2 = idx / dc;
      int e = r2 % t3; int r3 = r2 / t3;
      int c = r3 % dc; int b = r3 / dc;
      float v = Zb[(((long)a*t1 + b)*dc + c)*t3 + e] * inv;
      if (st == 2) Tout[idx] = v; else Tb[idx] = v;
    }
    __syncthreads();
  }
  if (tid == 0) fe[0] = feacc;
}

__global__ void init_kernel(float* __restrict__ W)
{
  int t = threadIdx.x;
  if (t == 0) W[0] = 0.0f;                      // FE
  if (t >= 8 && t < 20) ((unsigned*)W)[t] = 0u; // lam slots
}

// ============================================================================
extern "C" void kernel_launch(void* const* d_in, const int* in_sizes, int n_in,
                              void* d_out, int out_size, void* d_ws, size_t ws_size,
                              hipStream_t stream)
{
  const float* Aflat = (const float*)d_in[0];
  const float* T0    = (const float*)d_in[1];
  float* out = (float*)d_out;
  float* W = (float*)d_ws;
  (void)ws_size; (void)in_sizes; (void)n_in; (void)out_size;

  const int SH_n[12]  = {4,4,16,16,256,256,784,784,784,784,784,784};
  const int SH_d0[12] = {2,2,4,4,16,16,28,28,28,28,28,28};
  const int SH_dc[12] = {4,4,16,16,28,28,28,28,28,28,28,28};
  long aoff[12]; { long o = 0; for (int i = 0; i < 12; ++i) { aoff[i] = o; o += (long)SH_n[i]*(SH_n[i]-1)/2; } }
  long uoff[12]; { long o = 1024; for (int i = 0; i < 12; ++i) { uoff[i] = o; o += (long)SH_d0[i]*SH_d0[i]*SH_dc[i]; } }
  int T1d[12], T2d[12], T3d[12], T0d[12];
  { int a=2,b=2,c=2,d=2;
    for (int i = 0; i < 12; ++i) { T0d[i]=a; T1d[i]=b; T2d[i]=c; T3d[i]=d;
      int dc = SH_dc[i]; int na=b, nb=dc, nc=d, nd=dc; a=na; b=nb; c=nc; d=nd; } }

  // ---- workspace layout (float units) ----
  const long FE = 0, LAMV = 8;
  const long TA   = 150016;
  const long TB   = TA + 614656;           // 764672
  const long Z2o  = TB + 614656;           // 1379328 (1,409,024 fl)
  const long TTK  = Z2o + 1409024;         // (802,816 fl = R1p_max x 64 ush)
  const long TTo  = TTK + 802816;          // (401,408 fl: B2 896x896 ush)
  const long UT1o = TTo + 401408;          // 9 slots x 832x64 ush = 239,616 fl
  const long UT3o = UT1o + 240000;         // 9 slots x 64x896 ush = 258,048 fl
  const long BIG0 = UT3o + 258048;         // P (10,436,608 fl max)
  const long BIG2 = BIG0 + 10500000;       // Y (9,863,168 fl max)
  // phase-1 overlays (time-disjoint with P/Y):
  const long P_Af  = BIG0;                 // 6 x 802816 fl
  const long P_S4  = BIG0 + 4816896;       // 6 x 896x64 f32
  const long P_bf  = BIG0 + 5200000;       // 6 bf16 bufs x 2,408,448 fl
  const long P_Ab  = P_bf;
  const long P_An  = P_bf + 2408448;
  const long P_A2b = P_bf + 2*2408448;
  const long P_Q0  = P_bf + 3*2408448;
  const long P_Q1  = P_bf + 4*2408448;
  const long P_QT  = P_bf + 5*2408448;
  const long P_Bb  = BIG0 + 19700000;      // group-B overlay
  const long B_Af  = P_Bb;                 // 2 x 65536 f32
  const long B_S4  = P_Bb + 131072;        // 2 x 256x64 f32
  const long B_Ab  = P_Bb + 163840;        // 6 bf16 bufs x 65,536 fl
  const long B_An  = B_Ab + 65536;
  const long B_A2b = B_An + 65536;
  const long B_Q0  = B_A2b + 65536;
  const long B_Q1  = B_Q0 + 65536;
  const long B_QT  = B_Q1 + 65536;

  const float c5 = 1.0f/120.0f, c4 = 1.0f/24.0f, c3 = 1.0f/6.0f, c2 = 0.5f;

  ushort* TTKp = (ushort*)(W + TTK);
  ushort* B2b  = (ushort*)(W + TTo);
  ushort* UT1p = (ushort*)(W + UT1o);
  ushort* UT3p = (ushort*)(W + UT3o);
  ushort* Pb   = (ushort*)(W + BIG0);
  ushort* Yb   = (ushort*)(W + BIG2);
  float*  Z2f  = W + Z2o;
  unsigned* lamV = (unsigned*)(W + LAMV);

  // ================= Phase 1: U matrices =================
  {
    SmallStep4 sp;
    const int ss[4] = {0,0,1,1};
    for (int i = 0; i < 4; ++i) {
      sp.st[i].n = SH_n[i]; sp.st[i].d0 = SH_d0[i]; sp.st[i].dcut = SH_dc[i];
      sp.st[i].s = ss[i]; sp.st[i].aoff = aoff[i]; sp.st[i].uoff = uoff[i];
    }
    expm_small_kernel<<<4, 256, 0, stream>>>(Aflat, W, sp);
  }

  // ---- group A: steps 6-11 (n=784 -> Np=896, batch 6, s=1, Taylor-8) ----
  {
    const int n = 784, Np = 896, bt = 6;
    const long NN = (long)Np * Np;
    float* Af = W + P_Af;  float* S4 = W + P_S4;
    ushort* Ab = (ushort*)(W + P_Ab);  ushort* An = (ushort*)(W + P_An);
    ushort* A2b = (ushort*)(W + P_A2b);
    ushort* Q0 = (ushort*)(W + P_Q0);  ushort* Q1 = (ushort*)(W + P_Q1);
    ushort* QT = (ushort*)(W + P_QT);
    dim3 ge((int)((NN + 255) / 256), bt);
    build_A2<<<ge, 256, 0, stream>>>(Aflat, Af, Ab, An, n, Np, aoff[6], 306936, 0.5f);
    dim3 g(Np/128, Np/128, bt);
    gemm_mfma<128,128,false><<<g,256,0,stream>>>(Ab, An, nullptr, A2b, nullptr, 0.f, 0.f, 4, Np, Np, NN, NN, NN, 0,0,1);
    axpy_q2<<<ge, 256, 0, stream>>>(A2b, Af, Q0, Np);
    gemm_mfma<128,128,false><<<g,256,0,stream>>>(Q0, A2b, nullptr, Q1, Af, c5, c4, 5, Np, Np, NN, NN, NN, 0,0,1);
    gemm_mfma<128,128,false><<<g,256,0,stream>>>(Q1, A2b, nullptr, Q0, Af, c3, c2, 5, Np, Np, NN, NN, NN, 0,0,1);
    gemm_mfma<128,128,false><<<g,256,0,stream>>>(Q0, A2b, nullptr, Q1, Af, 1.f, 1.f, 5, Np, Np, NN, NN, NN, 0,0,1);
    // single squaring, only first 64 columns needed
    trans_to_bfT<ushort><<<dim3(2, Np/32, bt),256,0,stream>>>(Q1, QT, Np, 64, Np, Np, Np, NN, NN);
    gemm_mfma<64,64,false><<<dim3(1, Np/64, bt),256,0,stream>>>(Q1, QT, S4, nullptr, nullptr, 0.f, 0.f, 2,
                                                                64, Np, NN, NN, 57344, 0,0,1);
    extract_u2<<<dim3(86, bt), 256, 0, stream>>>(S4, W, n, 28, 64, uoff[6], 21952, 57344);
  }

  // ---- group B: steps 4,5 (n=256, batch 2, s=1) bf16 MFMA ----
  {
    const int n = 256, Np = 256, bt = 2;
    const long NN = (long)Np * Np;
    float* Af = W + B_Af;  float* S4 = W + B_S4;
    ushort* Ab = (ushort*)(W + B_Ab);  ushort* An = (ushort*)(W + B_An);
    ushort* A2b = (ushort*)(W + B_A2b);
    ushort* Q0 = (ushort*)(W + B_Q0);  ushort* Q1 = (ushort*)(W + B_Q1);
    ushort* QT = (ushort*)(W + B_QT);
    dim3 ge((int)((NN + 255) / 256), bt);
    build_A2<<<ge, 256, 0, stream>>>(Aflat, Af, Ab, An, n, Np, aoff[4], 32640, 0.5f);
    dim3 g(Np/128, Np/128, bt);
    gemm_mfma<128,128,false><<<g,256,0,stream>>>(Ab, An, nullptr, A2b, nullptr, 0.f, 0.f, 4, Np, Np, NN, NN, NN, 0,0,1);
    axpy_q2<<<ge, 256, 0, stream>>>(A2b, Af, Q0, Np);
    gemm_mfma<128,128,false><<<g,256,0,stream>>>(Q0, A2b, nullptr, Q1, Af, c5, c4, 5, Np, Np, NN, NN, NN, 0,0,1);
    gemm_mfma<128,128,false><<<g,256,0,stream>>>(Q1, A2b, nullptr, Q0, Af, c3, c2, 5, Np, Np, NN, NN, NN, 0,0,1);
    gemm_mfma<128,128,false><<<g,256,0,stream>>>(Q0, A2b, nullptr, Q1, Af, 1.f, 1.f, 5, Np, Np, NN, NN, NN, 0,0,1);
    trans_to_bfT<ushort><<<dim3(2, Np/32, bt),256,0,stream>>>(Q1, QT, Np, 64, Np, Np, Np, NN, NN);
    gemm_mfma<64,64,false><<<dim3(1, Np/64, bt),256,0,stream>>>(Q1, QT, S4, nullptr, nullptr, 0.f, 0.f, 2,
                                                                64, Np, NN, NN, 16384, 0,0,1);
    extract_u2<<<dim3(28, bt), 256, 0, stream>>>(S4, W, n, 28, 64, uoff[4], 7168, 16384);
  }

  // ---- U-derived operands: slots (i-3) for i in 3..11 ----
  build_ut1<<<dim3(16, 1), 256, 0, stream>>>(W + uoff[3], UT1p, 4, 16, 64, 0, 0);
  build_ut3<<<dim3(32, 1), 256, 0, stream>>>(W + uoff[3], UT3p, 4, 16, 128, 0, 0);
  build_ut1<<<dim3(112, 2), 256, 0, stream>>>(W + uoff[4], UT1p + 1L*832*64, 16, 28, 448, 7168, 832*64);
  build_ut3<<<dim3(64, 2), 256, 0, stream>>>(W + uoff[4], UT3p + 1L*64*896, 16, 28, 256, 7168, 64*896);
  build_ut1<<<dim3(208, 6), 256, 0, stream>>>(W + uoff[6], UT1p + 3L*832*64, 28, 28, 832, 21952, 832*64);
  build_ut3<<<dim3(224, 6), 256, 0, stream>>>(W + uoff[6], UT3p + 3L*64*896, 28, 28, 896, 21952, 64*896);

  // ================= Phase 2 =================
  init_kernel<<<1, 64, 0, stream>>>(W);
  float* Tcur = W + TA;
  float* Tnext = W + TB;
  // steps 0-2 fused (fp32, single block); writes step-3 input (4096 f32) + fe
  small_steps_kernel<<<1, 256, 0, stream>>>(T0, W, uoff[0], uoff[1], uoff[2], Tcur, W + FE);

  for (int i = 3; i < 12; ++i) {
    const int t1 = T1d[i], t2 = T2d[i], t3 = T3d[i], d0 = T0d[i], dc = SH_dc[i];
    const int M = t1*t2*dc, N = t2*t3;
    const float w = TEMPC / (float)(1 << (i + 1));
    const bool inBf = (i >= 4);
    const int npl = (t3 == 16) ? 4 : 5;
    const int npad = 1 << npl;
    const int Kp2 = d0 * npad;
    const int Npd = (N + 127) / 128 * 128;
    const long R1 = (long)t1 * t2 * t3;
    const long R1p = (long)t1 * t2 * npad;
    const int Mpad1 = (d0*dc + 63)/64*64;
    const int Mpad2 = (M + 127)/128*128;
    const ushort* Ut1_i = UT1p + (long)(i-3)*832*64;
    const ushort* Ut3_i = UT3p + (long)(i-3)*64*896;
    unsigned* lam_i = lamV + (i - 3);

    // K1: Ttk (n-padded) -> P = Ut1 @ Ttk
    if (inBf) transTk2<ushort><<<(int)((R1p*64 + 255)/256), 256, 0, stream>>>(
        (const ushort*)Tcur, TTKp, d0, t3, npl, R1, R1p);
    else      transTk2<float><<<(int)((R1p*64 + 255)/256), 256, 0, stream>>>(
        Tcur, TTKp, d0, t3, npl, R1, R1p);
    gemm_mfma<64,64,false><<<dim3((int)(R1p/64), Mpad1/64), 256, 0, stream>>>(
        Ut1_i, TTKp, nullptr, Pb, nullptr, 0.f, 0.f, 4, (int)R1p, 64, 0, 0, 0, 0, 0, 1);

    // B2 (K-remapped T^T), then GEMM2 reading A directly from P
    if (inBf) build_B2<ushort><<<dim3(Kp2/32, (N + 31)/32), 256, 0, stream>>>(
        (const ushort*)Tcur, B2b, t2, t3, d0, npl, Kp2, N);
    else      build_B2<float><<<dim3(Kp2/32, (N + 31)/32), 256, 0, stream>>>(
        Tcur, B2b, t2, t3, d0, npl, Kp2, N);
    gemm_mfma<128,128,true><<<dim3(Npd/128, Mpad2/128), 256, 0, stream>>>(
        Pb, B2b, nullptr, Yb, nullptr, 0.f, 0.f, 4, Npd, Kp2, 0, 0, 0,
        (int)R1p, npl, dc);

    // fused K3 (+absmax), then permute+scale (+fe update)
    if (d0 == 4)       k3_fused<128><<<t1*dc, 256, 0, stream>>>(Yb, Ut3_i, Z2f, lam_i, d0, t2, t3, dc, Npd);
    else if (d0 == 16) k3_fused<256><<<t1*dc, 256, 0, stream>>>(Yb, Ut3_i, Z2f, lam_i, d0, t2, t3, dc, Npd);
    else               k3_fused<896><<<t1*dc, 256, 0, stream>>>(Yb, Ut3_i, Z2f, lam_i, d0, t2, t3, dc, Npd);
    const int chunk = (dc == 16) ? 4 : 7;
    permute_scale2d<<<dim3(t1, dc/chunk), 256, chunk*t3*dc*2, stream>>>(
        Z2f, (ushort*)Tnext, lam_i, W + FE, w, out, dc, t3, chunk);

    float* tmp = Tcur; Tcur = Tnext; Tnext = tmp;
  }
}